// Round 10
// baseline (306.820 us; speedup 1.0000x reference)
//
#include <hip/hip_runtime.h>
#include <hip/hip_bf16.h>
#include <cmath>

#define B_   2
#define S_   2048
#define D_   1024
#define H_   16
#define DFF_ 4096
#define DH_  64
#define M_   (B_*S_)   // 4096 rows

typedef __bf16 bfx8 __attribute__((ext_vector_type(8)));
typedef __bf16 bfx4 __attribute__((ext_vector_type(4)));
typedef float  fx4  __attribute__((ext_vector_type(4)));

// ---------------------------------------------------------------- utilities
__device__ __forceinline__ void gload_lds16(const void* g, void* l) {
  __builtin_amdgcn_global_load_lds((__attribute__((address_space(1))) void*)(g),
                                   (__attribute__((address_space(3))) void*)(l),
                                   16, 0, 0);
}

// ------------------------------------------------------------- fp32 -> bf16
__global__ __launch_bounds__(256)
void to_bf16_kernel(const float* __restrict__ in, __bf16* __restrict__ out, int n) {
  int i = (blockIdx.x * 256 + threadIdx.x) * 4;
  if (i < n) {
    float4 v = *(const float4*)(in + i);
    bfx4 o;
    o[0] = (__bf16)v.x; o[1] = (__bf16)v.y; o[2] = (__bf16)v.z; o[3] = (__bf16)v.w;
    *(bfx4*)(out + i) = o;
  }
}

// ------------------------------------------------ mask * log2(e) (tiny)
__global__ __launch_bounds__(256)
void scale_mask_kernel(const float* __restrict__ in, float* __restrict__ out, int n) {
  int i = blockIdx.x * 256 + threadIdx.x;
  if (i < n) out[i] = in[i] * 1.44269504f;
}

// --------------------------------------- W [R][C] f32 -> Wt [C][R] bf16
__global__ __launch_bounds__(256)
void transpose_conv_kernel(const float* __restrict__ in, __bf16* __restrict__ out,
                           int R, int C) {
  __shared__ float t[32][33];
  int r0 = blockIdx.y * 32, c0 = blockIdx.x * 32;
  int tx = threadIdx.x, ty = threadIdx.y;   // 32 x 8
#pragma unroll
  for (int j = 0; j < 4; ++j) {
    int r = ty + j * 8;
    t[r][tx] = in[(size_t)(r0 + r) * C + c0 + tx];
  }
  __syncthreads();
#pragma unroll
  for (int j = 0; j < 4; ++j) {
    int c = ty + j * 8;
    out[(size_t)(c0 + c) * R + r0 + tx] = (__bf16)t[tx][c];
  }
}

// ----------------------- V [B,S,H,DH] bf16 -> Vt [B,H,DH,S] bf16
__global__ __launch_bounds__(256)
void transpose_v_kernel(const __bf16* __restrict__ vb, __bf16* __restrict__ vt) {
  __shared__ __bf16 t[32][33];
  int bh = blockIdx.z;
  int b = bh >> 4, h = bh & 15;
  int s0 = blockIdx.x * 32, d0 = blockIdx.y * 32;
  int tx = threadIdx.x, ty = threadIdx.y;
#pragma unroll
  for (int j = 0; j < 4; ++j) {
    int s = ty + j * 8;
    t[s][tx] = vb[(size_t)((b * S_ + s0 + s) * H_ + h) * DH_ + d0 + tx];
  }
  __syncthreads();
#pragma unroll
  for (int j = 0; j < 4; ++j) {
    int d = ty + j * 8;
    vt[(size_t)(bh * DH_ + d0 + d) * S_ + s0 + tx] = t[tx][d];
  }
}

// --------------------------------------------------------------- GEMM 128-tile
template<int MODE, int TBN>
__device__ __forceinline__ void gemm_body(const __bf16* __restrict__ A,
                                          const __bf16* __restrict__ Bt,
                                          const float* __restrict__ bias,
                                          void* __restrict__ out,
                                          int Ndim, int Kdim,
                                          int m0, int n0,
                                          __bf16* As, __bf16* Bs) {
  const int tid  = threadIdx.x;
  const int lane = tid & 63;
  const int w    = tid >> 6;
  const int wm   = w >> 1, wn = w & 1;
  constexpr int NF = TBN / 32;

  fx4 acc[4][NF];
#pragma unroll
  for (int i = 0; i < 4; ++i)
#pragma unroll
    for (int j = 0; j < NF; ++j) acc[i][j] = {0.f, 0.f, 0.f, 0.f};

  const int KT = Kdim / 64;
  for (int kt = 0; kt < KT; ++kt) {
    __syncthreads();
    const int kb0 = kt * 64;
#pragma unroll
    for (int i = 0; i < 4; ++i) {
      int o   = tid * 16 + i * 4096;
      int row = o >> 7, cb = o & 127;
      int cbs = cb ^ ((row & 7) << 4);
      gload_lds16((const char*)A + ((size_t)(m0 + row) * Kdim + kb0) * 2 + cbs,
                  (char*)As + o);
    }
#pragma unroll
    for (int i = 0; i < TBN / 32; ++i) {
      int o   = tid * 16 + i * 4096;
      int row = o >> 7, cb = o & 127;
      int cbs = cb ^ ((row & 7) << 4);
      gload_lds16((const char*)Bt + ((size_t)(n0 + row) * Kdim + kb0) * 2 + cbs,
                  (char*)Bs + o);
    }
    __syncthreads();

#pragma unroll
    for (int kk = 0; kk < 2; ++kk) {
      bfx8 afr[4], bfr[NF];
      const int cb = kk * 64 + ((lane >> 4) << 4);
#pragma unroll
      for (int mf = 0; mf < 4; ++mf) {
        int row = wm * 64 + mf * 16 + (lane & 15);
        afr[mf] = *(const bfx8*)((const char*)As + row * 128 + (cb ^ ((row & 7) << 4)));
      }
#pragma unroll
      for (int nf = 0; nf < NF; ++nf) {
        int row = wn * (TBN / 2) + nf * 16 + (lane & 15);
        bfr[nf] = *(const bfx8*)((const char*)Bs + row * 128 + (cb ^ ((row & 7) << 4)));
      }
#pragma unroll
      for (int mf = 0; mf < 4; ++mf)
#pragma unroll
        for (int nf = 0; nf < NF; ++nf)
          acc[mf][nf] = __builtin_amdgcn_mfma_f32_16x16x32_bf16(afr[mf], bfr[nf],
                                                                acc[mf][nf], 0, 0, 0);
    }
  }

#pragma unroll
  for (int mf = 0; mf < 4; ++mf) {
#pragma unroll
    for (int nf = 0; nf < NF; ++nf) {
      int col = n0 + wn * (TBN / 2) + nf * 16 + (lane & 15);
      float bvl = bias[col];
#pragma unroll
      for (int r = 0; r < 4; ++r) {
        int rowg = m0 + wm * 64 + mf * 16 + ((lane >> 4) << 2) + r;
        float v = acc[mf][nf][r] + bvl;
        if (MODE == 2) v = 0.5f * v * (1.0f + erff(v * 0.70710678118654752f));
        if (MODE == 1) ((float*)out)[(size_t)rowg * Ndim + col] = v;
        else          ((__bf16*)out)[(size_t)rowg * Ndim + col] = (__bf16)v;
      }
    }
  }
}

template<int MODE, int TBN>
__global__ __launch_bounds__(256)
void gemm_kernel(const __bf16* __restrict__ A, const __bf16* __restrict__ Bt,
                 const float* __restrict__ bias, void* __restrict__ out,
                 int Ndim, int Kdim) {
  __shared__ alignas(16) __bf16 As[128 * 64];
  __shared__ alignas(16) __bf16 Bs[TBN * 64];
  gemm_body<MODE, TBN>(A, Bt, bias, out, Ndim, Kdim,
                       blockIdx.y * 128, blockIdx.x * TBN, As, Bs);
}

// --------------------------------------------------------------- GEMM 256-tile
// (round-9 validated 8-phase schedule, unchanged)
__device__ __forceinline__ void stage_a256(const __bf16* __restrict__ A, int m0,
                                           int Kdim, int tile, int h, char* Asm) {
  char* dst = Asm + (tile & 1) * 32768;
  const int kb0 = tile * 64;
  const int tid = threadIdx.x;
#pragma unroll
  for (int it = 0; it < 2; ++it) {
    int o = tid * 16 + it * 8192;
    int lrow = o >> 7, cb = o & 127;
    int r = (lrow & 63) + h * 64 + ((lrow >> 6) << 7);
    int csrc = cb ^ ((r & 7) << 4);
    gload_lds16((const char*)A + ((size_t)(m0 + r) * Kdim + kb0) * 2 + csrc,
                dst + r * 128 + cb);
  }
}
__device__ __forceinline__ void stage_b256(const __bf16* __restrict__ Bt, int n0,
                                           int Kdim, int tile, int h, char* Bsm) {
  char* dst = Bsm + (tile & 1) * 32768;
  const int kb0 = tile * 64;
  const int tid = threadIdx.x;
#pragma unroll
  for (int it = 0; it < 2; ++it) {
    int o = tid * 16 + it * 8192;
    int lrow = o >> 7, cb = o & 127;
    int r = h * 128 + lrow;
    int csrc = cb ^ ((r & 7) << 4);
    gload_lds16((const char*)Bt + ((size_t)(n0 + r) * Kdim + kb0) * 2 + csrc,
                dst + r * 128 + cb);
  }
}

template<int MODE>
__device__ __forceinline__ void gemm256_body(const __bf16* __restrict__ A,
                                             const __bf16* __restrict__ Bt,
                                             const float* __restrict__ bias,
                                             void* __restrict__ out,
                                             int Ndim, int Kdim, int m0, int n0) {
  extern __shared__ char smem[];
  char* Asm = smem;
  char* Bsm = smem + 65536;
  const int tid  = threadIdx.x;
  const int lane = tid & 63;
  const int w    = tid >> 6;
  const int wm   = w >> 2;
  const int wn   = w & 3;
  const int g    = lane >> 4;
  const int ql   = lane & 15;
  const int KT   = Kdim / 64;

  fx4 acc[8][4];
#pragma unroll
  for (int i = 0; i < 8; ++i)
#pragma unroll
    for (int j = 0; j < 4; ++j) acc[i][j] = {0.f, 0.f, 0.f, 0.f};

  stage_a256(A, m0, Kdim, 0, 0, Asm);
  stage_a256(A, m0, Kdim, 0, 1, Asm);
  stage_b256(Bt, n0, Kdim, 0, 0, Bsm);
  stage_b256(Bt, n0, Kdim, 0, 1, Bsm);
  stage_a256(A, m0, Kdim, 1, 0, Asm);
  asm volatile("s_waitcnt vmcnt(2)" ::: "memory");
  __builtin_amdgcn_s_barrier();
  __builtin_amdgcn_sched_barrier(0);

  for (int t = 0; t < KT; ++t) {
    const char* Ab = Asm + (t & 1) * 32768;
    const char* Bb = Bsm + (t & 1) * 32768;
#pragma unroll
    for (int p = 0; p < 4; ++p) {
      const int ah = p >> 1, kk = p & 1;
      if (p == 0 && t + 1 < KT) stage_a256(A, m0, Kdim, t + 1, 1, Asm);
      if (p == 1 && t + 1 < KT) stage_b256(Bt, n0, Kdim, t + 1, 0, Bsm);
      if (p == 2 && t + 1 < KT) stage_b256(Bt, n0, Kdim, t + 1, 1, Bsm);
      if (p == 3 && t + 2 < KT) stage_a256(A, m0, Kdim, t + 2, 0, Asm);
      __builtin_amdgcn_sched_barrier(0);

      bfx8 af[4], bf[4];
      const int cbv = kk * 64 + g * 16;
#pragma unroll
      for (int j = 0; j < 4; ++j) {
        int arow = wm * 128 + (ah * 4 + j) * 16 + ql;
        af[j] = *(const bfx8*)(Ab + arow * 128 + (cbv ^ ((arow & 7) << 4)));
      }
#pragma unroll
      for (int nf = 0; nf < 4; ++nf) {
        int brow = wn * 64 + nf * 16 + ql;
        bf[nf] = *(const bfx8*)(Bb + brow * 128 + (cbv ^ ((brow & 7) << 4)));
      }
      __builtin_amdgcn_sched_barrier(0);
      __builtin_amdgcn_s_barrier();
      asm volatile("s_waitcnt lgkmcnt(0)" ::: "memory");
      __builtin_amdgcn_sched_barrier(0);
      __builtin_amdgcn_s_setprio(1);
#pragma unroll
      for (int j = 0; j < 4; ++j)
#pragma unroll
        for (int nf = 0; nf < 4; ++nf)
          acc[ah * 4 + j][nf] = __builtin_amdgcn_mfma_f32_16x16x32_bf16(
              af[j], bf[nf], acc[ah * 4 + j][nf], 0, 0, 0);
      __builtin_amdgcn_s_setprio(0);
      __builtin_amdgcn_s_barrier();
      __builtin_amdgcn_sched_barrier(0);
    }
    if (t + 1 < KT) {
      if (t + 2 < KT) asm volatile("s_waitcnt vmcnt(2)" ::: "memory");
      else            asm volatile("s_waitcnt vmcnt(0)" ::: "memory");
      __builtin_amdgcn_s_barrier();
      __builtin_amdgcn_sched_barrier(0);
    }
  }

#pragma unroll
  for (int mf = 0; mf < 8; ++mf) {
#pragma unroll
    for (int nf = 0; nf < 4; ++nf) {
      int col = n0 + wn * 64 + nf * 16 + ql;
      float bvl = bias[col];
#pragma unroll
      for (int r = 0; r < 4; ++r) {
        int rowg = m0 + wm * 128 + mf * 16 + g * 4 + r;
        float v = acc[mf][nf][r] + bvl;
        if (MODE == 2) v = 0.5f * v * (1.0f + erff(v * 0.70710678118654752f));
        if (MODE == 1) ((float*)out)[(size_t)rowg * Ndim + col] = v;
        else          ((__bf16*)out)[(size_t)rowg * Ndim + col] = (__bf16)v;
      }
    }
  }
}

template<int MODE>
__global__ __launch_bounds__(512)
void gemm256_kernel(const __bf16* __restrict__ A, const __bf16* __restrict__ Bt,
                    const float* __restrict__ bias, void* __restrict__ out,
                    int Ndim, int Kdim) {
  gemm256_body<MODE>(A, Bt, bias, out, Ndim, Kdim,
                     blockIdx.y * 256, blockIdx.x * 256);
}

struct QKVArgs {
  const __bf16* A[3]; const __bf16* Bt[3]; const float* bias[3]; __bf16* out[3];
};

__global__ __launch_bounds__(512)
void qkv256_kernel(QKVArgs args, int Ndim, int Kdim) {
  int z = blockIdx.z;
  gemm256_body<0>(args.A[z], args.Bt[z], args.bias[z], (void*)args.out[z],
                  Ndim, Kdim, blockIdx.y * 256, blockIdx.x * 256);
}

// --------------------------------------------------------- flash attention
// Round-9 skeleton + this round: (1) triple-buffered K/V, 2-tile lookahead,
// counted vmcnt {4,2,0}; (2) log2-domain softmax (mask pre-scaled by log2e,
// exp2f); (3) defer-max THR=8 (log2 units): skip rescale when
// __all(mx <= mrun+8); P <= 2^8, bf16-safe.
__global__ __launch_bounds__(512)
void attn_kernel(const __bf16* __restrict__ Qb, const __bf16* __restrict__ Kb,
                 const __bf16* __restrict__ Vt, const float* __restrict__ mask2,
                 __bf16* __restrict__ ctx) {
  __shared__ alignas(16) __bf16 Qs[128 * 64];        // 16 KB
  __shared__ alignas(16) __bf16 Ks[3 * 64 * 64];     // 24 KB (3-buf)
  __shared__ alignas(16) __bf16 Vs[3 * 64 * 64];     // 24 KB (3-buf)
  __shared__ alignas(16) __bf16 Ps[8 * 16 * 64];     // 16 KB  => 80 KB total

  const int tid  = threadIdx.x;
  const int lane = tid & 63;
  const int w    = tid >> 6;
  const int g    = lane >> 4;
  const int ql   = lane & 15;
  const int bh   = blockIdx.y;
  const int b    = bh >> 4;
  const int h    = bh & 15;
  const int q0   = blockIdx.x * 128;

  const size_t kbase  = ((size_t)(b * S_)) * D_ + h * DH_;
  const size_t vtbase = (size_t)bh * DH_ * S_;
  const int NT = S_ / 64;

  // stage Q + kv tiles 0,1
  const size_t qbase = ((size_t)(b * S_) + q0) * D_ + h * DH_;
#pragma unroll
  for (int i = 0; i < 2; ++i) {
    int o   = tid * 16 + i * 8192;
    int row = o >> 7, cb = o & 127;
    int cbs = cb ^ ((row & 7) << 4);
    gload_lds16((const char*)Qb + (qbase + (size_t)row * D_) * 2 + cbs, (char*)Qs + o);
  }
  {
    int o   = tid * 16;
    int row = o >> 7, cb = o & 127;
    int cbs = cb ^ ((row & 7) << 4);
    gload_lds16((const char*)Kb + (kbase + (size_t)row * D_) * 2 + cbs, (char*)Ks + o);
    gload_lds16((const char*)Vt + (vtbase + (size_t)row * S_) * 2 + cbs, (char*)Vs + o);
    gload_lds16((const char*)Kb + (kbase + (size_t)(64 + row) * D_) * 2 + cbs,
                (char*)Ks + 8192 + o);
    gload_lds16((const char*)Vt + (vtbase + (size_t)row * S_ + 64) * 2 + cbs,
                (char*)Vs + 8192 + o);
  }
  asm volatile("s_waitcnt vmcnt(2)" ::: "memory");   // Q + tile0 landed; tile1 in flight
  __builtin_amdgcn_s_barrier();
  __builtin_amdgcn_sched_barrier(0);

  bfx8 aq[2];
  {
    int row = w * 16 + ql;
#pragma unroll
    for (int kk = 0; kk < 2; ++kk) {
      int cb = kk * 64 + g * 16;
      aq[kk] = *(const bfx8*)((const char*)Qs + row * 128 + (cb ^ ((row & 7) << 4)));
    }
  }

  float mrun = -1e30f, lrun = 0.f;   // log2-domain running max
  fx4 acc[4];
#pragma unroll
  for (int d = 0; d < 4; ++d) acc[d] = {0.f, 0.f, 0.f, 0.f};

  char* pw = (char*)Ps + w * 2048;
  const float SCL = 0.18033688f;     // 0.125 * log2(e)

  for (int t = 0; t < NT; ++t) {
    const int kv0 = t * 64;
    if (t + 2 < NT) {                // stage tile t+2 into buf (t+2)%3
      int o   = tid * 16;
      int row = o >> 7, cb = o & 127;
      int cbs = cb ^ ((row & 7) << 4);
      int nkv = kv0 + 128;
      int bo  = ((t + 2) % 3) * 8192;
      gload_lds16((const char*)Kb + (kbase + (size_t)(nkv + row) * D_) * 2 + cbs,
                  (char*)Ks + bo + o);
      gload_lds16((const char*)Vt + (vtbase + (size_t)row * S_ + nkv) * 2 + cbs,
                  (char*)Vs + bo + o);
    }
    __builtin_amdgcn_sched_barrier(0);
    if (t > 0) {                     // drain tile t (tile0 drained in prologue)
      if (t + 2 < NT)      asm volatile("s_waitcnt vmcnt(4)" ::: "memory");
      else if (t + 1 < NT) asm volatile("s_waitcnt vmcnt(2)" ::: "memory");
      else                 asm volatile("s_waitcnt vmcnt(0)" ::: "memory");
      __builtin_amdgcn_s_barrier();
      __builtin_amdgcn_sched_barrier(0);
    }
    const char* Kc = (const char*)Ks + (t % 3) * 8192;
    const char* Vc = (const char*)Vs + (t % 3) * 8192;

    // swapped QK^T
    fx4 sc[4];
#pragma unroll
    for (int nf = 0; nf < 4; ++nf) sc[nf] = {0.f, 0.f, 0.f, 0.f};
#pragma unroll
    for (int kk = 0; kk < 2; ++kk) {
      const int cb = kk * 64 + g * 16;
      bfx8 bk[4];
#pragma unroll
      for (int nf = 0; nf < 4; ++nf) {
        int row = nf * 16 + ql;
        bk[nf] = *(const bfx8*)(Kc + row * 128 + (cb ^ ((row & 7) << 4)));
      }
#pragma unroll
      for (int nf = 0; nf < 4; ++nf)
        sc[nf] = __builtin_amdgcn_mfma_f32_16x16x32_bf16(bk[nf], aq[kk], sc[nf], 0, 0, 0);
    }

    // log2-domain scale + pre-scaled mask
    float sv[4][4];
#pragma unroll
    for (int nf = 0; nf < 4; ++nf) {
      float4 mk = *(const float4*)(mask2 + b * S_ + kv0 + nf * 16 + g * 4);
      sv[nf][0] = sc[nf][0] * SCL + mk.x;
      sv[nf][1] = sc[nf][1] * SCL + mk.y;
      sv[nf][2] = sc[nf][2] * SCL + mk.z;
      sv[nf][3] = sc[nf][3] * SCL + mk.w;
    }
    float mx = fmaxf(fmaxf(fmaxf(sv[0][0], sv[0][1]), fmaxf(sv[0][2], sv[0][3])),
                     fmaxf(fmaxf(sv[1][0], sv[1][1]), fmaxf(sv[1][2], sv[1][3])));
    mx = fmaxf(mx, fmaxf(fmaxf(fmaxf(sv[2][0], sv[2][1]), fmaxf(sv[2][2], sv[2][3])),
                         fmaxf(fmaxf(sv[3][0], sv[3][1]), fmaxf(sv[3][2], sv[3][3]))));
    mx = fmaxf(mx, __shfl_xor(mx, 16));
    mx = fmaxf(mx, __shfl_xor(mx, 32));

    // defer-max: only rescale when tile max exceeds running max + 8 (log2)
    if (!__all(mx <= mrun + 8.0f)) {
      float mnew  = fmaxf(mrun, mx);
      float alpha = exp2f(mrun - mnew);
      lrun *= alpha;
      float af[4];
#pragma unroll
      for (int r = 0; r < 4; ++r) af[r] = __shfl(alpha, g * 4 + r);
#pragma unroll
      for (int d = 0; d < 4; ++d)
#pragma unroll
        for (int r = 0; r < 4; ++r) acc[d][r] *= af[r];
      mrun = mnew;
    }

    float rs = 0.f;
#pragma unroll
    for (int nf = 0; nf < 4; ++nf)
#pragma unroll
      for (int r = 0; r < 4; ++r) {
        float p = exp2f(sv[nf][r] - mrun);
        sv[nf][r] = p; rs += p;
      }
    rs += __shfl_xor(rs, 16);
    rs += __shfl_xor(rs, 32);
    lrun += rs;

    // write P strip row ql (vector bfx4)
#pragma unroll
    for (int nf = 0; nf < 4; ++nf) {
      bfx4 pv;
      pv[0] = (__bf16)sv[nf][0]; pv[1] = (__bf16)sv[nf][1];
      pv[2] = (__bf16)sv[nf][2]; pv[3] = (__bf16)sv[nf][3];
      int c = (nf * 32 + g * 8) ^ ((ql & 7) << 4);
      *(bfx4*)(pw + ql * 128 + c) = pv;
    }

    // fence: P-strip writes complete + no compiler motion of PV reads above
    asm volatile("s_waitcnt lgkmcnt(0)" ::: "memory");
    __builtin_amdgcn_sched_barrier(0);

    // PV
#pragma unroll
    for (int kk = 0; kk < 2; ++kk) {
      int prow = ql;
      int cb   = kk * 64 + g * 16;
      bfx8 ap  = *(const bfx8*)((const char*)pw + prow * 128 + (cb ^ ((prow & 7) << 4)));
#pragma unroll
      for (int d = 0; d < 4; ++d) {
        int vrow = d * 16 + ql;
        bfx8 bv  = *(const bfx8*)(Vc + vrow * 128 + (cb ^ ((vrow & 7) << 4)));
        acc[d] = __builtin_amdgcn_mfma_f32_16x16x32_bf16(ap, bv, acc[d], 0, 0, 0);
      }
    }

    __builtin_amdgcn_s_barrier();        // all reads of buf t%3 retired
    __builtin_amdgcn_sched_barrier(0);
  }

  float linv = 1.0f / lrun;
#pragma unroll
  for (int r = 0; r < 4; ++r) {
    float inv = __shfl(linv, g * 4 + r);
    int qrow = q0 + w * 16 + g * 4 + r;
    size_t base = ((size_t)(b * S_) + qrow) * D_ + h * DH_;
#pragma unroll
    for (int d = 0; d < 4; ++d)
      ctx[base + d * 16 + ql] = (__bf16)(acc[d][r] * inv);
  }
}

// -------------------------------------------- residual + LayerNorm (row=1024)
template<bool WRITE_BF16>
__global__ __launch_bounds__(256)
void ln_kernel(const float* __restrict__ a, const float* __restrict__ b,
               const float* __restrict__ g, const float* __restrict__ beta,
               float* __restrict__ outf, __bf16* __restrict__ outb) {
  const int row = blockIdx.x;
  const int tid = threadIdx.x;
  const size_t base = (size_t)row * D_;
  float4 xa = *(const float4*)(a + base + tid * 4);
  float4 xb = *(const float4*)(b + base + tid * 4);
  float x[4] = {xa.x + xb.x, xa.y + xb.y, xa.z + xb.z, xa.w + xb.w};
  float s = x[0] + x[1] + x[2] + x[3];
#pragma unroll
  for (int m = 1; m < 64; m <<= 1) s += __shfl_xor(s, m);
  __shared__ float red[8];
  if ((tid & 63) == 0) red[tid >> 6] = s;
  __syncthreads();
  float mu = (red[0] + red[1] + red[2] + red[3]) * (1.0f / D_);
  float v0 = 0.f;
#pragma unroll
  for (int i = 0; i < 4; ++i) { float d = x[i] - mu; v0 += d * d; }
#pragma unroll
  for (int m = 1; m < 64; m <<= 1) v0 += __shfl_xor(v0, m);
  if ((tid & 63) == 0) red[4 + (tid >> 6)] = v0;
  __syncthreads();
  float var = (red[4] + red[5] + red[6] + red[7]) * (1.0f / D_);
  float rs = rsqrtf(var + 1e-12f);
#pragma unroll
  for (int i = 0; i < 4; ++i) {
    int col = tid * 4 + i;
    x[i] = (x[i] - mu) * rs * g[col] + beta[col];
  }
  *(float4*)(outf + base + tid * 4) = make_float4(x[0], x[1], x[2], x[3]);
  if (WRITE_BF16) {
    bfx4 o;
    o[0] = (__bf16)x[0]; o[1] = (__bf16)x[1]; o[2] = (__bf16)x[2]; o[3] = (__bf16)x[3];
    *(bfx4*)(outb + base + tid * 4) = o;
  }
}

// ---------------------------------------------------------------- launch
extern "C" void kernel_launch(void* const* d_in, const int* in_sizes, int n_in,
                              void* d_out, int out_size, void* d_ws, size_t ws_size,
                              hipStream_t stream) {
  const float* query    = (const float*)d_in[0];
  const float* key_in   = (const float*)d_in[1];
  const float* value_in = (const float*)d_in[2];
  const float* mask     = (const float*)d_in[3];
  const float* Wq = (const float*)d_in[4];  const float* bq = (const float*)d_in[5];
  const float* Wk = (const float*)d_in[6];  const float* bk = (const float*)d_in[7];
  const float* Wv = (const float*)d_in[8];  const float* bv = (const float*)d_in[9];
  const float* Wo = (const float*)d_in[10]; const float* bo = (const float*)d_in[11];
  const float* ln1g = (const float*)d_in[12]; const float* ln1b = (const float*)d_in[13];
  const float* Wi = (const float*)d_in[14]; const float* bi = (const float*)d_in[15];
  const float* Wd = (const float*)d_in[16]; const float* bd = (const float*)d_in[17];
  const float* ln2g = (const float*)d_in[18]; const float* ln2b = (const float*)d_in[19];

  char* ws = (char*)d_ws;
  const size_t MB = 1ull << 20;
  if (ws_size < 112 * MB) return;

  __bf16* xq   = (__bf16*)(ws + 0 * MB);
  __bf16* xk   = (__bf16*)(ws + 8 * MB);
  __bf16* xv   = (__bf16*)(ws + 16 * MB);
  float*  alin = (float*)(ws + 0 * MB);
  float*  mask2= (float*)(ws + 0 * MB);     // written AFTER qkv256 (xq dead),
                                            // dead before Wo writes alin
  __bf16* x1b  = (__bf16*)(ws + 16 * MB);
  __bf16* qb   = (__bf16*)(ws + 24 * MB);
  __bf16* kb   = (__bf16*)(ws + 32 * MB);
  __bf16* vb   = (__bf16*)(ws + 40 * MB);
  __bf16* vt   = (__bf16*)(ws + 48 * MB);
  __bf16* inter= (__bf16*)(ws + 24 * MB);
  __bf16* ctxb = (__bf16*)(ws + 56 * MB);
  float*  ff   = (float*)(ws + 56 * MB);
  float*  x1f  = (float*)(ws + 72 * MB);
  __bf16* wqt  = (__bf16*)(ws + 88 * MB);
  __bf16* wkt  = (__bf16*)(ws + 90 * MB);
  __bf16* wvt  = (__bf16*)(ws + 92 * MB);
  __bf16* wot  = (__bf16*)(ws + 94 * MB);
  __bf16* wit  = (__bf16*)(ws + 96 * MB);
  __bf16* wdt  = (__bf16*)(ws + 104 * MB);

  dim3 b256(256);
  dim3 tblk(32, 8);
  const int n1 = M_ * D_;

  to_bf16_kernel<<<dim3(n1 / 1024), b256, 0, stream>>>(query, xq, n1);
  to_bf16_kernel<<<dim3(n1 / 1024), b256, 0, stream>>>(key_in, xk, n1);
  to_bf16_kernel<<<dim3(n1 / 1024), b256, 0, stream>>>(value_in, xv, n1);

  transpose_conv_kernel<<<dim3(D_ / 32, D_ / 32), tblk, 0, stream>>>(Wq, wqt, D_, D_);
  transpose_conv_kernel<<<dim3(D_ / 32, D_ / 32), tblk, 0, stream>>>(Wk, wkt, D_, D_);
  transpose_conv_kernel<<<dim3(D_ / 32, D_ / 32), tblk, 0, stream>>>(Wv, wvt, D_, D_);
  transpose_conv_kernel<<<dim3(D_ / 32, D_ / 32), tblk, 0, stream>>>(Wo, wot, D_, D_);
  transpose_conv_kernel<<<dim3(DFF_ / 32, D_ / 32), tblk, 0, stream>>>(Wi, wit, D_, DFF_);
  transpose_conv_kernel<<<dim3(D_ / 32, DFF_ / 32), tblk, 0, stream>>>(Wd, wdt, DFF_, D_);

  QKVArgs qa;
  qa.A[0] = xq;  qa.A[1] = xk;  qa.A[2] = xv;
  qa.Bt[0] = wqt; qa.Bt[1] = wkt; qa.Bt[2] = wvt;
  qa.bias[0] = bq; qa.bias[1] = bk; qa.bias[2] = bv;
  qa.out[0] = qb; qa.out[1] = kb; qa.out[2] = vb;
  qkv256_kernel<<<dim3(D_ / 256, M_ / 256, 3), dim3(512), 131072, stream>>>(qa, D_, D_);

  transpose_v_kernel<<<dim3(S_ / 32, 2, B_ * H_), tblk, 0, stream>>>(vb, vt);

  scale_mask_kernel<<<dim3((B_ * S_ + 255) / 256), b256, 0, stream>>>(mask, mask2, B_ * S_);

  attn_kernel<<<dim3(S_ / 128, B_ * H_), dim3(512), 0, stream>>>(qb, kb, vt, mask2, ctxb);

  gemm_kernel<1, 64><<<dim3(D_ / 64, M_ / 128), b256, 0, stream>>>(ctxb, wot, bo, (void*)alin, D_, D_);

  ln_kernel<true><<<dim3(M_), b256, 0, stream>>>(alin, query, ln1g, ln1b, x1f, x1b);

  gemm256_kernel<2><<<dim3(DFF_ / 256, M_ / 256), dim3(512), 131072, stream>>>(x1b, wit, bi, (void*)inter, DFF_, D_);

  gemm_kernel<1, 64><<<dim3(D_ / 64, M_ / 128), b256, 0, stream>>>(inter, wdt, bd, (void*)ff, D_, DFF_);

  ln_kernel<false><<<dim3(M_), b256, 0, stream>>>(ff, x1f, ln2g, ln2b, (float*)d_out, nullptr);
}

// Round 11
// 292.362 us; speedup vs baseline: 1.0494x; 1.0494x over previous
//
#include <hip/hip_runtime.h>
#include <hip/hip_bf16.h>
#include <cmath>

#define B_   2
#define S_   2048
#define D_   1024
#define H_   16
#define DFF_ 4096
#define DH_  64
#define M_   (B_*S_)   // 4096 rows

typedef __bf16 bfx8 __attribute__((ext_vector_type(8)));
typedef __bf16 bfx4 __attribute__((ext_vector_type(4)));
typedef float  fx4  __attribute__((ext_vector_type(4)));

__device__ __forceinline__ float fast_exp2(float x) {
  float r;
  asm volatile("v_exp_f32 %0, %1" : "=v"(r) : "v"(x));
  return r;
}

// ---------------------------------------------------------------- utilities
__device__ __forceinline__ void gload_lds16(const void* g, void* l) {
  __builtin_amdgcn_global_load_lds((__attribute__((address_space(1))) void*)(g),
                                   (__attribute__((address_space(3))) void*)(l),
                                   16, 0, 0);
}

// ------------------------------------------------------------- fp32 -> bf16
__global__ __launch_bounds__(256)
void to_bf16_kernel(const float* __restrict__ in, __bf16* __restrict__ out, int n) {
  int i = (blockIdx.x * 256 + threadIdx.x) * 4;
  if (i < n) {
    float4 v = *(const float4*)(in + i);
    bfx4 o;
    o[0] = (__bf16)v.x; o[1] = (__bf16)v.y; o[2] = (__bf16)v.z; o[3] = (__bf16)v.w;
    *(bfx4*)(out + i) = o;
  }
}

// ------------------------------------------------ mask * log2(e) (tiny)
__global__ __launch_bounds__(256)
void scale_mask_kernel(const float* __restrict__ in, float* __restrict__ out, int n) {
  int i = blockIdx.x * 256 + threadIdx.x;
  if (i < n) out[i] = in[i] * 1.44269504f;
}

// --------------------------------------- W [R][C] f32 -> Wt [C][R] bf16
__global__ __launch_bounds__(256)
void transpose_conv_kernel(const float* __restrict__ in, __bf16* __restrict__ out,
                           int R, int C) {
  __shared__ float t[32][33];
  int r0 = blockIdx.y * 32, c0 = blockIdx.x * 32;
  int tx = threadIdx.x, ty = threadIdx.y;   // 32 x 8
#pragma unroll
  for (int j = 0; j < 4; ++j) {
    int r = ty + j * 8;
    t[r][tx] = in[(size_t)(r0 + r) * C + c0 + tx];
  }
  __syncthreads();
#pragma unroll
  for (int j = 0; j < 4; ++j) {
    int c = ty + j * 8;
    out[(size_t)(c0 + c) * R + r0 + tx] = (__bf16)t[tx][c];
  }
}

// ----------------------- V [B,S,H,DH] bf16 -> Vt [B,H,DH,S] bf16
__global__ __launch_bounds__(256)
void transpose_v_kernel(const __bf16* __restrict__ vb, __bf16* __restrict__ vt) {
  __shared__ __bf16 t[32][33];
  int bh = blockIdx.z;
  int b = bh >> 4, h = bh & 15;
  int s0 = blockIdx.x * 32, d0 = blockIdx.y * 32;
  int tx = threadIdx.x, ty = threadIdx.y;
#pragma unroll
  for (int j = 0; j < 4; ++j) {
    int s = ty + j * 8;
    t[s][tx] = vb[(size_t)((b * S_ + s0 + s) * H_ + h) * DH_ + d0 + tx];
  }
  __syncthreads();
#pragma unroll
  for (int j = 0; j < 4; ++j) {
    int d = ty + j * 8;
    vt[(size_t)(bh * DH_ + d0 + d) * S_ + s0 + tx] = t[tx][d];
  }
}

// --------------------------------------------------------------- GEMM 128-tile
template<int MODE, int TBN>
__device__ __forceinline__ void gemm_body(const __bf16* __restrict__ A,
                                          const __bf16* __restrict__ Bt,
                                          const float* __restrict__ bias,
                                          void* __restrict__ out,
                                          int Ndim, int Kdim,
                                          int m0, int n0,
                                          __bf16* As, __bf16* Bs) {
  const int tid  = threadIdx.x;
  const int lane = tid & 63;
  const int w    = tid >> 6;
  const int wm   = w >> 1, wn = w & 1;
  constexpr int NF = TBN / 32;

  fx4 acc[4][NF];
#pragma unroll
  for (int i = 0; i < 4; ++i)
#pragma unroll
    for (int j = 0; j < NF; ++j) acc[i][j] = {0.f, 0.f, 0.f, 0.f};

  const int KT = Kdim / 64;
  for (int kt = 0; kt < KT; ++kt) {
    __syncthreads();
    const int kb0 = kt * 64;
#pragma unroll
    for (int i = 0; i < 4; ++i) {
      int o   = tid * 16 + i * 4096;
      int row = o >> 7, cb = o & 127;
      int cbs = cb ^ ((row & 7) << 4);
      gload_lds16((const char*)A + ((size_t)(m0 + row) * Kdim + kb0) * 2 + cbs,
                  (char*)As + o);
    }
#pragma unroll
    for (int i = 0; i < TBN / 32; ++i) {
      int o   = tid * 16 + i * 4096;
      int row = o >> 7, cb = o & 127;
      int cbs = cb ^ ((row & 7) << 4);
      gload_lds16((const char*)Bt + ((size_t)(n0 + row) * Kdim + kb0) * 2 + cbs,
                  (char*)Bs + o);
    }
    __syncthreads();

#pragma unroll
    for (int kk = 0; kk < 2; ++kk) {
      bfx8 afr[4], bfr[NF];
      const int cb = kk * 64 + ((lane >> 4) << 4);
#pragma unroll
      for (int mf = 0; mf < 4; ++mf) {
        int row = wm * 64 + mf * 16 + (lane & 15);
        afr[mf] = *(const bfx8*)((const char*)As + row * 128 + (cb ^ ((row & 7) << 4)));
      }
#pragma unroll
      for (int nf = 0; nf < NF; ++nf) {
        int row = wn * (TBN / 2) + nf * 16 + (lane & 15);
        bfr[nf] = *(const bfx8*)((const char*)Bs + row * 128 + (cb ^ ((row & 7) << 4)));
      }
#pragma unroll
      for (int mf = 0; mf < 4; ++mf)
#pragma unroll
        for (int nf = 0; nf < NF; ++nf)
          acc[mf][nf] = __builtin_amdgcn_mfma_f32_16x16x32_bf16(afr[mf], bfr[nf],
                                                                acc[mf][nf], 0, 0, 0);
    }
  }

#pragma unroll
  for (int mf = 0; mf < 4; ++mf) {
#pragma unroll
    for (int nf = 0; nf < NF; ++nf) {
      int col = n0 + wn * (TBN / 2) + nf * 16 + (lane & 15);
      float bvl = bias[col];
#pragma unroll
      for (int r = 0; r < 4; ++r) {
        int rowg = m0 + wm * 64 + mf * 16 + ((lane >> 4) << 2) + r;
        float v = acc[mf][nf][r] + bvl;
        if (MODE == 2) v = 0.5f * v * (1.0f + erff(v * 0.70710678118654752f));
        if (MODE == 1) ((float*)out)[(size_t)rowg * Ndim + col] = v;
        else          ((__bf16*)out)[(size_t)rowg * Ndim + col] = (__bf16)v;
      }
    }
  }
}

template<int MODE, int TBN>
__global__ __launch_bounds__(256)
void gemm_kernel(const __bf16* __restrict__ A, const __bf16* __restrict__ Bt,
                 const float* __restrict__ bias, void* __restrict__ out,
                 int Ndim, int Kdim) {
  __shared__ alignas(16) __bf16 As[128 * 64];
  __shared__ alignas(16) __bf16 Bs[TBN * 64];
  gemm_body<MODE, TBN>(A, Bt, bias, out, Ndim, Kdim,
                       blockIdx.y * 128, blockIdx.x * TBN, As, Bs);
}

// --------------------------------------------------------------- GEMM 256-tile
// (round-9 validated 8-phase schedule, unchanged)
__device__ __forceinline__ void stage_a256(const __bf16* __restrict__ A, int m0,
                                           int Kdim, int tile, int h, char* Asm) {
  char* dst = Asm + (tile & 1) * 32768;
  const int kb0 = tile * 64;
  const int tid = threadIdx.x;
#pragma unroll
  for (int it = 0; it < 2; ++it) {
    int o = tid * 16 + it * 8192;
    int lrow = o >> 7, cb = o & 127;
    int r = (lrow & 63) + h * 64 + ((lrow >> 6) << 7);
    int csrc = cb ^ ((r & 7) << 4);
    gload_lds16((const char*)A + ((size_t)(m0 + r) * Kdim + kb0) * 2 + csrc,
                dst + r * 128 + cb);
  }
}
__device__ __forceinline__ void stage_b256(const __bf16* __restrict__ Bt, int n0,
                                           int Kdim, int tile, int h, char* Bsm) {
  char* dst = Bsm + (tile & 1) * 32768;
  const int kb0 = tile * 64;
  const int tid = threadIdx.x;
#pragma unroll
  for (int it = 0; it < 2; ++it) {
    int o = tid * 16 + it * 8192;
    int lrow = o >> 7, cb = o & 127;
    int r = h * 128 + lrow;
    int csrc = cb ^ ((r & 7) << 4);
    gload_lds16((const char*)Bt + ((size_t)(n0 + r) * Kdim + kb0) * 2 + csrc,
                dst + r * 128 + cb);
  }
}

template<int MODE>
__device__ __forceinline__ void gemm256_body(const __bf16* __restrict__ A,
                                             const __bf16* __restrict__ Bt,
                                             const float* __restrict__ bias,
                                             void* __restrict__ out,
                                             int Ndim, int Kdim, int m0, int n0) {
  extern __shared__ char smem[];
  char* Asm = smem;
  char* Bsm = smem + 65536;
  const int tid  = threadIdx.x;
  const int lane = tid & 63;
  const int w    = tid >> 6;
  const int wm   = w >> 2;
  const int wn   = w & 3;
  const int g    = lane >> 4;
  const int ql   = lane & 15;
  const int KT   = Kdim / 64;

  fx4 acc[8][4];
#pragma unroll
  for (int i = 0; i < 8; ++i)
#pragma unroll
    for (int j = 0; j < 4; ++j) acc[i][j] = {0.f, 0.f, 0.f, 0.f};

  stage_a256(A, m0, Kdim, 0, 0, Asm);
  stage_a256(A, m0, Kdim, 0, 1, Asm);
  stage_b256(Bt, n0, Kdim, 0, 0, Bsm);
  stage_b256(Bt, n0, Kdim, 0, 1, Bsm);
  stage_a256(A, m0, Kdim, 1, 0, Asm);
  asm volatile("s_waitcnt vmcnt(2)" ::: "memory");
  __builtin_amdgcn_s_barrier();
  __builtin_amdgcn_sched_barrier(0);

  for (int t = 0; t < KT; ++t) {
    const char* Ab = Asm + (t & 1) * 32768;
    const char* Bb = Bsm + (t & 1) * 32768;
#pragma unroll
    for (int p = 0; p < 4; ++p) {
      const int ah = p >> 1, kk = p & 1;
      if (p == 0 && t + 1 < KT) stage_a256(A, m0, Kdim, t + 1, 1, Asm);
      if (p == 1 && t + 1 < KT) stage_b256(Bt, n0, Kdim, t + 1, 0, Bsm);
      if (p == 2 && t + 1 < KT) stage_b256(Bt, n0, Kdim, t + 1, 1, Bsm);
      if (p == 3 && t + 2 < KT) stage_a256(A, m0, Kdim, t + 2, 0, Asm);
      __builtin_amdgcn_sched_barrier(0);

      bfx8 af[4], bf[4];
      const int cbv = kk * 64 + g * 16;
#pragma unroll
      for (int j = 0; j < 4; ++j) {
        int arow = wm * 128 + (ah * 4 + j) * 16 + ql;
        af[j] = *(const bfx8*)(Ab + arow * 128 + (cbv ^ ((arow & 7) << 4)));
      }
#pragma unroll
      for (int nf = 0; nf < 4; ++nf) {
        int brow = wn * 64 + nf * 16 + ql;
        bf[nf] = *(const bfx8*)(Bb + brow * 128 + (cbv ^ ((brow & 7) << 4)));
      }
      __builtin_amdgcn_sched_barrier(0);
      __builtin_amdgcn_s_barrier();
      asm volatile("s_waitcnt lgkmcnt(0)" ::: "memory");
      __builtin_amdgcn_sched_barrier(0);
      __builtin_amdgcn_s_setprio(1);
#pragma unroll
      for (int j = 0; j < 4; ++j)
#pragma unroll
        for (int nf = 0; nf < 4; ++nf)
          acc[ah * 4 + j][nf] = __builtin_amdgcn_mfma_f32_16x16x32_bf16(
              af[j], bf[nf], acc[ah * 4 + j][nf], 0, 0, 0);
      __builtin_amdgcn_s_setprio(0);
      __builtin_amdgcn_s_barrier();
      __builtin_amdgcn_sched_barrier(0);
    }
    if (t + 1 < KT) {
      if (t + 2 < KT) asm volatile("s_waitcnt vmcnt(2)" ::: "memory");
      else            asm volatile("s_waitcnt vmcnt(0)" ::: "memory");
      __builtin_amdgcn_s_barrier();
      __builtin_amdgcn_sched_barrier(0);
    }
  }

#pragma unroll
  for (int mf = 0; mf < 8; ++mf) {
#pragma unroll
    for (int nf = 0; nf < 4; ++nf) {
      int col = n0 + wn * 64 + nf * 16 + ql;
      float bvl = bias[col];
#pragma unroll
      for (int r = 0; r < 4; ++r) {
        int rowg = m0 + wm * 128 + mf * 16 + g * 4 + r;
        float v = acc[mf][nf][r] + bvl;
        if (MODE == 2) v = 0.5f * v * (1.0f + erff(v * 0.70710678118654752f));
        if (MODE == 1) ((float*)out)[(size_t)rowg * Ndim + col] = v;
        else          ((__bf16*)out)[(size_t)rowg * Ndim + col] = (__bf16)v;
      }
    }
  }
}

template<int MODE>
__global__ __launch_bounds__(512)
void gemm256_kernel(const __bf16* __restrict__ A, const __bf16* __restrict__ Bt,
                    const float* __restrict__ bias, void* __restrict__ out,
                    int Ndim, int Kdim) {
  gemm256_body<MODE>(A, Bt, bias, out, Ndim, Kdim,
                     blockIdx.y * 256, blockIdx.x * 256);
}

struct QKVArgs {
  const __bf16* A[3]; const __bf16* Bt[3]; const float* bias[3]; __bf16* out[3];
};

__global__ __launch_bounds__(512)
void qkv256_kernel(QKVArgs args, int Ndim, int Kdim) {
  int z = blockIdx.z;
  gemm256_body<0>(args.A[z], args.Bt[z], args.bias[z], (void*)args.out[z],
                  Ndim, Kdim, blockIdx.y * 256, blockIdx.x * 256);
}

// --------------------------------------------------------- flash attention
// Round-8 skeleton VERBATIM (dbuf K/V, vmcnt(2), proven 77.9us) + softmax
// diet only: log2-domain (mask pre-scaled by log2e), single-instruction
// v_exp_f32 (not libm exp2f), defer-max THR=8 (skip rescale when
// __all(mx <= mrun+8); P <= 2^8, bf16-safe).
__global__ __launch_bounds__(512)
void attn_kernel(const __bf16* __restrict__ Qb, const __bf16* __restrict__ Kb,
                 const __bf16* __restrict__ Vt, const float* __restrict__ mask2,
                 __bf16* __restrict__ ctx) {
  __shared__ alignas(16) __bf16 Qs[128 * 64];        // 16 KB
  __shared__ alignas(16) __bf16 Ks[2 * 64 * 64];     // 16 KB (dbuf)
  __shared__ alignas(16) __bf16 Vs[2 * 64 * 64];     // 16 KB (dbuf)
  __shared__ alignas(16) __bf16 Ps[8 * 16 * 64];     // 16 KB

  const int tid  = threadIdx.x;
  const int lane = tid & 63;
  const int w    = tid >> 6;
  const int g    = lane >> 4;
  const int ql   = lane & 15;
  const int bh   = blockIdx.y;
  const int b    = bh >> 4;
  const int h    = bh & 15;
  const int q0   = blockIdx.x * 128;

  const size_t kbase  = ((size_t)(b * S_)) * D_ + h * DH_;
  const size_t vtbase = (size_t)bh * DH_ * S_;

  const size_t qbase = ((size_t)(b * S_) + q0) * D_ + h * DH_;
#pragma unroll
  for (int i = 0; i < 2; ++i) {
    int o   = tid * 16 + i * 8192;
    int row = o >> 7, cb = o & 127;
    int cbs = cb ^ ((row & 7) << 4);
    gload_lds16((const char*)Qb + (qbase + (size_t)row * D_) * 2 + cbs, (char*)Qs + o);
  }
  {
    int o   = tid * 16;
    int row = o >> 7, cb = o & 127;
    int cbs = cb ^ ((row & 7) << 4);
    gload_lds16((const char*)Kb + (kbase + (size_t)row * D_) * 2 + cbs, (char*)Ks + o);
    gload_lds16((const char*)Vt + (vtbase + (size_t)row * S_) * 2 + cbs, (char*)Vs + o);
  }
  __syncthreads();   // full drain: Q + tile0 landed

  bfx8 aq[2];
  {
    int row = w * 16 + ql;
#pragma unroll
    for (int kk = 0; kk < 2; ++kk) {
      int cb = kk * 64 + g * 16;
      aq[kk] = *(const bfx8*)((const char*)Qs + row * 128 + (cb ^ ((row & 7) << 4)));
    }
  }

  float mrun = -1e30f, lrun = 0.f;   // log2-domain running stats
  fx4 acc[4];
#pragma unroll
  for (int d = 0; d < 4; ++d) acc[d] = {0.f, 0.f, 0.f, 0.f};

  char* pw = (char*)Ps + w * 2048;
  const int NT = S_ / 64;
  const float SCL = 0.18033688f;     // 0.125 * log2(e)

  for (int t = 0; t < NT; ++t) {
    const int kv0 = t * 64;
    if (t < NT - 1) {
      int o   = tid * 16;
      int row = o >> 7, cb = o & 127;
      int cbs = cb ^ ((row & 7) << 4);
      int nkv = kv0 + 64;
      gload_lds16((const char*)Kb + (kbase + (size_t)(nkv + row) * D_) * 2 + cbs,
                  (char*)Ks + ((t + 1) & 1) * 8192 + o);
      gload_lds16((const char*)Vt + (vtbase + (size_t)row * S_ + nkv) * 2 + cbs,
                  (char*)Vs + ((t + 1) & 1) * 8192 + o);
    }
    __builtin_amdgcn_sched_barrier(0);
    if (t > 0) {
      if (t < NT - 1) asm volatile("s_waitcnt vmcnt(2)" ::: "memory");
      else            asm volatile("s_waitcnt vmcnt(0)" ::: "memory");
      __builtin_amdgcn_s_barrier();
      __builtin_amdgcn_sched_barrier(0);
    }
    const char* Kc = (const char*)Ks + (t & 1) * 8192;
    const char* Vc = (const char*)Vs + (t & 1) * 8192;

    // swapped QK^T: sc[nf] lane holds S[kv = nf*16+g*4+r][q = w*16+ql]
    fx4 sc[4];
#pragma unroll
    for (int nf = 0; nf < 4; ++nf) sc[nf] = {0.f, 0.f, 0.f, 0.f};
#pragma unroll
    for (int kk = 0; kk < 2; ++kk) {
      const int cb = kk * 64 + g * 16;
      bfx8 bk[4];
#pragma unroll
      for (int nf = 0; nf < 4; ++nf) {
        int row = nf * 16 + ql;
        bk[nf] = *(const bfx8*)(Kc + row * 128 + (cb ^ ((row & 7) << 4)));
      }
#pragma unroll
      for (int nf = 0; nf < 4; ++nf)
        sc[nf] = __builtin_amdgcn_mfma_f32_16x16x32_bf16(bk[nf], aq[kk], sc[nf], 0, 0, 0);
    }

    // log2-domain scale + pre-scaled mask
    float sv[4][4];
#pragma unroll
    for (int nf = 0; nf < 4; ++nf) {
      float4 mk = *(const float4*)(mask2 + b * S_ + kv0 + nf * 16 + g * 4);
      sv[nf][0] = sc[nf][0] * SCL + mk.x;
      sv[nf][1] = sc[nf][1] * SCL + mk.y;
      sv[nf][2] = sc[nf][2] * SCL + mk.z;
      sv[nf][3] = sc[nf][3] * SCL + mk.w;
    }
    float mx = sv[0][0];
#pragma unroll
    for (int nf = 0; nf < 4; ++nf)
#pragma unroll
      for (int r = 0; r < 4; ++r) mx = fmaxf(mx, sv[nf][r]);
    mx = fmaxf(mx, __shfl_xor(mx, 16));
    mx = fmaxf(mx, __shfl_xor(mx, 32));

    // defer-max: rescale only when tile max exceeds running max + 8 (log2)
    if (!__all(mx <= mrun + 8.0f)) {
      float mnew  = fmaxf(mrun, mx);
      float alpha = fast_exp2(mrun - mnew);
      lrun *= alpha;
      float af[4];
#pragma unroll
      for (int r = 0; r < 4; ++r) af[r] = __shfl(alpha, g * 4 + r);
#pragma unroll
      for (int d = 0; d < 4; ++d)
#pragma unroll
        for (int r = 0; r < 4; ++r) acc[d][r] *= af[r];
      mrun = mnew;
    }

    float rs = 0.f;
#pragma unroll
    for (int nf = 0; nf < 4; ++nf)
#pragma unroll
      for (int r = 0; r < 4; ++r) {
        float p = fast_exp2(sv[nf][r] - mrun);
        sv[nf][r] = p; rs += p;
      }
    rs += __shfl_xor(rs, 16);
    rs += __shfl_xor(rs, 32);
    lrun += rs;

    // write P strip row ql (vector bfx4)
#pragma unroll
    for (int nf = 0; nf < 4; ++nf) {
      bfx4 pv;
      pv[0] = (__bf16)sv[nf][0]; pv[1] = (__bf16)sv[nf][1];
      pv[2] = (__bf16)sv[nf][2]; pv[3] = (__bf16)sv[nf][3];
      int c = (nf * 32 + g * 8) ^ ((ql & 7) << 4);
      *(bfx4*)(pw + ql * 128 + c) = pv;
    }

    // fence: P-strip writes complete + no compiler motion of PV reads above
    asm volatile("s_waitcnt lgkmcnt(0)" ::: "memory");
    __builtin_amdgcn_sched_barrier(0);

    // PV
#pragma unroll
    for (int kk = 0; kk < 2; ++kk) {
      int prow = ql;
      int cb   = kk * 64 + g * 16;
      bfx8 ap  = *(const bfx8*)((const char*)pw + prow * 128 + (cb ^ ((prow & 7) << 4)));
#pragma unroll
      for (int d = 0; d < 4; ++d) {
        int vrow = d * 16 + ql;
        bfx8 bv  = *(const bfx8*)(Vc + vrow * 128 + (cb ^ ((vrow & 7) << 4)));
        acc[d] = __builtin_amdgcn_mfma_f32_16x16x32_bf16(ap, bv, acc[d], 0, 0, 0);
      }
    }

    __builtin_amdgcn_s_barrier();
    __builtin_amdgcn_sched_barrier(0);
  }

  float linv = 1.0f / lrun;
#pragma unroll
  for (int r = 0; r < 4; ++r) {
    float inv = __shfl(linv, g * 4 + r);
    int qrow = q0 + w * 16 + g * 4 + r;
    size_t base = ((size_t)(b * S_) + qrow) * D_ + h * DH_;
#pragma unroll
    for (int d = 0; d < 4; ++d)
      ctx[base + d * 16 + ql] = (__bf16)(acc[d][r] * inv);
  }
}

// -------------------------------------------- residual + LayerNorm (row=1024)
template<bool WRITE_BF16>
__global__ __launch_bounds__(256)
void ln_kernel(const float* __restrict__ a, const float* __restrict__ b,
               const float* __restrict__ g, const float* __restrict__ beta,
               float* __restrict__ outf, __bf16* __restrict__ outb) {
  const int row = blockIdx.x;
  const int tid = threadIdx.x;
  const size_t base = (size_t)row * D_;
  float4 xa = *(const float4*)(a + base + tid * 4);
  float4 xb = *(const float4*)(b + base + tid * 4);
  float x[4] = {xa.x + xb.x, xa.y + xb.y, xa.z + xb.z, xa.w + xb.w};
  float s = x[0] + x[1] + x[2] + x[3];
#pragma unroll
  for (int m = 1; m < 64; m <<= 1) s += __shfl_xor(s, m);
  __shared__ float red[8];
  if ((tid & 63) == 0) red[tid >> 6] = s;
  __syncthreads();
  float mu = (red[0] + red[1] + red[2] + red[3]) * (1.0f / D_);
  float v0 = 0.f;
#pragma unroll
  for (int i = 0; i < 4; ++i) { float d = x[i] - mu; v0 += d * d; }
#pragma unroll
  for (int m = 1; m < 64; m <<= 1) v0 += __shfl_xor(v0, m);
  if ((tid & 63) == 0) red[4 + (tid >> 6)] = v0;
  __syncthreads();
  float var = (red[4] + red[5] + red[6] + red[7]) * (1.0f / D_);
  float rs = rsqrtf(var + 1e-12f);
#pragma unroll
  for (int i = 0; i < 4; ++i) {
    int col = tid * 4 + i;
    x[i] = (x[i] - mu) * rs * g[col] + beta[col];
  }
  *(float4*)(outf + base + tid * 4) = make_float4(x[0], x[1], x[2], x[3]);
  if (WRITE_BF16) {
    bfx4 o;
    o[0] = (__bf16)x[0]; o[1] = (__bf16)x[1]; o[2] = (__bf16)x[2]; o[3] = (__bf16)x[3];
    *(bfx4*)(outb + base + tid * 4) = o;
  }
}

// ---------------------------------------------------------------- launch
extern "C" void kernel_launch(void* const* d_in, const int* in_sizes, int n_in,
                              void* d_out, int out_size, void* d_ws, size_t ws_size,
                              hipStream_t stream) {
  const float* query    = (const float*)d_in[0];
  const float* key_in   = (const float*)d_in[1];
  const float* value_in = (const float*)d_in[2];
  const float* mask     = (const float*)d_in[3];
  const float* Wq = (const float*)d_in[4];  const float* bq = (const float*)d_in[5];
  const float* Wk = (const float*)d_in[6];  const float* bk = (const float*)d_in[7];
  const float* Wv = (const float*)d_in[8];  const float* bv = (const float*)d_in[9];
  const float* Wo = (const float*)d_in[10]; const float* bo = (const float*)d_in[11];
  const float* ln1g = (const float*)d_in[12]; const float* ln1b = (const float*)d_in[13];
  const float* Wi = (const float*)d_in[14]; const float* bi = (const float*)d_in[15];
  const float* Wd = (const float*)d_in[16]; const float* bd = (const float*)d_in[17];
  const float* ln2g = (const float*)d_in[18]; const float* ln2b = (const float*)d_in[19];

  char* ws = (char*)d_ws;
  const size_t MB = 1ull << 20;
  if (ws_size < 112 * MB) return;

  __bf16* xq   = (__bf16*)(ws + 0 * MB);
  __bf16* xk   = (__bf16*)(ws + 8 * MB);
  __bf16* xv   = (__bf16*)(ws + 16 * MB);
  float*  alin = (float*)(ws + 0 * MB);
  float*  mask2= (float*)(ws + 0 * MB);     // written AFTER qkv256 (xq dead),
                                            // dead before Wo writes alin
  __bf16* x1b  = (__bf16*)(ws + 16 * MB);
  __bf16* qb   = (__bf16*)(ws + 24 * MB);
  __bf16* kb   = (__bf16*)(ws + 32 * MB);
  __bf16* vb   = (__bf16*)(ws + 40 * MB);
  __bf16* vt   = (__bf16*)(ws + 48 * MB);
  __bf16* inter= (__bf16*)(ws + 24 * MB);
  __bf16* ctxb = (__bf16*)(ws + 56 * MB);
  float*  ff   = (float*)(ws + 56 * MB);
  float*  x1f  = (float*)(ws + 72 * MB);
  __bf16* wqt  = (__bf16*)(ws + 88 * MB);
  __bf16* wkt  = (__bf16*)(ws + 90 * MB);
  __bf16* wvt  = (__bf16*)(ws + 92 * MB);
  __bf16* wot  = (__bf16*)(ws + 94 * MB);
  __bf16* wit  = (__bf16*)(ws + 96 * MB);
  __bf16* wdt  = (__bf16*)(ws + 104 * MB);

  dim3 b256(256);
  dim3 tblk(32, 8);
  const int n1 = M_ * D_;

  to_bf16_kernel<<<dim3(n1 / 1024), b256, 0, stream>>>(query, xq, n1);
  to_bf16_kernel<<<dim3(n1 / 1024), b256, 0, stream>>>(key_in, xk, n1);
  to_bf16_kernel<<<dim3(n1 / 1024), b256, 0, stream>>>(value_in, xv, n1);

  transpose_conv_kernel<<<dim3(D_ / 32, D_ / 32), tblk, 0, stream>>>(Wq, wqt, D_, D_);
  transpose_conv_kernel<<<dim3(D_ / 32, D_ / 32), tblk, 0, stream>>>(Wk, wkt, D_, D_);
  transpose_conv_kernel<<<dim3(D_ / 32, D_ / 32), tblk, 0, stream>>>(Wv, wvt, D_, D_);
  transpose_conv_kernel<<<dim3(D_ / 32, D_ / 32), tblk, 0, stream>>>(Wo, wot, D_, D_);
  transpose_conv_kernel<<<dim3(DFF_ / 32, D_ / 32), tblk, 0, stream>>>(Wi, wit, D_, DFF_);
  transpose_conv_kernel<<<dim3(D_ / 32, DFF_ / 32), tblk, 0, stream>>>(Wd, wdt, DFF_, D_);

  QKVArgs qa;
  qa.A[0] = xq;  qa.A[1] = xk;  qa.A[2] = xv;
  qa.Bt[0] = wqt; qa.Bt[1] = wkt; qa.Bt[2] = wvt;
  qa.bias[0] = bq; qa.bias[1] = bk; qa.bias[2] = bv;
  qa.out[0] = qb; qa.out[1] = kb; qa.out[2] = vb;
  qkv256_kernel<<<dim3(D_ / 256, M_ / 256, 3), dim3(512), 131072, stream>>>(qa, D_, D_);

  transpose_v_kernel<<<dim3(S_ / 32, 2, B_ * H_), tblk, 0, stream>>>(vb, vt);

  scale_mask_kernel<<<dim3((B_ * S_ + 255) / 256), b256, 0, stream>>>(mask, mask2, B_ * S_);

  attn_kernel<<<dim3(S_ / 128, B_ * H_), dim3(512), 0, stream>>>(qb, kb, vt, mask2, ctxb);

  gemm_kernel<1, 64><<<dim3(D_ / 64, M_ / 128), b256, 0, stream>>>(ctxb, wot, bo, (void*)alin, D_, D_);

  ln_kernel<true><<<dim3(M_), b256, 0, stream>>>(alin, query, ln1g, ln1b, x1f, x1b);

  gemm256_kernel<2><<<dim3(DFF_ / 256, M_ / 256), dim3(512), 131072, stream>>>(x1b, wit, bi, (void*)inter, DFF_, D_);

  gemm_kernel<1, 64><<<dim3(D_ / 64, M_ / 128), b256, 0, stream>>>(inter, wdt, bd, (void*)ff, D_, DFF_);

  ln_kernel<false><<<dim3(M_), b256, 0, stream>>>(ff, x1f, ln2g, ln2b, (float*)d_out, nullptr);
}

// Round 12
// 289.639 us; speedup vs baseline: 1.0593x; 1.0094x over previous
//
#include <hip/hip_runtime.h>
#include <hip/hip_bf16.h>
#include <cmath>

#define B_   2
#define S_   2048
#define D_   1024
#define H_   16
#define DFF_ 4096
#define DH_  64
#define M_   (B_*S_)   // 4096 rows

typedef __bf16 bfx8 __attribute__((ext_vector_type(8)));
typedef __bf16 bfx4 __attribute__((ext_vector_type(4)));
typedef float  fx4  __attribute__((ext_vector_type(4)));

__device__ __forceinline__ float fast_exp2(float x) {
  float r;
  asm volatile("v_exp_f32 %0, %1" : "=v"(r) : "v"(x));
  return r;
}

// ---------------------------------------------------------------- utilities
__device__ __forceinline__ void gload_lds16(const void* g, void* l) {
  __builtin_amdgcn_global_load_lds((__attribute__((address_space(1))) void*)(g),
                                   (__attribute__((address_space(3))) void*)(l),
                                   16, 0, 0);
}

// ------------------------------------------------------------- fp32 -> bf16
__global__ __launch_bounds__(256)
void to_bf16_kernel(const float* __restrict__ in, __bf16* __restrict__ out, int n) {
  int i = (blockIdx.x * 256 + threadIdx.x) * 4;
  if (i < n) {
    float4 v = *(const float4*)(in + i);
    bfx4 o;
    o[0] = (__bf16)v.x; o[1] = (__bf16)v.y; o[2] = (__bf16)v.z; o[3] = (__bf16)v.w;
    *(bfx4*)(out + i) = o;
  }
}

// ------------------------------------------------ mask * log2(e) (tiny)
__global__ __launch_bounds__(256)
void scale_mask_kernel(const float* __restrict__ in, float* __restrict__ out, int n) {
  int i = blockIdx.x * 256 + threadIdx.x;
  if (i < n) out[i] = in[i] * 1.44269504f;
}

// --------------------------------------- W [R][C] f32 -> Wt [C][R] bf16
__global__ __launch_bounds__(256)
void transpose_conv_kernel(const float* __restrict__ in, __bf16* __restrict__ out,
                           int R, int C) {
  __shared__ float t[32][33];
  int r0 = blockIdx.y * 32, c0 = blockIdx.x * 32;
  int tx = threadIdx.x, ty = threadIdx.y;   // 32 x 8
#pragma unroll
  for (int j = 0; j < 4; ++j) {
    int r = ty + j * 8;
    t[r][tx] = in[(size_t)(r0 + r) * C + c0 + tx];
  }
  __syncthreads();
#pragma unroll
  for (int j = 0; j < 4; ++j) {
    int c = ty + j * 8;
    out[(size_t)(c0 + c) * R + r0 + tx] = (__bf16)t[tx][c];
  }
}

// ----------------------- V [B,S,H,DH] bf16 -> Vt [B,H,DH,S] bf16
__global__ __launch_bounds__(256)
void transpose_v_kernel(const __bf16* __restrict__ vb, __bf16* __restrict__ vt) {
  __shared__ __bf16 t[32][33];
  int bh = blockIdx.z;
  int b = bh >> 4, h = bh & 15;
  int s0 = blockIdx.x * 32, d0 = blockIdx.y * 32;
  int tx = threadIdx.x, ty = threadIdx.y;
#pragma unroll
  for (int j = 0; j < 4; ++j) {
    int s = ty + j * 8;
    t[s][tx] = vb[(size_t)((b * S_ + s0 + s) * H_ + h) * DH_ + d0 + tx];
  }
  __syncthreads();
#pragma unroll
  for (int j = 0; j < 4; ++j) {
    int d = ty + j * 8;
    vt[(size_t)(bh * DH_ + d0 + d) * S_ + s0 + tx] = t[tx][d];
  }
}

// --------------------------------------------------------------- GEMM 128-tile
template<int MODE, int TBN>
__device__ __forceinline__ void gemm_body(const __bf16* __restrict__ A,
                                          const __bf16* __restrict__ Bt,
                                          const float* __restrict__ bias,
                                          void* __restrict__ out,
                                          int Ndim, int Kdim,
                                          int m0, int n0,
                                          __bf16* As, __bf16* Bs) {
  const int tid  = threadIdx.x;
  const int lane = tid & 63;
  const int w    = tid >> 6;
  const int wm   = w >> 1, wn = w & 1;
  constexpr int NF = TBN / 32;

  fx4 acc[4][NF];
#pragma unroll
  for (int i = 0; i < 4; ++i)
#pragma unroll
    for (int j = 0; j < NF; ++j) acc[i][j] = {0.f, 0.f, 0.f, 0.f};

  const int KT = Kdim / 64;
  for (int kt = 0; kt < KT; ++kt) {
    __syncthreads();
    const int kb0 = kt * 64;
#pragma unroll
    for (int i = 0; i < 4; ++i) {
      int o   = tid * 16 + i * 4096;
      int row = o >> 7, cb = o & 127;
      int cbs = cb ^ ((row & 7) << 4);
      gload_lds16((const char*)A + ((size_t)(m0 + row) * Kdim + kb0) * 2 + cbs,
                  (char*)As + o);
    }
#pragma unroll
    for (int i = 0; i < TBN / 32; ++i) {
      int o   = tid * 16 + i * 4096;
      int row = o >> 7, cb = o & 127;
      int cbs = cb ^ ((row & 7) << 4);
      gload_lds16((const char*)Bt + ((size_t)(n0 + row) * Kdim + kb0) * 2 + cbs,
                  (char*)Bs + o);
    }
    __syncthreads();

#pragma unroll
    for (int kk = 0; kk < 2; ++kk) {
      bfx8 afr[4], bfr[NF];
      const int cb = kk * 64 + ((lane >> 4) << 4);
#pragma unroll
      for (int mf = 0; mf < 4; ++mf) {
        int row = wm * 64 + mf * 16 + (lane & 15);
        afr[mf] = *(const bfx8*)((const char*)As + row * 128 + (cb ^ ((row & 7) << 4)));
      }
#pragma unroll
      for (int nf = 0; nf < NF; ++nf) {
        int row = wn * (TBN / 2) + nf * 16 + (lane & 15);
        bfr[nf] = *(const bfx8*)((const char*)Bs + row * 128 + (cb ^ ((row & 7) << 4)));
      }
#pragma unroll
      for (int mf = 0; mf < 4; ++mf)
#pragma unroll
        for (int nf = 0; nf < NF; ++nf)
          acc[mf][nf] = __builtin_amdgcn_mfma_f32_16x16x32_bf16(afr[mf], bfr[nf],
                                                                acc[mf][nf], 0, 0, 0);
    }
  }

#pragma unroll
  for (int mf = 0; mf < 4; ++mf) {
#pragma unroll
    for (int nf = 0; nf < NF; ++nf) {
      int col = n0 + wn * (TBN / 2) + nf * 16 + (lane & 15);
      float bvl = bias[col];
#pragma unroll
      for (int r = 0; r < 4; ++r) {
        int rowg = m0 + wm * 64 + mf * 16 + ((lane >> 4) << 2) + r;
        float v = acc[mf][nf][r] + bvl;
        if (MODE == 2) v = 0.5f * v * (1.0f + erff(v * 0.70710678118654752f));
        if (MODE == 1) ((float*)out)[(size_t)rowg * Ndim + col] = v;
        else          ((__bf16*)out)[(size_t)rowg * Ndim + col] = (__bf16)v;
      }
    }
  }
}

template<int MODE, int TBN>
__global__ __launch_bounds__(256)
void gemm_kernel(const __bf16* __restrict__ A, const __bf16* __restrict__ Bt,
                 const float* __restrict__ bias, void* __restrict__ out,
                 int Ndim, int Kdim) {
  __shared__ alignas(16) __bf16 As[128 * 64];
  __shared__ alignas(16) __bf16 Bs[TBN * 64];
  gemm_body<MODE, TBN>(A, Bt, bias, out, Ndim, Kdim,
                       blockIdx.y * 128, blockIdx.x * TBN, As, Bs);
}

// --------------------------------------------------------------- GEMM 256-tile
// (round-9 validated 8-phase schedule, unchanged)
__device__ __forceinline__ void stage_a256(const __bf16* __restrict__ A, int m0,
                                           int Kdim, int tile, int h, char* Asm) {
  char* dst = Asm + (tile & 1) * 32768;
  const int kb0 = tile * 64;
  const int tid = threadIdx.x;
#pragma unroll
  for (int it = 0; it < 2; ++it) {
    int o = tid * 16 + it * 8192;
    int lrow = o >> 7, cb = o & 127;
    int r = (lrow & 63) + h * 64 + ((lrow >> 6) << 7);
    int csrc = cb ^ ((r & 7) << 4);
    gload_lds16((const char*)A + ((size_t)(m0 + r) * Kdim + kb0) * 2 + csrc,
                dst + r * 128 + cb);
  }
}
__device__ __forceinline__ void stage_b256(const __bf16* __restrict__ Bt, int n0,
                                           int Kdim, int tile, int h, char* Bsm) {
  char* dst = Bsm + (tile & 1) * 32768;
  const int kb0 = tile * 64;
  const int tid = threadIdx.x;
#pragma unroll
  for (int it = 0; it < 2; ++it) {
    int o = tid * 16 + it * 8192;
    int lrow = o >> 7, cb = o & 127;
    int r = h * 128 + lrow;
    int csrc = cb ^ ((r & 7) << 4);
    gload_lds16((const char*)Bt + ((size_t)(n0 + r) * Kdim + kb0) * 2 + csrc,
                dst + r * 128 + cb);
  }
}

template<int MODE>
__device__ __forceinline__ void gemm256_body(const __bf16* __restrict__ A,
                                             const __bf16* __restrict__ Bt,
                                             const float* __restrict__ bias,
                                             void* __restrict__ out,
                                             int Ndim, int Kdim, int m0, int n0) {
  extern __shared__ char smem[];
  char* Asm = smem;
  char* Bsm = smem + 65536;
  const int tid  = threadIdx.x;
  const int lane = tid & 63;
  const int w    = tid >> 6;
  const int wm   = w >> 2;
  const int wn   = w & 3;
  const int g    = lane >> 4;
  const int ql   = lane & 15;
  const int KT   = Kdim / 64;

  fx4 acc[8][4];
#pragma unroll
  for (int i = 0; i < 8; ++i)
#pragma unroll
    for (int j = 0; j < 4; ++j) acc[i][j] = {0.f, 0.f, 0.f, 0.f};

  stage_a256(A, m0, Kdim, 0, 0, Asm);
  stage_a256(A, m0, Kdim, 0, 1, Asm);
  stage_b256(Bt, n0, Kdim, 0, 0, Bsm);
  stage_b256(Bt, n0, Kdim, 0, 1, Bsm);
  stage_a256(A, m0, Kdim, 1, 0, Asm);
  asm volatile("s_waitcnt vmcnt(2)" ::: "memory");
  __builtin_amdgcn_s_barrier();
  __builtin_amdgcn_sched_barrier(0);

  for (int t = 0; t < KT; ++t) {
    const char* Ab = Asm + (t & 1) * 32768;
    const char* Bb = Bsm + (t & 1) * 32768;
#pragma unroll
    for (int p = 0; p < 4; ++p) {
      const int ah = p >> 1, kk = p & 1;
      if (p == 0 && t + 1 < KT) stage_a256(A, m0, Kdim, t + 1, 1, Asm);
      if (p == 1 && t + 1 < KT) stage_b256(Bt, n0, Kdim, t + 1, 0, Bsm);
      if (p == 2 && t + 1 < KT) stage_b256(Bt, n0, Kdim, t + 1, 1, Bsm);
      if (p == 3 && t + 2 < KT) stage_a256(A, m0, Kdim, t + 2, 0, Asm);
      __builtin_amdgcn_sched_barrier(0);

      bfx8 af[4], bf[4];
      const int cbv = kk * 64 + g * 16;
#pragma unroll
      for (int j = 0; j < 4; ++j) {
        int arow = wm * 128 + (ah * 4 + j) * 16 + ql;
        af[j] = *(const bfx8*)(Ab + arow * 128 + (cbv ^ ((arow & 7) << 4)));
      }
#pragma unroll
      for (int nf = 0; nf < 4; ++nf) {
        int brow = wn * 64 + nf * 16 + ql;
        bf[nf] = *(const bfx8*)(Bb + brow * 128 + (cbv ^ ((brow & 7) << 4)));
      }
      __builtin_amdgcn_sched_barrier(0);
      __builtin_amdgcn_s_barrier();
      asm volatile("s_waitcnt lgkmcnt(0)" ::: "memory");
      __builtin_amdgcn_sched_barrier(0);
      __builtin_amdgcn_s_setprio(1);
#pragma unroll
      for (int j = 0; j < 4; ++j)
#pragma unroll
        for (int nf = 0; nf < 4; ++nf)
          acc[ah * 4 + j][nf] = __builtin_amdgcn_mfma_f32_16x16x32_bf16(
              af[j], bf[nf], acc[ah * 4 + j][nf], 0, 0, 0);
      __builtin_amdgcn_s_setprio(0);
      __builtin_amdgcn_s_barrier();
      __builtin_amdgcn_sched_barrier(0);
    }
    if (t + 1 < KT) {
      if (t + 2 < KT) asm volatile("s_waitcnt vmcnt(2)" ::: "memory");
      else            asm volatile("s_waitcnt vmcnt(0)" ::: "memory");
      __builtin_amdgcn_s_barrier();
      __builtin_amdgcn_sched_barrier(0);
    }
  }

#pragma unroll
  for (int mf = 0; mf < 8; ++mf) {
#pragma unroll
    for (int nf = 0; nf < 4; ++nf) {
      int col = n0 + wn * 64 + nf * 16 + ql;
      float bvl = bias[col];
#pragma unroll
      for (int r = 0; r < 4; ++r) {
        int rowg = m0 + wm * 128 + mf * 16 + g * 4 + r;
        float v = acc[mf][nf][r] + bvl;
        if (MODE == 2) v = 0.5f * v * (1.0f + erff(v * 0.70710678118654752f));
        if (MODE == 1) ((float*)out)[(size_t)rowg * Ndim + col] = v;
        else          ((__bf16*)out)[(size_t)rowg * Ndim + col] = (__bf16)v;
      }
    }
  }
}

template<int MODE>
__global__ __launch_bounds__(512)
void gemm256_kernel(const __bf16* __restrict__ A, const __bf16* __restrict__ Bt,
                    const float* __restrict__ bias, void* __restrict__ out,
                    int Ndim, int Kdim) {
  gemm256_body<MODE>(A, Bt, bias, out, Ndim, Kdim,
                     blockIdx.y * 256, blockIdx.x * 256);
}

struct QKVArgs {
  const __bf16* A[3]; const __bf16* Bt[3]; const float* bias[3]; __bf16* out[3];
};

__global__ __launch_bounds__(512)
void qkv256_kernel(QKVArgs args, int Ndim, int Kdim) {
  int z = blockIdx.z;
  gemm256_body<0>(args.A[z], args.Bt[z], args.bias[z], (void*)args.out[z],
                  Ndim, Kdim, blockIdx.y * 256, blockIdx.x * 256);
}

// --------------------------------------------------------- flash attention
// Round-11 validated softmax (log2-domain, defer-max, v_exp_f32) + THIS ROUND:
// mask row preloaded to LDS (K-loop has ONLY staging VMEM -> clean vmcnt) and
// depth-2 prefetch via 3-buf K/V (steady vmcnt(4), tail 2 -> 0). Q staging
// overlays the P-strip region (Q dead after aq read; extra barrier guards).
// LDS = Ks 24K + Vs 24K + Ps 16K + Ms 8K = 72 KB -> 2 blocks/CU.
__global__ __launch_bounds__(512)
void attn_kernel(const __bf16* __restrict__ Qb, const __bf16* __restrict__ Kb,
                 const __bf16* __restrict__ Vt, const float* __restrict__ mask2,
                 __bf16* __restrict__ ctx) {
  __shared__ alignas(16) __bf16 Ks[3 * 64 * 64];     // 24 KB (3-buf)
  __shared__ alignas(16) __bf16 Vs[3 * 64 * 64];     // 24 KB (3-buf)
  __shared__ alignas(16) __bf16 Ps[8 * 16 * 64];     // 16 KB (aliased by Q stage)
  __shared__ alignas(16) float  Ms[2048];            //  8 KB mask row (log2-scaled)

  const int tid  = threadIdx.x;
  const int lane = tid & 63;
  const int w    = tid >> 6;
  const int g    = lane >> 4;
  const int ql   = lane & 15;
  const int bh   = blockIdx.y;
  const int b    = bh >> 4;
  const int h    = bh & 15;
  const int q0   = blockIdx.x * 128;

  const size_t kbase  = ((size_t)(b * S_)) * D_ + h * DH_;
  const size_t vtbase = (size_t)bh * DH_ * S_;
  const int NT = S_ / 64;

  // ---- prologue: per-thread issues 7 gload_lds: Q[2], Ms[1], t0[2], t1[2]
  char* Qsm = (char*)Ps;                             // overlay
  const size_t qbase = ((size_t)(b * S_) + q0) * D_ + h * DH_;
#pragma unroll
  for (int i = 0; i < 2; ++i) {
    int o   = tid * 16 + i * 8192;
    int row = o >> 7, cb = o & 127;
    int cbs = cb ^ ((row & 7) << 4);
    gload_lds16((const char*)Qb + (qbase + (size_t)row * D_) * 2 + cbs, Qsm + o);
  }
  {
    int o = tid * 16;                                // 512 thr x 16B = 8 KB
    gload_lds16((const char*)mask2 + (size_t)b * S_ * 4 + o, (char*)Ms + o);
  }
  {
    int o   = tid * 16;
    int row = o >> 7, cb = o & 127;
    int cbs = cb ^ ((row & 7) << 4);
    gload_lds16((const char*)Kb + (kbase + (size_t)row * D_) * 2 + cbs, (char*)Ks + o);
    gload_lds16((const char*)Vt + (vtbase + (size_t)row * S_) * 2 + cbs, (char*)Vs + o);
    gload_lds16((const char*)Kb + (kbase + (size_t)(64 + row) * D_) * 2 + cbs,
                (char*)Ks + 8192 + o);
    gload_lds16((const char*)Vt + (vtbase + (size_t)row * S_ + 64) * 2 + cbs,
                (char*)Vs + 8192 + o);
  }
  asm volatile("s_waitcnt vmcnt(4)" ::: "memory");   // Q + Ms landed (t0,t1 in flight)
  __builtin_amdgcn_s_barrier();                      // all waves' Q/Ms visible
  __builtin_amdgcn_sched_barrier(0);

  bfx8 aq[2];
  {
    int row = w * 16 + ql;
#pragma unroll
    for (int kk = 0; kk < 2; ++kk) {
      int cb = kk * 64 + g * 16;
      aq[kk] = *(const bfx8*)(Qsm + row * 128 + (cb ^ ((row & 7) << 4)));
    }
  }
  __syncthreads();                                   // all aq reads done -> Ps free
  asm volatile("s_waitcnt vmcnt(2)" ::: "memory");   // tile0 landed (t1 in flight)
  __builtin_amdgcn_s_barrier();
  __builtin_amdgcn_sched_barrier(0);

  float mrun = -1e30f, lrun = 0.f;   // log2-domain running stats
  fx4 acc[4];
#pragma unroll
  for (int d = 0; d < 4; ++d) acc[d] = {0.f, 0.f, 0.f, 0.f};

  char* pw = (char*)Ps + w * 2048;
  const float SCL = 0.18033688f;     // 0.125 * log2(e)

  for (int t = 0; t < NT; ++t) {
    const int kv0 = t * 64;
    if (t + 2 < NT) {                // stage tile t+2 into buf (t+2)%3
      int o   = tid * 16;
      int row = o >> 7, cb = o & 127;
      int cbs = cb ^ ((row & 7) << 4);
      int nkv = kv0 + 128;
      int bo  = ((t + 2) % 3) * 8192;
      gload_lds16((const char*)Kb + (kbase + (size_t)(nkv + row) * D_) * 2 + cbs,
                  (char*)Ks + bo + o);
      gload_lds16((const char*)Vt + (vtbase + (size_t)row * S_ + nkv) * 2 + cbs,
                  (char*)Vs + bo + o);
    }
    __builtin_amdgcn_sched_barrier(0);
    if (t > 0) {                     // tile t landed when only t+1,t+2 outstanding
      if (t + 2 < NT)      asm volatile("s_waitcnt vmcnt(4)" ::: "memory");
      else if (t + 1 < NT) asm volatile("s_waitcnt vmcnt(2)" ::: "memory");
      else                 asm volatile("s_waitcnt vmcnt(0)" ::: "memory");
      __builtin_amdgcn_s_barrier();
      __builtin_amdgcn_sched_barrier(0);
    }
    const char* Kc = (const char*)Ks + (t % 3) * 8192;
    const char* Vc = (const char*)Vs + (t % 3) * 8192;

    // swapped QK^T: sc[nf] lane holds S[kv = nf*16+g*4+r][q = w*16+ql]
    fx4 sc[4];
#pragma unroll
    for (int nf = 0; nf < 4; ++nf) sc[nf] = {0.f, 0.f, 0.f, 0.f};
#pragma unroll
    for (int kk = 0; kk < 2; ++kk) {
      const int cb = kk * 64 + g * 16;
      bfx8 bk[4];
#pragma unroll
      for (int nf = 0; nf < 4; ++nf) {
        int row = nf * 16 + ql;
        bk[nf] = *(const bfx8*)(Kc + row * 128 + (cb ^ ((row & 7) << 4)));
      }
#pragma unroll
      for (int nf = 0; nf < 4; ++nf)
        sc[nf] = __builtin_amdgcn_mfma_f32_16x16x32_bf16(bk[nf], aq[kk], sc[nf], 0, 0, 0);
    }

    // log2-domain scale + mask from LDS
    float sv[4][4];
#pragma unroll
    for (int nf = 0; nf < 4; ++nf) {
      float4 mk = *(const float4*)((const char*)Ms + (kv0 + nf * 16 + g * 4) * 4);
      sv[nf][0] = sc[nf][0] * SCL + mk.x;
      sv[nf][1] = sc[nf][1] * SCL + mk.y;
      sv[nf][2] = sc[nf][2] * SCL + mk.z;
      sv[nf][3] = sc[nf][3] * SCL + mk.w;
    }
    float mx = sv[0][0];
#pragma unroll
    for (int nf = 0; nf < 4; ++nf)
#pragma unroll
      for (int r = 0; r < 4; ++r) mx = fmaxf(mx, sv[nf][r]);
    mx = fmaxf(mx, __shfl_xor(mx, 16));
    mx = fmaxf(mx, __shfl_xor(mx, 32));

    // defer-max: rescale only when tile max exceeds running max + 8 (log2)
    if (!__all(mx <= mrun + 8.0f)) {
      float mnew  = fmaxf(mrun, mx);
      float alpha = fast_exp2(mrun - mnew);
      lrun *= alpha;
      float af[4];
#pragma unroll
      for (int r = 0; r < 4; ++r) af[r] = __shfl(alpha, g * 4 + r);
#pragma unroll
      for (int d = 0; d < 4; ++d)
#pragma unroll
        for (int r = 0; r < 4; ++r) acc[d][r] *= af[r];
      mrun = mnew;
    }

    float rs = 0.f;
#pragma unroll
    for (int nf = 0; nf < 4; ++nf)
#pragma unroll
      for (int r = 0; r < 4; ++r) {
        float p = fast_exp2(sv[nf][r] - mrun);
        sv[nf][r] = p; rs += p;
      }
    rs += __shfl_xor(rs, 16);
    rs += __shfl_xor(rs, 32);
    lrun += rs;

    // write P strip row ql (vector bfx4)
#pragma unroll
    for (int nf = 0; nf < 4; ++nf) {
      bfx4 pv;
      pv[0] = (__bf16)sv[nf][0]; pv[1] = (__bf16)sv[nf][1];
      pv[2] = (__bf16)sv[nf][2]; pv[3] = (__bf16)sv[nf][3];
      int c = (nf * 32 + g * 8) ^ ((ql & 7) << 4);
      *(bfx4*)(pw + ql * 128 + c) = pv;
    }

    // fence: P-strip writes complete + no compiler motion of PV reads above
    asm volatile("s_waitcnt lgkmcnt(0)" ::: "memory");
    __builtin_amdgcn_sched_barrier(0);

    // PV
#pragma unroll
    for (int kk = 0; kk < 2; ++kk) {
      int prow = ql;
      int cb   = kk * 64 + g * 16;
      bfx8 ap  = *(const bfx8*)((const char*)pw + prow * 128 + (cb ^ ((prow & 7) << 4)));
#pragma unroll
      for (int d = 0; d < 4; ++d) {
        int vrow = d * 16 + ql;
        bfx8 bv  = *(const bfx8*)(Vc + vrow * 128 + (cb ^ ((vrow & 7) << 4)));
        acc[d] = __builtin_amdgcn_mfma_f32_16x16x32_bf16(ap, bv, acc[d], 0, 0, 0);
      }
    }

    __builtin_amdgcn_s_barrier();    // all reads of buf t%3 retired before reuse
    __builtin_amdgcn_sched_barrier(0);
  }

  float linv = 1.0f / lrun;
#pragma unroll
  for (int r = 0; r < 4; ++r) {
    float inv = __shfl(linv, g * 4 + r);
    int qrow = q0 + w * 16 + g * 4 + r;
    size_t base = ((size_t)(b * S_) + qrow) * D_ + h * DH_;
#pragma unroll
    for (int d = 0; d < 4; ++d)
      ctx[base + d * 16 + ql] = (__bf16)(acc[d][r] * inv);
  }
}

// -------------------------------------------- residual + LayerNorm (row=1024)
template<bool WRITE_BF16>
__global__ __launch_bounds__(256)
void ln_kernel(const float* __restrict__ a, const float* __restrict__ b,
               const float* __restrict__ g, const float* __restrict__ beta,
               float* __restrict__ outf, __bf16* __restrict__ outb) {
  const int row = blockIdx.x;
  const int tid = threadIdx.x;
  const size_t base = (size_t)row * D_;
  float4 xa = *(const float4*)(a + base + tid * 4);
  float4 xb = *(const float4*)(b + base + tid * 4);
  float x[4] = {xa.x + xb.x, xa.y + xb.y, xa.z + xb.z, xa.w + xb.w};
  float s = x[0] + x[1] + x[2] + x[3];
#pragma unroll
  for (int m = 1; m < 64; m <<= 1) s += __shfl_xor(s, m);
  __shared__ float red[8];
  if ((tid & 63) == 0) red[tid >> 6] = s;
  __syncthreads();
  float mu = (red[0] + red[1] + red[2] + red[3]) * (1.0f / D_);
  float v0 = 0.f;
#pragma unroll
  for (int i = 0; i < 4; ++i) { float d = x[i] - mu; v0 += d * d; }
#pragma unroll
  for (int m = 1; m < 64; m <<= 1) v0 += __shfl_xor(v0, m);
  if ((tid & 63) == 0) red[4 + (tid >> 6)] = v0;
  __syncthreads();
  float var = (red[4] + red[5] + red[6] + red[7]) * (1.0f / D_);
  float rs = rsqrtf(var + 1e-12f);
#pragma unroll
  for (int i = 0; i < 4; ++i) {
    int col = tid * 4 + i;
    x[i] = (x[i] - mu) * rs * g[col] + beta[col];
  }
  *(float4*)(outf + base + tid * 4) = make_float4(x[0], x[1], x[2], x[3]);
  if (WRITE_BF16) {
    bfx4 o;
    o[0] = (__bf16)x[0]; o[1] = (__bf16)x[1]; o[2] = (__bf16)x[2]; o[3] = (__bf16)x[3];
    *(bfx4*)(outb + base + tid * 4) = o;
  }
}

// ---------------------------------------------------------------- launch
extern "C" void kernel_launch(void* const* d_in, const int* in_sizes, int n_in,
                              void* d_out, int out_size, void* d_ws, size_t ws_size,
                              hipStream_t stream) {
  const float* query    = (const float*)d_in[0];
  const float* key_in   = (const float*)d_in[1];
  const float* value_in = (const float*)d_in[2];
  const float* mask     = (const float*)d_in[3];
  const float* Wq = (const float*)d_in[4];  const float* bq = (const float*)d_in[5];
  const float* Wk = (const float*)d_in[6];  const float* bk = (const float*)d_in[7];
  const float* Wv = (const float*)d_in[8];  const float* bv = (const float*)d_in[9];
  const float* Wo = (const float*)d_in[10]; const float* bo = (const float*)d_in[11];
  const float* ln1g = (const float*)d_in[12]; const float* ln1b = (const float*)d_in[13];
  const float* Wi = (const float*)d_in[14]; const float* bi = (const float*)d_in[15];
  const float* Wd = (const float*)d_in[16]; const float* bd = (const float*)d_in[17];
  const float* ln2g = (const float*)d_in[18]; const float* ln2b = (const float*)d_in[19];

  char* ws = (char*)d_ws;
  const size_t MB = 1ull << 20;
  if (ws_size < 112 * MB) return;

  __bf16* xq   = (__bf16*)(ws + 0 * MB);
  __bf16* xk   = (__bf16*)(ws + 8 * MB);
  __bf16* xv   = (__bf16*)(ws + 16 * MB);
  float*  alin = (float*)(ws + 0 * MB);
  float*  mask2= (float*)(ws + 0 * MB);     // written AFTER qkv256 (xq dead),
                                            // dead before Wo writes alin
  __bf16* x1b  = (__bf16*)(ws + 16 * MB);
  __bf16* qb   = (__bf16*)(ws + 24 * MB);
  __bf16* kb   = (__bf16*)(ws + 32 * MB);
  __bf16* vb   = (__bf16*)(ws + 40 * MB);
  __bf16* vt   = (__bf16*)(ws + 48 * MB);
  __bf16* inter= (__bf16*)(ws + 24 * MB);
  __bf16* ctxb = (__bf16*)(ws + 56 * MB);
  float*  ff   = (float*)(ws + 56 * MB);
  float*  x1f  = (float*)(ws + 72 * MB);
  __bf16* wqt  = (__bf16*)(ws + 88 * MB);
  __bf16* wkt  = (__bf16*)(ws + 90 * MB);
  __bf16* wvt  = (__bf16*)(ws + 92 * MB);
  __bf16* wot  = (__bf16*)(ws + 94 * MB);
  __bf16* wit  = (__bf16*)(ws + 96 * MB);
  __bf16* wdt  = (__bf16*)(ws + 104 * MB);

  dim3 b256(256);
  dim3 tblk(32, 8);
  const int n1 = M_ * D_;

  to_bf16_kernel<<<dim3(n1 / 1024), b256, 0, stream>>>(query, xq, n1);
  to_bf16_kernel<<<dim3(n1 / 1024), b256, 0, stream>>>(key_in, xk, n1);
  to_bf16_kernel<<<dim3(n1 / 1024), b256, 0, stream>>>(value_in, xv, n1);

  transpose_conv_kernel<<<dim3(D_ / 32, D_ / 32), tblk, 0, stream>>>(Wq, wqt, D_, D_);
  transpose_conv_kernel<<<dim3(D_ / 32, D_ / 32), tblk, 0, stream>>>(Wk, wkt, D_, D_);
  transpose_conv_kernel<<<dim3(D_ / 32, D_ / 32), tblk, 0, stream>>>(Wv, wvt, D_, D_);
  transpose_conv_kernel<<<dim3(D_ / 32, D_ / 32), tblk, 0, stream>>>(Wo, wot, D_, D_);
  transpose_conv_kernel<<<dim3(DFF_ / 32, D_ / 32), tblk, 0, stream>>>(Wi, wit, D_, DFF_);
  transpose_conv_kernel<<<dim3(D_ / 32, DFF_ / 32), tblk, 0, stream>>>(Wd, wdt, DFF_, D_);

  QKVArgs qa;
  qa.A[0] = xq;  qa.A[1] = xk;  qa.A[2] = xv;
  qa.Bt[0] = wqt; qa.Bt[1] = wkt; qa.Bt[2] = wvt;
  qa.bias[0] = bq; qa.bias[1] = bk; qa.bias[2] = bv;
  qa.out[0] = qb; qa.out[1] = kb; qa.out[2] = vb;
  qkv256_kernel<<<dim3(D_ / 256, M_ / 256, 3), dim3(512), 131072, stream>>>(qa, D_, D_);

  transpose_v_kernel<<<dim3(S_ / 32, 2, B_ * H_), tblk, 0, stream>>>(vb, vt);

  scale_mask_kernel<<<dim3((B_ * S_ + 255) / 256), b256, 0, stream>>>(mask, mask2, B_ * S_);

  attn_kernel<<<dim3(S_ / 128, B_ * H_), dim3(512), 0, stream>>>(qb, kb, vt, mask2, ctxb);

  gemm_kernel<1, 64><<<dim3(D_ / 64, M_ / 128), b256, 0, stream>>>(ctxb, wot, bo, (void*)alin, D_, D_);

  ln_kernel<true><<<dim3(M_), b256, 0, stream>>>(alin, query, ln1g, ln1b, x1f, x1b);

  gemm256_kernel<2><<<dim3(DFF_ / 256, M_ / 256), dim3(512), 131072, stream>>>(x1b, wit, bi, (void*)inter, DFF_, D_);

  gemm_kernel<1, 64><<<dim3(D_ / 64, M_ / 128), b256, 0, stream>>>(inter, wdt, bd, (void*)ff, D_, DFF_);

  ln_kernel<false><<<dim3(M_), b256, 0, stream>>>(ff, x1f, ln2g, ln2b, (float*)d_out, nullptr);
}

// Round 13
// 274.037 us; speedup vs baseline: 1.1196x; 1.0569x over previous
//
#include <hip/hip_runtime.h>
#include <hip/hip_bf16.h>
#include <cmath>

#define B_   2
#define S_   2048
#define D_   1024
#define H_   16
#define DFF_ 4096
#define DH_  64
#define M_   (B_*S_)   // 4096 rows

typedef __bf16 bfx8 __attribute__((ext_vector_type(8)));
typedef __bf16 bfx4 __attribute__((ext_vector_type(4)));
typedef float  fx4  __attribute__((ext_vector_type(4)));

__device__ __forceinline__ float fast_exp2(float x) {
  float r;
  asm volatile("v_exp_f32 %0, %1" : "=v"(r) : "v"(x));
  return r;
}

// Abramowitz-Stegun 7.1.26 erf (max abs err 1.5e-7; exact at bf16 granularity)
__device__ __forceinline__ float fast_erf(float x) {
  float ax = fabsf(x);
  float t  = __builtin_amdgcn_rcpf(fmaf(0.3275911f, ax, 1.0f));
  float p  = fmaf(1.061405429f, t, -1.453152027f);
  p = fmaf(p, t, 1.421413741f);
  p = fmaf(p, t, -0.284496736f);
  p = fmaf(p, t, 0.254829592f);
  p = p * t;
  float e  = fast_exp2(-ax * ax * 1.44269504f);
  float r  = 1.0f - p * e;
  return copysignf(r, x);
}

// ---------------------------------------------------------------- utilities
__device__ __forceinline__ void gload_lds16(const void* g, void* l) {
  __builtin_amdgcn_global_load_lds((__attribute__((address_space(1))) void*)(g),
                                   (__attribute__((address_space(3))) void*)(l),
                                   16, 0, 0);
}

// ---------------------------------------------- fp32 -> bf16 (3 tensors, z)
struct CvtArgs { const float* in[3]; __bf16* out[3]; };

__global__ __launch_bounds__(256)
void to_bf16_3_kernel(CvtArgs args, int n) {
  int z = blockIdx.y;
  int i = (blockIdx.x * 256 + threadIdx.x) * 4;
  if (i < n) {
    float4 v = *(const float4*)(args.in[z] + i);
    bfx4 o;
    o[0] = (__bf16)v.x; o[1] = (__bf16)v.y; o[2] = (__bf16)v.z; o[3] = (__bf16)v.w;
    *(bfx4*)(args.out[z] + i) = o;
  }
}

// ------------------------------------------------ mask * log2(e) (tiny)
__global__ __launch_bounds__(256)
void scale_mask_kernel(const float* __restrict__ in, float* __restrict__ out, int n) {
  int i = blockIdx.x * 256 + threadIdx.x;
  if (i < n) out[i] = in[i] * 1.44269504f;
}

// --------------------------------------- W [R][C] f32 -> Wt [C][R] bf16
__global__ __launch_bounds__(256)
void transpose_conv_kernel(const float* __restrict__ in, __bf16* __restrict__ out,
                           int R, int C) {
  __shared__ float t[32][33];
  int r0 = blockIdx.y * 32, c0 = blockIdx.x * 32;
  int tx = threadIdx.x, ty = threadIdx.y;   // 32 x 8
#pragma unroll
  for (int j = 0; j < 4; ++j) {
    int r = ty + j * 8;
    t[r][tx] = in[(size_t)(r0 + r) * C + c0 + tx];
  }
  __syncthreads();
#pragma unroll
  for (int j = 0; j < 4; ++j) {
    int c = ty + j * 8;
    out[(size_t)(c0 + c) * R + r0 + tx] = (__bf16)t[tx][c];
  }
}

// ----------------------- V [B,S,H,DH] bf16 -> Vt [B,H,DH,S] bf16
__global__ __launch_bounds__(256)
void transpose_v_kernel(const __bf16* __restrict__ vb, __bf16* __restrict__ vt) {
  __shared__ __bf16 t[32][33];
  int bh = blockIdx.z;
  int b = bh >> 4, h = bh & 15;
  int s0 = blockIdx.x * 32, d0 = blockIdx.y * 32;
  int tx = threadIdx.x, ty = threadIdx.y;
#pragma unroll
  for (int j = 0; j < 4; ++j) {
    int s = ty + j * 8;
    t[s][tx] = vb[(size_t)((b * S_ + s0 + s) * H_ + h) * DH_ + d0 + tx];
  }
  __syncthreads();
#pragma unroll
  for (int j = 0; j < 4; ++j) {
    int d = ty + j * 8;
    vt[(size_t)(bh * DH_ + d0 + d) * S_ + s0 + tx] = t[tx][d];
  }
}

// --------------------------------------------------------------- GEMM 128-tile
// MODE 0: bf16 out. 1: f32 out. 2: GELU bf16 out. 3: f32 out + residual add.
template<int MODE, int TBN>
__device__ __forceinline__ void gemm_body(const __bf16* __restrict__ A,
                                          const __bf16* __restrict__ Bt,
                                          const float* __restrict__ bias,
                                          const float* __restrict__ res,
                                          void* __restrict__ out,
                                          int Ndim, int Kdim,
                                          int m0, int n0,
                                          __bf16* As, __bf16* Bs) {
  const int tid  = threadIdx.x;
  const int lane = tid & 63;
  const int w    = tid >> 6;
  const int wm   = w >> 1, wn = w & 1;
  constexpr int NF = TBN / 32;

  fx4 acc[4][NF];
#pragma unroll
  for (int i = 0; i < 4; ++i)
#pragma unroll
    for (int j = 0; j < NF; ++j) acc[i][j] = {0.f, 0.f, 0.f, 0.f};

  const int KT = Kdim / 64;
  for (int kt = 0; kt < KT; ++kt) {
    __syncthreads();
    const int kb0 = kt * 64;
#pragma unroll
    for (int i = 0; i < 4; ++i) {
      int o   = tid * 16 + i * 4096;
      int row = o >> 7, cb = o & 127;
      int cbs = cb ^ ((row & 7) << 4);
      gload_lds16((const char*)A + ((size_t)(m0 + row) * Kdim + kb0) * 2 + cbs,
                  (char*)As + o);
    }
#pragma unroll
    for (int i = 0; i < TBN / 32; ++i) {
      int o   = tid * 16 + i * 4096;
      int row = o >> 7, cb = o & 127;
      int cbs = cb ^ ((row & 7) << 4);
      gload_lds16((const char*)Bt + ((size_t)(n0 + row) * Kdim + kb0) * 2 + cbs,
                  (char*)Bs + o);
    }
    __syncthreads();

#pragma unroll
    for (int kk = 0; kk < 2; ++kk) {
      bfx8 afr[4], bfr[NF];
      const int cb = kk * 64 + ((lane >> 4) << 4);
#pragma unroll
      for (int mf = 0; mf < 4; ++mf) {
        int row = wm * 64 + mf * 16 + (lane & 15);
        afr[mf] = *(const bfx8*)((const char*)As + row * 128 + (cb ^ ((row & 7) << 4)));
      }
#pragma unroll
      for (int nf = 0; nf < NF; ++nf) {
        int row = wn * (TBN / 2) + nf * 16 + (lane & 15);
        bfr[nf] = *(const bfx8*)((const char*)Bs + row * 128 + (cb ^ ((row & 7) << 4)));
      }
#pragma unroll
      for (int mf = 0; mf < 4; ++mf)
#pragma unroll
        for (int nf = 0; nf < NF; ++nf)
          acc[mf][nf] = __builtin_amdgcn_mfma_f32_16x16x32_bf16(afr[mf], bfr[nf],
                                                                acc[mf][nf], 0, 0, 0);
    }
  }

#pragma unroll
  for (int mf = 0; mf < 4; ++mf) {
#pragma unroll
    for (int nf = 0; nf < NF; ++nf) {
      int col = n0 + wn * (TBN / 2) + nf * 16 + (lane & 15);
      float bvl = bias[col];
#pragma unroll
      for (int r = 0; r < 4; ++r) {
        int rowg = m0 + wm * 64 + mf * 16 + ((lane >> 4) << 2) + r;
        float v = acc[mf][nf][r] + bvl;
        if (MODE == 2) v = 0.5f * v * (1.0f + fast_erf(v * 0.70710678118654752f));
        if (MODE == 3) v += res[(size_t)rowg * Ndim + col];
        if (MODE == 1 || MODE == 3) ((float*)out)[(size_t)rowg * Ndim + col] = v;
        else                        ((__bf16*)out)[(size_t)rowg * Ndim + col] = (__bf16)v;
      }
    }
  }
}

template<int MODE, int TBN>
__global__ __launch_bounds__(256)
void gemm_kernel(const __bf16* __restrict__ A, const __bf16* __restrict__ Bt,
                 const float* __restrict__ bias, const float* __restrict__ res,
                 void* __restrict__ out, int Ndim, int Kdim) {
  __shared__ alignas(16) __bf16 As[128 * 64];
  __shared__ alignas(16) __bf16 Bs[TBN * 64];
  gemm_body<MODE, TBN>(A, Bt, bias, res, out, Ndim, Kdim,
                       blockIdx.y * 128, blockIdx.x * TBN, As, Bs);
}

// --------------------------------------------------------------- GEMM 256-tile
// (round-9 validated 8-phase schedule, unchanged except fast_erf in MODE 2)
__device__ __forceinline__ void stage_a256(const __bf16* __restrict__ A, int m0,
                                           int Kdim, int tile, int h, char* Asm) {
  char* dst = Asm + (tile & 1) * 32768;
  const int kb0 = tile * 64;
  const int tid = threadIdx.x;
#pragma unroll
  for (int it = 0; it < 2; ++it) {
    int o = tid * 16 + it * 8192;
    int lrow = o >> 7, cb = o & 127;
    int r = (lrow & 63) + h * 64 + ((lrow >> 6) << 7);
    int csrc = cb ^ ((r & 7) << 4);
    gload_lds16((const char*)A + ((size_t)(m0 + r) * Kdim + kb0) * 2 + csrc,
                dst + r * 128 + cb);
  }
}
__device__ __forceinline__ void stage_b256(const __bf16* __restrict__ Bt, int n0,
                                           int Kdim, int tile, int h, char* Bsm) {
  char* dst = Bsm + (tile & 1) * 32768;
  const int kb0 = tile * 64;
  const int tid = threadIdx.x;
#pragma unroll
  for (int it = 0; it < 2; ++it) {
    int o = tid * 16 + it * 8192;
    int lrow = o >> 7, cb = o & 127;
    int r = h * 128 + lrow;
    int csrc = cb ^ ((r & 7) << 4);
    gload_lds16((const char*)Bt + ((size_t)(n0 + r) * Kdim + kb0) * 2 + csrc,
                dst + r * 128 + cb);
  }
}

template<int MODE>
__device__ __forceinline__ void gemm256_body(const __bf16* __restrict__ A,
                                             const __bf16* __restrict__ Bt,
                                             const float* __restrict__ bias,
                                             void* __restrict__ out,
                                             int Ndim, int Kdim, int m0, int n0) {
  extern __shared__ char smem[];
  char* Asm = smem;
  char* Bsm = smem + 65536;
  const int tid  = threadIdx.x;
  const int lane = tid & 63;
  const int w    = tid >> 6;
  const int wm   = w >> 2;
  const int wn   = w & 3;
  const int g    = lane >> 4;
  const int ql   = lane & 15;
  const int KT   = Kdim / 64;

  fx4 acc[8][4];
#pragma unroll
  for (int i = 0; i < 8; ++i)
#pragma unroll
    for (int j = 0; j < 4; ++j) acc[i][j] = {0.f, 0.f, 0.f, 0.f};

  stage_a256(A, m0, Kdim, 0, 0, Asm);
  stage_a256(A, m0, Kdim, 0, 1, Asm);
  stage_b256(Bt, n0, Kdim, 0, 0, Bsm);
  stage_b256(Bt, n0, Kdim, 0, 1, Bsm);
  stage_a256(A, m0, Kdim, 1, 0, Asm);
  asm volatile("s_waitcnt vmcnt(2)" ::: "memory");
  __builtin_amdgcn_s_barrier();
  __builtin_amdgcn_sched_barrier(0);

  for (int t = 0; t < KT; ++t) {
    const char* Ab = Asm + (t & 1) * 32768;
    const char* Bb = Bsm + (t & 1) * 32768;
#pragma unroll
    for (int p = 0; p < 4; ++p) {
      const int ah = p >> 1, kk = p & 1;
      if (p == 0 && t + 1 < KT) stage_a256(A, m0, Kdim, t + 1, 1, Asm);
      if (p == 1 && t + 1 < KT) stage_b256(Bt, n0, Kdim, t + 1, 0, Bsm);
      if (p == 2 && t + 1 < KT) stage_b256(Bt, n0, Kdim, t + 1, 1, Bsm);
      if (p == 3 && t + 2 < KT) stage_a256(A, m0, Kdim, t + 2, 0, Asm);
      __builtin_amdgcn_sched_barrier(0);

      bfx8 af[4], bf[4];
      const int cbv = kk * 64 + g * 16;
#pragma unroll
      for (int j = 0; j < 4; ++j) {
        int arow = wm * 128 + (ah * 4 + j) * 16 + ql;
        af[j] = *(const bfx8*)(Ab + arow * 128 + (cbv ^ ((arow & 7) << 4)));
      }
#pragma unroll
      for (int nf = 0; nf < 4; ++nf) {
        int brow = wn * 64 + nf * 16 + ql;
        bf[nf] = *(const bfx8*)(Bb + brow * 128 + (cbv ^ ((brow & 7) << 4)));
      }
      __builtin_amdgcn_sched_barrier(0);
      __builtin_amdgcn_s_barrier();
      asm volatile("s_waitcnt lgkmcnt(0)" ::: "memory");
      __builtin_amdgcn_sched_barrier(0);
      __builtin_amdgcn_s_setprio(1);
#pragma unroll
      for (int j = 0; j < 4; ++j)
#pragma unroll
        for (int nf = 0; nf < 4; ++nf)
          acc[ah * 4 + j][nf] = __builtin_amdgcn_mfma_f32_16x16x32_bf16(
              af[j], bf[nf], acc[ah * 4 + j][nf], 0, 0, 0);
      __builtin_amdgcn_s_setprio(0);
      __builtin_amdgcn_s_barrier();
      __builtin_amdgcn_sched_barrier(0);
    }
    if (t + 1 < KT) {
      if (t + 2 < KT) asm volatile("s_waitcnt vmcnt(2)" ::: "memory");
      else            asm volatile("s_waitcnt vmcnt(0)" ::: "memory");
      __builtin_amdgcn_s_barrier();
      __builtin_amdgcn_sched_barrier(0);
    }
  }

#pragma unroll
  for (int mf = 0; mf < 8; ++mf) {
#pragma unroll
    for (int nf = 0; nf < 4; ++nf) {
      int col = n0 + wn * 64 + nf * 16 + ql;
      float bvl = bias[col];
#pragma unroll
      for (int r = 0; r < 4; ++r) {
        int rowg = m0 + wm * 128 + mf * 16 + g * 4 + r;
        float v = acc[mf][nf][r] + bvl;
        if (MODE == 2) v = 0.5f * v * (1.0f + fast_erf(v * 0.70710678118654752f));
        if (MODE == 1) ((float*)out)[(size_t)rowg * Ndim + col] = v;
        else          ((__bf16*)out)[(size_t)rowg * Ndim + col] = (__bf16)v;
      }
    }
  }
}

template<int MODE>
__global__ __launch_bounds__(512)
void gemm256_kernel(const __bf16* __restrict__ A, const __bf16* __restrict__ Bt,
                    const float* __restrict__ bias, void* __restrict__ out,
                    int Ndim, int Kdim) {
  gemm256_body<MODE>(A, Bt, bias, out, Ndim, Kdim,
                     blockIdx.y * 256, blockIdx.x * 256);
}

struct QKVArgs {
  const __bf16* A[3]; const __bf16* Bt[3]; const float* bias[3]; __bf16* out[3];
};

__global__ __launch_bounds__(512)
void qkv256_kernel(QKVArgs args, int Ndim, int Kdim) {
  int z = blockIdx.z;
  gemm256_body<0>(args.A[z], args.Bt[z], args.bias[z], (void*)args.out[z],
                  Ndim, Kdim, blockIdx.y * 256, blockIdx.x * 256);
}

// --------------------------------------------------------- flash attention
// Round-12 validated (3-buf depth-2 counted pipeline, mask-in-LDS, Q/P overlay,
// log2 softmax + defer-max). This round: max/sum reductions in tree form.
__global__ __launch_bounds__(512)
void attn_kernel(const __bf16* __restrict__ Qb, const __bf16* __restrict__ Kb,
                 const __bf16* __restrict__ Vt, const float* __restrict__ mask2,
                 __bf16* __restrict__ ctx) {
  __shared__ alignas(16) __bf16 Ks[3 * 64 * 64];     // 24 KB (3-buf)
  __shared__ alignas(16) __bf16 Vs[3 * 64 * 64];     // 24 KB (3-buf)
  __shared__ alignas(16) __bf16 Ps[8 * 16 * 64];     // 16 KB (aliased by Q stage)
  __shared__ alignas(16) float  Ms[2048];            //  8 KB mask row

  const int tid  = threadIdx.x;
  const int lane = tid & 63;
  const int w    = tid >> 6;
  const int g    = lane >> 4;
  const int ql   = lane & 15;
  const int bh   = blockIdx.y;
  const int b    = bh >> 4;
  const int h    = bh & 15;
  const int q0   = blockIdx.x * 128;

  const size_t kbase  = ((size_t)(b * S_)) * D_ + h * DH_;
  const size_t vtbase = (size_t)bh * DH_ * S_;
  const int NT = S_ / 64;

  char* Qsm = (char*)Ps;                             // overlay
  const size_t qbase = ((size_t)(b * S_) + q0) * D_ + h * DH_;
#pragma unroll
  for (int i = 0; i < 2; ++i) {
    int o   = tid * 16 + i * 8192;
    int row = o >> 7, cb = o & 127;
    int cbs = cb ^ ((row & 7) << 4);
    gload_lds16((const char*)Qb + (qbase + (size_t)row * D_) * 2 + cbs, Qsm + o);
  }
  {
    int o = tid * 16;
    gload_lds16((const char*)mask2 + (size_t)b * S_ * 4 + o, (char*)Ms + o);
  }
  {
    int o   = tid * 16;
    int row = o >> 7, cb = o & 127;
    int cbs = cb ^ ((row & 7) << 4);
    gload_lds16((const char*)Kb + (kbase + (size_t)row * D_) * 2 + cbs, (char*)Ks + o);
    gload_lds16((const char*)Vt + (vtbase + (size_t)row * S_) * 2 + cbs, (char*)Vs + o);
    gload_lds16((const char*)Kb + (kbase + (size_t)(64 + row) * D_) * 2 + cbs,
                (char*)Ks + 8192 + o);
    gload_lds16((const char*)Vt + (vtbase + (size_t)row * S_ + 64) * 2 + cbs,
                (char*)Vs + 8192 + o);
  }
  asm volatile("s_waitcnt vmcnt(4)" ::: "memory");
  __builtin_amdgcn_s_barrier();
  __builtin_amdgcn_sched_barrier(0);

  bfx8 aq[2];
  {
    int row = w * 16 + ql;
#pragma unroll
    for (int kk = 0; kk < 2; ++kk) {
      int cb = kk * 64 + g * 16;
      aq[kk] = *(const bfx8*)(Qsm + row * 128 + (cb ^ ((row & 7) << 4)));
    }
  }
  __syncthreads();
  asm volatile("s_waitcnt vmcnt(2)" ::: "memory");
  __builtin_amdgcn_s_barrier();
  __builtin_amdgcn_sched_barrier(0);

  float mrun = -1e30f, lrun = 0.f;
  fx4 acc[4];
#pragma unroll
  for (int d = 0; d < 4; ++d) acc[d] = {0.f, 0.f, 0.f, 0.f};

  char* pw = (char*)Ps + w * 2048;
  const float SCL = 0.18033688f;

  for (int t = 0; t < NT; ++t) {
    const int kv0 = t * 64;
    if (t + 2 < NT) {
      int o   = tid * 16;
      int row = o >> 7, cb = o & 127;
      int cbs = cb ^ ((row & 7) << 4);
      int nkv = kv0 + 128;
      int bo  = ((t + 2) % 3) * 8192;
      gload_lds16((const char*)Kb + (kbase + (size_t)(nkv + row) * D_) * 2 + cbs,
                  (char*)Ks + bo + o);
      gload_lds16((const char*)Vt + (vtbase + (size_t)row * S_ + nkv) * 2 + cbs,
                  (char*)Vs + bo + o);
    }
    __builtin_amdgcn_sched_barrier(0);
    if (t > 0) {
      if (t + 2 < NT)      asm volatile("s_waitcnt vmcnt(4)" ::: "memory");
      else if (t + 1 < NT) asm volatile("s_waitcnt vmcnt(2)" ::: "memory");
      else                 asm volatile("s_waitcnt vmcnt(0)" ::: "memory");
      __builtin_amdgcn_s_barrier();
      __builtin_amdgcn_sched_barrier(0);
    }
    const char* Kc = (const char*)Ks + (t % 3) * 8192;
    const char* Vc = (const char*)Vs + (t % 3) * 8192;

    fx4 sc[4];
#pragma unroll
    for (int nf = 0; nf < 4; ++nf) sc[nf] = {0.f, 0.f, 0.f, 0.f};
#pragma unroll
    for (int kk = 0; kk < 2; ++kk) {
      const int cb = kk * 64 + g * 16;
      bfx8 bk[4];
#pragma unroll
      for (int nf = 0; nf < 4; ++nf) {
        int row = nf * 16 + ql;
        bk[nf] = *(const bfx8*)(Kc + row * 128 + (cb ^ ((row & 7) << 4)));
      }
#pragma unroll
      for (int nf = 0; nf < 4; ++nf)
        sc[nf] = __builtin_amdgcn_mfma_f32_16x16x32_bf16(bk[nf], aq[kk], sc[nf], 0, 0, 0);
    }

    float sv[4][4];
#pragma unroll
    for (int nf = 0; nf < 4; ++nf) {
      float4 mk = *(const float4*)((const char*)Ms + (kv0 + nf * 16 + g * 4) * 4);
      sv[nf][0] = sc[nf][0] * SCL + mk.x;
      sv[nf][1] = sc[nf][1] * SCL + mk.y;
      sv[nf][2] = sc[nf][2] * SCL + mk.z;
      sv[nf][3] = sc[nf][3] * SCL + mk.w;
    }
    // tree max (v_max3-friendly, short dep chain)
    float t0 = fmaxf(fmaxf(sv[0][0], sv[0][1]), fmaxf(sv[0][2], sv[0][3]));
    float t1 = fmaxf(fmaxf(sv[1][0], sv[1][1]), fmaxf(sv[1][2], sv[1][3]));
    float t2 = fmaxf(fmaxf(sv[2][0], sv[2][1]), fmaxf(sv[2][2], sv[2][3]));
    float t3 = fmaxf(fmaxf(sv[3][0], sv[3][1]), fmaxf(sv[3][2], sv[3][3]));
    float mx = fmaxf(fmaxf(t0, t1), fmaxf(t2, t3));
    mx = fmaxf(mx, __shfl_xor(mx, 16));
    mx = fmaxf(mx, __shfl_xor(mx, 32));

    if (!__all(mx <= mrun + 8.0f)) {
      float mnew  = fmaxf(mrun, mx);
      float alpha = fast_exp2(mrun - mnew);
      lrun *= alpha;
      float af[4];
#pragma unroll
      for (int r = 0; r < 4; ++r) af[r] = __shfl(alpha, g * 4 + r);
#pragma unroll
      for (int d = 0; d < 4; ++d)
#pragma unroll
        for (int r = 0; r < 4; ++r) acc[d][r] *= af[r];
      mrun = mnew;
    }

    float ps[4];
#pragma unroll
    for (int nf = 0; nf < 4; ++nf) {
#pragma unroll
      for (int r = 0; r < 4; ++r) sv[nf][r] = fast_exp2(sv[nf][r] - mrun);
      ps[nf] = (sv[nf][0] + sv[nf][1]) + (sv[nf][2] + sv[nf][3]);
    }
    float rs = (ps[0] + ps[1]) + (ps[2] + ps[3]);
    rs += __shfl_xor(rs, 16);
    rs += __shfl_xor(rs, 32);
    lrun += rs;

#pragma unroll
    for (int nf = 0; nf < 4; ++nf) {
      bfx4 pv;
      pv[0] = (__bf16)sv[nf][0]; pv[1] = (__bf16)sv[nf][1];
      pv[2] = (__bf16)sv[nf][2]; pv[3] = (__bf16)sv[nf][3];
      int c = (nf * 32 + g * 8) ^ ((ql & 7) << 4);
      *(bfx4*)(pw + ql * 128 + c) = pv;
    }

    asm volatile("s_waitcnt lgkmcnt(0)" ::: "memory");
    __builtin_amdgcn_sched_barrier(0);

#pragma unroll
    for (int kk = 0; kk < 2; ++kk) {
      int prow = ql;
      int cb   = kk * 64 + g * 16;
      bfx8 ap  = *(const bfx8*)((const char*)pw + prow * 128 + (cb ^ ((prow & 7) << 4)));
#pragma unroll
      for (int d = 0; d < 4; ++d) {
        int vrow = d * 16 + ql;
        bfx8 bv  = *(const bfx8*)(Vc + vrow * 128 + (cb ^ ((vrow & 7) << 4)));
        acc[d] = __builtin_amdgcn_mfma_f32_16x16x32_bf16(ap, bv, acc[d], 0, 0, 0);
      }
    }

    __builtin_amdgcn_s_barrier();
    __builtin_amdgcn_sched_barrier(0);
  }

  float linv = 1.0f / lrun;
#pragma unroll
  for (int r = 0; r < 4; ++r) {
    float inv = __shfl(linv, g * 4 + r);
    int qrow = q0 + w * 16 + g * 4 + r;
    size_t base = ((size_t)(b * S_) + qrow) * D_ + h * DH_;
#pragma unroll
    for (int d = 0; d < 4; ++d)
      ctx[base + d * 16 + ql] = (__bf16)(acc[d][r] * inv);
  }
}

// -------------------- LayerNorm over presummed input (row=1024)
template<bool WRITE_BF16>
__global__ __launch_bounds__(256)
void ln_kernel(const float* __restrict__ a,
               const float* __restrict__ g, const float* __restrict__ beta,
               float* __restrict__ outf, __bf16* __restrict__ outb) {
  const int row = blockIdx.x;
  const int tid = threadIdx.x;
  const size_t base = (size_t)row * D_;
  float4 xa = *(const float4*)(a + base + tid * 4);
  float x[4] = {xa.x, xa.y, xa.z, xa.w};
  float s = x[0] + x[1] + x[2] + x[3];
#pragma unroll
  for (int m = 1; m < 64; m <<= 1) s += __shfl_xor(s, m);
  __shared__ float red[8];
  if ((tid & 63) == 0) red[tid >> 6] = s;
  __syncthreads();
  float mu = (red[0] + red[1] + red[2] + red[3]) * (1.0f / D_);
  float v0 = 0.f;
#pragma unroll
  for (int i = 0; i < 4; ++i) { float d = x[i] - mu; v0 += d * d; }
#pragma unroll
  for (int m = 1; m < 64; m <<= 1) v0 += __shfl_xor(v0, m);
  if ((tid & 63) == 0) red[4 + (tid >> 6)] = v0;
  __syncthreads();
  float var = (red[4] + red[5] + red[6] + red[7]) * (1.0f / D_);
  float rs = rsqrtf(var + 1e-12f);
#pragma unroll
  for (int i = 0; i < 4; ++i) {
    int col = tid * 4 + i;
    x[i] = (x[i] - mu) * rs * g[col] + beta[col];
  }
  *(float4*)(outf + base + tid * 4) = make_float4(x[0], x[1], x[2], x[3]);
  if (WRITE_BF16) {
    bfx4 o;
    o[0] = (__bf16)x[0]; o[1] = (__bf16)x[1]; o[2] = (__bf16)x[2]; o[3] = (__bf16)x[3];
    *(bfx4*)(outb + base + tid * 4) = o;
  }
}

// ---------------------------------------------------------------- launch
extern "C" void kernel_launch(void* const* d_in, const int* in_sizes, int n_in,
                              void* d_out, int out_size, void* d_ws, size_t ws_size,
                              hipStream_t stream) {
  const float* query    = (const float*)d_in[0];
  const float* key_in   = (const float*)d_in[1];
  const float* value_in = (const float*)d_in[2];
  const float* mask     = (const float*)d_in[3];
  const float* Wq = (const float*)d_in[4];  const float* bq = (const float*)d_in[5];
  const float* Wk = (const float*)d_in[6];  const float* bk = (const float*)d_in[7];
  const float* Wv = (const float*)d_in[8];  const float* bv = (const float*)d_in[9];
  const float* Wo = (const float*)d_in[10]; const float* bo = (const float*)d_in[11];
  const float* ln1g = (const float*)d_in[12]; const float* ln1b = (const float*)d_in[13];
  const float* Wi = (const float*)d_in[14]; const float* bi = (const float*)d_in[15];
  const float* Wd = (const float*)d_in[16]; const float* bd = (const float*)d_in[17];
  const float* ln2g = (const float*)d_in[18]; const float* ln2b = (const float*)d_in[19];

  char* ws = (char*)d_ws;
  const size_t MB = 1ull << 20;
  if (ws_size < 112 * MB) return;

  __bf16* xq   = (__bf16*)(ws + 0 * MB);
  __bf16* xk   = (__bf16*)(ws + 8 * MB);
  __bf16* xv   = (__bf16*)(ws + 16 * MB);
  float*  alin = (float*)(ws + 0 * MB);     // presummed (acc+bias+query)
  float*  mask2= (float*)(ws + 0 * MB);     // written after qkv256 (xq dead),
                                            // dead before Wo writes alin
  __bf16* x1b  = (__bf16*)(ws + 16 * MB);
  __bf16* qb   = (__bf16*)(ws + 24 * MB);
  __bf16* kb   = (__bf16*)(ws + 32 * MB);
  __bf16* vb   = (__bf16*)(ws + 40 * MB);
  __bf16* vt   = (__bf16*)(ws + 48 * MB);
  __bf16* inter= (__bf16*)(ws + 24 * MB);
  __bf16* ctxb = (__bf16*)(ws + 56 * MB);
  float*  ff   = (float*)(ws + 56 * MB);    // presummed (acc+bias+x1f)
  float*  x1f  = (float*)(ws + 72 * MB);
  __bf16* wqt  = (__bf16*)(ws + 88 * MB);
  __bf16* wkt  = (__bf16*)(ws + 90 * MB);
  __bf16* wvt  = (__bf16*)(ws + 92 * MB);
  __bf16* wot  = (__bf16*)(ws + 94 * MB);
  __bf16* wit  = (__bf16*)(ws + 96 * MB);
  __bf16* wdt  = (__bf16*)(ws + 104 * MB);

  dim3 b256(256);
  dim3 tblk(32, 8);
  const int n1 = M_ * D_;

  CvtArgs ca;
  ca.in[0] = query; ca.in[1] = key_in; ca.in[2] = value_in;
  ca.out[0] = xq;   ca.out[1] = xk;    ca.out[2] = xv;
  to_bf16_3_kernel<<<dim3(n1 / 1024, 3), b256, 0, stream>>>(ca, n1);

  transpose_conv_kernel<<<dim3(D_ / 32, D_ / 32), tblk, 0, stream>>>(Wq, wqt, D_, D_);
  transpose_conv_kernel<<<dim3(D_ / 32, D_ / 32), tblk, 0, stream>>>(Wk, wkt, D_, D_);
  transpose_conv_kernel<<<dim3(D_ / 32, D_ / 32), tblk, 0, stream>>>(Wv, wvt, D_, D_);
  transpose_conv_kernel<<<dim3(D_ / 32, D_ / 32), tblk, 0, stream>>>(Wo, wot, D_, D_);
  transpose_conv_kernel<<<dim3(DFF_ / 32, D_ / 32), tblk, 0, stream>>>(Wi, wit, D_, DFF_);
  transpose_conv_kernel<<<dim3(D_ / 32, DFF_ / 32), tblk, 0, stream>>>(Wd, wdt, DFF_, D_);

  QKVArgs qa;
  qa.A[0] = xq;  qa.A[1] = xk;  qa.A[2] = xv;
  qa.Bt[0] = wqt; qa.Bt[1] = wkt; qa.Bt[2] = wvt;
  qa.bias[0] = bq; qa.bias[1] = bk; qa.bias[2] = bv;
  qa.out[0] = qb; qa.out[1] = kb; qa.out[2] = vb;
  qkv256_kernel<<<dim3(D_ / 256, M_ / 256, 3), dim3(512), 131072, stream>>>(qa, D_, D_);

  transpose_v_kernel<<<dim3(S_ / 32, 2, B_ * H_), tblk, 0, stream>>>(vb, vt);

  scale_mask_kernel<<<dim3((B_ * S_ + 255) / 256), b256, 0, stream>>>(mask, mask2, B_ * S_);

  attn_kernel<<<dim3(S_ / 128, B_ * H_), dim3(512), 0, stream>>>(qb, kb, vt, mask2, ctxb);

  // Wo with fused +query residual -> alin presummed
  gemm_kernel<3, 64><<<dim3(D_ / 64, M_ / 128), b256, 0, stream>>>(ctxb, wot, bo, query, (void*)alin, D_, D_);

  ln_kernel<true><<<dim3(M_), b256, 0, stream>>>(alin, ln1g, ln1b, x1f, x1b);

  gemm256_kernel<2><<<dim3(DFF_ / 256, M_ / 256), dim3(512), 131072, stream>>>(x1b, wit, bi, (void*)inter, DFF_, D_);

  // Wd with fused +x1f residual -> ff presummed
  gemm_kernel<3, 64><<<dim3(D_ / 64, M_ / 128), b256, 0, stream>>>(inter, wdt, bd, x1f, (void*)ff, D_, DFF_);

  ln_kernel<false><<<dim3(M_), b256, 0, stream>>>(ff, ln2g, ln2b, (float*)d_out, nullptr);
}

// Round 14
// 269.405 us; speedup vs baseline: 1.1389x; 1.0172x over previous
//
#include <hip/hip_runtime.h>
#include <hip/hip_bf16.h>
#include <cmath>

#define B_   2
#define S_   2048
#define D_   1024
#define H_   16
#define DFF_ 4096
#define DH_  64
#define M_   (B_*S_)   // 4096 rows

typedef __bf16 bfx8 __attribute__((ext_vector_type(8)));
typedef __bf16 bfx4 __attribute__((ext_vector_type(4)));
typedef float  fx4  __attribute__((ext_vector_type(4)));

__device__ __forceinline__ float fast_exp2(float x) {
  float r;
  asm volatile("v_exp_f32 %0, %1" : "=v"(r) : "v"(x));
  return r;
}

// Abramowitz-Stegun 7.1.26 erf (max abs err 1.5e-7; exact at bf16 granularity)
__device__ __forceinline__ float fast_erf(float x) {
  float ax = fabsf(x);
  float t  = __builtin_amdgcn_rcpf(fmaf(0.3275911f, ax, 1.0f));
  float p  = fmaf(1.061405429f, t, -1.453152027f);
  p = fmaf(p, t, 1.421413741f);
  p = fmaf(p, t, -0.284496736f);
  p = fmaf(p, t, 0.254829592f);
  p = p * t;
  float e  = fast_exp2(-ax * ax * 1.44269504f);
  float r  = 1.0f - p * e;
  return copysignf(r, x);
}

// ---------------------------------------------------------------- utilities
__device__ __forceinline__ void gload_lds16(const void* g, void* l) {
  __builtin_amdgcn_global_load_lds((__attribute__((address_space(1))) void*)(g),
                                   (__attribute__((address_space(3))) void*)(l),
                                   16, 0, 0);
}

// ---------------------------------------------- fp32 -> bf16 (3 tensors, z)
struct CvtArgs { const float* in[3]; __bf16* out[3]; };

__global__ __launch_bounds__(256)
void to_bf16_3_kernel(CvtArgs args, int n) {
  int z = blockIdx.y;
  int i = (blockIdx.x * 256 + threadIdx.x) * 4;
  if (i < n) {
    float4 v = *(const float4*)(args.in[z] + i);
    bfx4 o;
    o[0] = (__bf16)v.x; o[1] = (__bf16)v.y; o[2] = (__bf16)v.z; o[3] = (__bf16)v.w;
    *(bfx4*)(args.out[z] + i) = o;
  }
}

// ------------------------------------------------ mask * log2(e) (tiny)
__global__ __launch_bounds__(256)
void scale_mask_kernel(const float* __restrict__ in, float* __restrict__ out, int n) {
  int i = blockIdx.x * 256 + threadIdx.x;
  if (i < n) out[i] = in[i] * 1.44269504f;
}

// --------------------------------------- W [R][C] f32 -> Wt [C][R] bf16
__global__ __launch_bounds__(256)
void transpose_conv_kernel(const float* __restrict__ in, __bf16* __restrict__ out,
                           int R, int C) {
  __shared__ float t[32][33];
  int r0 = blockIdx.y * 32, c0 = blockIdx.x * 32;
  int tx = threadIdx.x, ty = threadIdx.y;   // 32 x 8
#pragma unroll
  for (int j = 0; j < 4; ++j) {
    int r = ty + j * 8;
    t[r][tx] = in[(size_t)(r0 + r) * C + c0 + tx];
  }
  __syncthreads();
#pragma unroll
  for (int j = 0; j < 4; ++j) {
    int c = ty + j * 8;
    out[(size_t)(c0 + c) * R + r0 + tx] = (__bf16)t[tx][c];
  }
}

// ----------------------- V [B,S,H,DH] bf16 -> Vt [B,H,DH,S] bf16
__global__ __launch_bounds__(256)
void transpose_v_kernel(const __bf16* __restrict__ vb, __bf16* __restrict__ vt) {
  __shared__ __bf16 t[32][33];
  int bh = blockIdx.z;
  int b = bh >> 4, h = bh & 15;
  int s0 = blockIdx.x * 32, d0 = blockIdx.y * 32;
  int tx = threadIdx.x, ty = threadIdx.y;
#pragma unroll
  for (int j = 0; j < 4; ++j) {
    int s = ty + j * 8;
    t[s][tx] = vb[(size_t)((b * S_ + s0 + s) * H_ + h) * DH_ + d0 + tx];
  }
  __syncthreads();
#pragma unroll
  for (int j = 0; j < 4; ++j) {
    int d = ty + j * 8;
    vt[(size_t)(bh * DH_ + d0 + d) * S_ + s0 + tx] = t[tx][d];
  }
}

// --------------------------------------------------------------- GEMM 128-tile
// MODE 0: bf16 out. 1: f32 out. 2: GELU bf16 out.
// MODE 4: bf16 out + bf16 residual add (res is const __bf16*).
template<int MODE, int TBN>
__device__ __forceinline__ void gemm_body(const __bf16* __restrict__ A,
                                          const __bf16* __restrict__ Bt,
                                          const float* __restrict__ bias,
                                          const void* __restrict__ res,
                                          void* __restrict__ out,
                                          int Ndim, int Kdim,
                                          int m0, int n0,
                                          __bf16* As, __bf16* Bs) {
  const int tid  = threadIdx.x;
  const int lane = tid & 63;
  const int w    = tid >> 6;
  const int wm   = w >> 1, wn = w & 1;
  constexpr int NF = TBN / 32;

  fx4 acc[4][NF];
#pragma unroll
  for (int i = 0; i < 4; ++i)
#pragma unroll
    for (int j = 0; j < NF; ++j) acc[i][j] = {0.f, 0.f, 0.f, 0.f};

  const int KT = Kdim / 64;
  for (int kt = 0; kt < KT; ++kt) {
    __syncthreads();
    const int kb0 = kt * 64;
#pragma unroll
    for (int i = 0; i < 4; ++i) {
      int o   = tid * 16 + i * 4096;
      int row = o >> 7, cb = o & 127;
      int cbs = cb ^ ((row & 7) << 4);
      gload_lds16((const char*)A + ((size_t)(m0 + row) * Kdim + kb0) * 2 + cbs,
                  (char*)As + o);
    }
#pragma unroll
    for (int i = 0; i < TBN / 32; ++i) {
      int o   = tid * 16 + i * 4096;
      int row = o >> 7, cb = o & 127;
      int cbs = cb ^ ((row & 7) << 4);
      gload_lds16((const char*)Bt + ((size_t)(n0 + row) * Kdim + kb0) * 2 + cbs,
                  (char*)Bs + o);
    }
    __syncthreads();

#pragma unroll
    for (int kk = 0; kk < 2; ++kk) {
      bfx8 afr[4], bfr[NF];
      const int cb = kk * 64 + ((lane >> 4) << 4);
#pragma unroll
      for (int mf = 0; mf < 4; ++mf) {
        int row = wm * 64 + mf * 16 + (lane & 15);
        afr[mf] = *(const bfx8*)((const char*)As + row * 128 + (cb ^ ((row & 7) << 4)));
      }
#pragma unroll
      for (int nf = 0; nf < NF; ++nf) {
        int row = wn * (TBN / 2) + nf * 16 + (lane & 15);
        bfr[nf] = *(const bfx8*)((const char*)Bs + row * 128 + (cb ^ ((row & 7) << 4)));
      }
#pragma unroll
      for (int mf = 0; mf < 4; ++mf)
#pragma unroll
        for (int nf = 0; nf < NF; ++nf)
          acc[mf][nf] = __builtin_amdgcn_mfma_f32_16x16x32_bf16(afr[mf], bfr[nf],
                                                                acc[mf][nf], 0, 0, 0);
    }
  }

#pragma unroll
  for (int mf = 0; mf < 4; ++mf) {
#pragma unroll
    for (int nf = 0; nf < NF; ++nf) {
      int col = n0 + wn * (TBN / 2) + nf * 16 + (lane & 15);
      float bvl = bias[col];
#pragma unroll
      for (int r = 0; r < 4; ++r) {
        int rowg = m0 + wm * 64 + mf * 16 + ((lane >> 4) << 2) + r;
        float v = acc[mf][nf][r] + bvl;
        if (MODE == 2) v = 0.5f * v * (1.0f + fast_erf(v * 0.70710678118654752f));
        if (MODE == 4) v += (float)((const __bf16*)res)[(size_t)rowg * Ndim + col];
        if (MODE == 1) ((float*)out)[(size_t)rowg * Ndim + col] = v;
        else           ((__bf16*)out)[(size_t)rowg * Ndim + col] = (__bf16)v;
      }
    }
  }
}

template<int MODE, int TBN>
__global__ __launch_bounds__(256)
void gemm_kernel(const __bf16* __restrict__ A, const __bf16* __restrict__ Bt,
                 const float* __restrict__ bias, const void* __restrict__ res,
                 void* __restrict__ out, int Ndim, int Kdim) {
  __shared__ alignas(16) __bf16 As[128 * 64];
  __shared__ alignas(16) __bf16 Bs[TBN * 64];
  gemm_body<MODE, TBN>(A, Bt, bias, res, out, Ndim, Kdim,
                       blockIdx.y * 128, blockIdx.x * TBN, As, Bs);
}

// --------------------------------------------------------------- GEMM 256-tile
// (round-9 validated 8-phase schedule, unchanged)
__device__ __forceinline__ void stage_a256(const __bf16* __restrict__ A, int m0,
                                           int Kdim, int tile, int h, char* Asm) {
  char* dst = Asm + (tile & 1) * 32768;
  const int kb0 = tile * 64;
  const int tid = threadIdx.x;
#pragma unroll
  for (int it = 0; it < 2; ++it) {
    int o = tid * 16 + it * 8192;
    int lrow = o >> 7, cb = o & 127;
    int r = (lrow & 63) + h * 64 + ((lrow >> 6) << 7);
    int csrc = cb ^ ((r & 7) << 4);
    gload_lds16((const char*)A + ((size_t)(m0 + r) * Kdim + kb0) * 2 + csrc,
                dst + r * 128 + cb);
  }
}
__device__ __forceinline__ void stage_b256(const __bf16* __restrict__ Bt, int n0,
                                           int Kdim, int tile, int h, char* Bsm) {
  char* dst = Bsm + (tile & 1) * 32768;
  const int kb0 = tile * 64;
  const int tid = threadIdx.x;
#pragma unroll
  for (int it = 0; it < 2; ++it) {
    int o = tid * 16 + it * 8192;
    int lrow = o >> 7, cb = o & 127;
    int r = h * 128 + lrow;
    int csrc = cb ^ ((r & 7) << 4);
    gload_lds16((const char*)Bt + ((size_t)(n0 + r) * Kdim + kb0) * 2 + csrc,
                dst + r * 128 + cb);
  }
}

template<int MODE>
__device__ __forceinline__ void gemm256_body(const __bf16* __restrict__ A,
                                             const __bf16* __restrict__ Bt,
                                             const float* __restrict__ bias,
                                             void* __restrict__ out,
                                             int Ndim, int Kdim, int m0, int n0) {
  extern __shared__ char smem[];
  char* Asm = smem;
  char* Bsm = smem + 65536;
  const int tid  = threadIdx.x;
  const int lane = tid & 63;
  const int w    = tid >> 6;
  const int wm   = w >> 2;
  const int wn   = w & 3;
  const int g    = lane >> 4;
  const int ql   = lane & 15;
  const int KT   = Kdim / 64;

  fx4 acc[8][4];
#pragma unroll
  for (int i = 0; i < 8; ++i)
#pragma unroll
    for (int j = 0; j < 4; ++j) acc[i][j] = {0.f, 0.f, 0.f, 0.f};

  stage_a256(A, m0, Kdim, 0, 0, Asm);
  stage_a256(A, m0, Kdim, 0, 1, Asm);
  stage_b256(Bt, n0, Kdim, 0, 0, Bsm);
  stage_b256(Bt, n0, Kdim, 0, 1, Bsm);
  stage_a256(A, m0, Kdim, 1, 0, Asm);
  asm volatile("s_waitcnt vmcnt(2)" ::: "memory");
  __builtin_amdgcn_s_barrier();
  __builtin_amdgcn_sched_barrier(0);

  for (int t = 0; t < KT; ++t) {
    const char* Ab = Asm + (t & 1) * 32768;
    const char* Bb = Bsm + (t & 1) * 32768;
#pragma unroll
    for (int p = 0; p < 4; ++p) {
      const int ah = p >> 1, kk = p & 1;
      if (p == 0 && t + 1 < KT) stage_a256(A, m0, Kdim, t + 1, 1, Asm);
      if (p == 1 && t + 1 < KT) stage_b256(Bt, n0, Kdim, t + 1, 0, Bsm);
      if (p == 2 && t + 1 < KT) stage_b256(Bt, n0, Kdim, t + 1, 1, Bsm);
      if (p == 3 && t + 2 < KT) stage_a256(A, m0, Kdim, t + 2, 0, Asm);
      __builtin_amdgcn_sched_barrier(0);

      bfx8 af[4], bf[4];
      const int cbv = kk * 64 + g * 16;
#pragma unroll
      for (int j = 0; j < 4; ++j) {
        int arow = wm * 128 + (ah * 4 + j) * 16 + ql;
        af[j] = *(const bfx8*)(Ab + arow * 128 + (cbv ^ ((arow & 7) << 4)));
      }
#pragma unroll
      for (int nf = 0; nf < 4; ++nf) {
        int brow = wn * 64 + nf * 16 + ql;
        bf[nf] = *(const bfx8*)(Bb + brow * 128 + (cbv ^ ((brow & 7) << 4)));
      }
      __builtin_amdgcn_sched_barrier(0);
      __builtin_amdgcn_s_barrier();
      asm volatile("s_waitcnt lgkmcnt(0)" ::: "memory");
      __builtin_amdgcn_sched_barrier(0);
      __builtin_amdgcn_s_setprio(1);
#pragma unroll
      for (int j = 0; j < 4; ++j)
#pragma unroll
        for (int nf = 0; nf < 4; ++nf)
          acc[ah * 4 + j][nf] = __builtin_amdgcn_mfma_f32_16x16x32_bf16(
              af[j], bf[nf], acc[ah * 4 + j][nf], 0, 0, 0);
      __builtin_amdgcn_s_setprio(0);
      __builtin_amdgcn_s_barrier();
      __builtin_amdgcn_sched_barrier(0);
    }
    if (t + 1 < KT) {
      if (t + 2 < KT) asm volatile("s_waitcnt vmcnt(2)" ::: "memory");
      else            asm volatile("s_waitcnt vmcnt(0)" ::: "memory");
      __builtin_amdgcn_s_barrier();
      __builtin_amdgcn_sched_barrier(0);
    }
  }

#pragma unroll
  for (int mf = 0; mf < 8; ++mf) {
#pragma unroll
    for (int nf = 0; nf < 4; ++nf) {
      int col = n0 + wn * 64 + nf * 16 + ql;
      float bvl = bias[col];
#pragma unroll
      for (int r = 0; r < 4; ++r) {
        int rowg = m0 + wm * 128 + mf * 16 + g * 4 + r;
        float v = acc[mf][nf][r] + bvl;
        if (MODE == 2) v = 0.5f * v * (1.0f + fast_erf(v * 0.70710678118654752f));
        if (MODE == 1) ((float*)out)[(size_t)rowg * Ndim + col] = v;
        else          ((__bf16*)out)[(size_t)rowg * Ndim + col] = (__bf16)v;
      }
    }
  }
}

template<int MODE>
__global__ __launch_bounds__(512)
void gemm256_kernel(const __bf16* __restrict__ A, const __bf16* __restrict__ Bt,
                    const float* __restrict__ bias, void* __restrict__ out,
                    int Ndim, int Kdim) {
  gemm256_body<MODE>(A, Bt, bias, out, Ndim, Kdim,
                     blockIdx.y * 256, blockIdx.x * 256);
}

struct QKVArgs {
  const __bf16* A[3]; const __bf16* Bt[3]; const float* bias[3]; __bf16* out[3];
};

__global__ __launch_bounds__(512)
void qkv256_kernel(QKVArgs args, int Ndim, int Kdim) {
  int z = blockIdx.z;
  gemm256_body<0>(args.A[z], args.Bt[z], args.bias[z], (void*)args.out[z],
                  Ndim, Kdim, blockIdx.y * 256, blockIdx.x * 256);
}

// --------------------------------------------------------- flash attention
// (round-13 validated, unchanged)
__global__ __launch_bounds__(512)
void attn_kernel(const __bf16* __restrict__ Qb, const __bf16* __restrict__ Kb,
                 const __bf16* __restrict__ Vt, const float* __restrict__ mask2,
                 __bf16* __restrict__ ctx) {
  __shared__ alignas(16) __bf16 Ks[3 * 64 * 64];     // 24 KB (3-buf)
  __shared__ alignas(16) __bf16 Vs[3 * 64 * 64];     // 24 KB (3-buf)
  __shared__ alignas(16) __bf16 Ps[8 * 16 * 64];     // 16 KB (aliased by Q stage)
  __shared__ alignas(16) float  Ms[2048];            //  8 KB mask row

  const int tid  = threadIdx.x;
  const int lane = tid & 63;
  const int w    = tid >> 6;
  const int g    = lane >> 4;
  const int ql   = lane & 15;
  const int bh   = blockIdx.y;
  const int b    = bh >> 4;
  const int h    = bh & 15;
  const int q0   = blockIdx.x * 128;

  const size_t kbase  = ((size_t)(b * S_)) * D_ + h * DH_;
  const size_t vtbase = (size_t)bh * DH_ * S_;
  const int NT = S_ / 64;

  char* Qsm = (char*)Ps;                             // overlay
  const size_t qbase = ((size_t)(b * S_) + q0) * D_ + h * DH_;
#pragma unroll
  for (int i = 0; i < 2; ++i) {
    int o   = tid * 16 + i * 8192;
    int row = o >> 7, cb = o & 127;
    int cbs = cb ^ ((row & 7) << 4);
    gload_lds16((const char*)Qb + (qbase + (size_t)row * D_) * 2 + cbs, Qsm + o);
  }
  {
    int o = tid * 16;
    gload_lds16((const char*)mask2 + (size_t)b * S_ * 4 + o, (char*)Ms + o);
  }
  {
    int o   = tid * 16;
    int row = o >> 7, cb = o & 127;
    int cbs = cb ^ ((row & 7) << 4);
    gload_lds16((const char*)Kb + (kbase + (size_t)row * D_) * 2 + cbs, (char*)Ks + o);
    gload_lds16((const char*)Vt + (vtbase + (size_t)row * S_) * 2 + cbs, (char*)Vs + o);
    gload_lds16((const char*)Kb + (kbase + (size_t)(64 + row) * D_) * 2 + cbs,
                (char*)Ks + 8192 + o);
    gload_lds16((const char*)Vt + (vtbase + (size_t)row * S_ + 64) * 2 + cbs,
                (char*)Vs + 8192 + o);
  }
  asm volatile("s_waitcnt vmcnt(4)" ::: "memory");
  __builtin_amdgcn_s_barrier();
  __builtin_amdgcn_sched_barrier(0);

  bfx8 aq[2];
  {
    int row = w * 16 + ql;
#pragma unroll
    for (int kk = 0; kk < 2; ++kk) {
      int cb = kk * 64 + g * 16;
      aq[kk] = *(const bfx8*)(Qsm + row * 128 + (cb ^ ((row & 7) << 4)));
    }
  }
  __syncthreads();
  asm volatile("s_waitcnt vmcnt(2)" ::: "memory");
  __builtin_amdgcn_s_barrier();
  __builtin_amdgcn_sched_barrier(0);

  float mrun = -1e30f, lrun = 0.f;
  fx4 acc[4];
#pragma unroll
  for (int d = 0; d < 4; ++d) acc[d] = {0.f, 0.f, 0.f, 0.f};

  char* pw = (char*)Ps + w * 2048;
  const float SCL = 0.18033688f;

  for (int t = 0; t < NT; ++t) {
    const int kv0 = t * 64;
    if (t + 2 < NT) {
      int o   = tid * 16;
      int row = o >> 7, cb = o & 127;
      int cbs = cb ^ ((row & 7) << 4);
      int nkv = kv0 + 128;
      int bo  = ((t + 2) % 3) * 8192;
      gload_lds16((const char*)Kb + (kbase + (size_t)(nkv + row) * D_) * 2 + cbs,
                  (char*)Ks + bo + o);
      gload_lds16((const char*)Vt + (vtbase + (size_t)row * S_ + nkv) * 2 + cbs,
                  (char*)Vs + bo + o);
    }
    __builtin_amdgcn_sched_barrier(0);
    if (t > 0) {
      if (t + 2 < NT)      asm volatile("s_waitcnt vmcnt(4)" ::: "memory");
      else if (t + 1 < NT) asm volatile("s_waitcnt vmcnt(2)" ::: "memory");
      else                 asm volatile("s_waitcnt vmcnt(0)" ::: "memory");
      __builtin_amdgcn_s_barrier();
      __builtin_amdgcn_sched_barrier(0);
    }
    const char* Kc = (const char*)Ks + (t % 3) * 8192;
    const char* Vc = (const char*)Vs + (t % 3) * 8192;

    fx4 sc[4];
#pragma unroll
    for (int nf = 0; nf < 4; ++nf) sc[nf] = {0.f, 0.f, 0.f, 0.f};
#pragma unroll
    for (int kk = 0; kk < 2; ++kk) {
      const int cb = kk * 64 + g * 16;
      bfx8 bk[4];
#pragma unroll
      for (int nf = 0; nf < 4; ++nf) {
        int row = nf * 16 + ql;
        bk[nf] = *(const bfx8*)(Kc + row * 128 + (cb ^ ((row & 7) << 4)));
      }
#pragma unroll
      for (int nf = 0; nf < 4; ++nf)
        sc[nf] = __builtin_amdgcn_mfma_f32_16x16x32_bf16(bk[nf], aq[kk], sc[nf], 0, 0, 0);
    }

    float sv[4][4];
#pragma unroll
    for (int nf = 0; nf < 4; ++nf) {
      float4 mk = *(const float4*)((const char*)Ms + (kv0 + nf * 16 + g * 4) * 4);
      sv[nf][0] = sc[nf][0] * SCL + mk.x;
      sv[nf][1] = sc[nf][1] * SCL + mk.y;
      sv[nf][2] = sc[nf][2] * SCL + mk.z;
      sv[nf][3] = sc[nf][3] * SCL + mk.w;
    }
    float t0 = fmaxf(fmaxf(sv[0][0], sv[0][1]), fmaxf(sv[0][2], sv[0][3]));
    float t1 = fmaxf(fmaxf(sv[1][0], sv[1][1]), fmaxf(sv[1][2], sv[1][3]));
    float t2 = fmaxf(fmaxf(sv[2][0], sv[2][1]), fmaxf(sv[2][2], sv[2][3]));
    float t3 = fmaxf(fmaxf(sv[3][0], sv[3][1]), fmaxf(sv[3][2], sv[3][3]));
    float mx = fmaxf(fmaxf(t0, t1), fmaxf(t2, t3));
    mx = fmaxf(mx, __shfl_xor(mx, 16));
    mx = fmaxf(mx, __shfl_xor(mx, 32));

    if (!__all(mx <= mrun + 8.0f)) {
      float mnew  = fmaxf(mrun, mx);
      float alpha = fast_exp2(mrun - mnew);
      lrun *= alpha;
      float af[4];
#pragma unroll
      for (int r = 0; r < 4; ++r) af[r] = __shfl(alpha, g * 4 + r);
#pragma unroll
      for (int d = 0; d < 4; ++d)
#pragma unroll
        for (int r = 0; r < 4; ++r) acc[d][r] *= af[r];
      mrun = mnew;
    }

    float ps[4];
#pragma unroll
    for (int nf = 0; nf < 4; ++nf) {
#pragma unroll
      for (int r = 0; r < 4; ++r) sv[nf][r] = fast_exp2(sv[nf][r] - mrun);
      ps[nf] = (sv[nf][0] + sv[nf][1]) + (sv[nf][2] + sv[nf][3]);
    }
    float rs = (ps[0] + ps[1]) + (ps[2] + ps[3]);
    rs += __shfl_xor(rs, 16);
    rs += __shfl_xor(rs, 32);
    lrun += rs;

#pragma unroll
    for (int nf = 0; nf < 4; ++nf) {
      bfx4 pv;
      pv[0] = (__bf16)sv[nf][0]; pv[1] = (__bf16)sv[nf][1];
      pv[2] = (__bf16)sv[nf][2]; pv[3] = (__bf16)sv[nf][3];
      int c = (nf * 32 + g * 8) ^ ((ql & 7) << 4);
      *(bfx4*)(pw + ql * 128 + c) = pv;
    }

    asm volatile("s_waitcnt lgkmcnt(0)" ::: "memory");
    __builtin_amdgcn_sched_barrier(0);

#pragma unroll
    for (int kk = 0; kk < 2; ++kk) {
      int prow = ql;
      int cb   = kk * 64 + g * 16;
      bfx8 ap  = *(const bfx8*)((const char*)pw + prow * 128 + (cb ^ ((prow & 7) << 4)));
#pragma unroll
      for (int d = 0; d < 4; ++d) {
        int vrow = d * 16 + ql;
        bfx8 bv  = *(const bfx8*)(Vc + vrow * 128 + (cb ^ ((vrow & 7) << 4)));
        acc[d] = __builtin_amdgcn_mfma_f32_16x16x32_bf16(ap, bv, acc[d], 0, 0, 0);
      }
    }

    __builtin_amdgcn_s_barrier();
    __builtin_amdgcn_sched_barrier(0);
  }

  float linv = 1.0f / lrun;
#pragma unroll
  for (int r = 0; r < 4; ++r) {
    float inv = __shfl(linv, g * 4 + r);
    int qrow = q0 + w * 16 + g * 4 + r;
    size_t base = ((size_t)(b * S_) + qrow) * D_ + h * DH_;
#pragma unroll
    for (int d = 0; d < 4; ++d)
      ctx[base + d * 16 + ql] = (__bf16)(acc[d][r] * inv);
  }
}

// -------------------- LayerNorm over presummed bf16 input (row=1024)
template<bool WRITE_BF16>
__global__ __launch_bounds__(256)
void ln_kernel(const __bf16* __restrict__ a,
               const float* __restrict__ g, const float* __restrict__ beta,
               float* __restrict__ outf, __bf16* __restrict__ outb) {
  const int row = blockIdx.x;
  const int tid = threadIdx.x;
  const size_t base = (size_t)row * D_;
  bfx4 xa = *(const bfx4*)(a + base + tid * 4);
  float x[4] = {(float)xa[0], (float)xa[1], (float)xa[2], (float)xa[3]};
  float s = x[0] + x[1] + x[2] + x[3];
#pragma unroll
  for (int m = 1; m < 64; m <<= 1) s += __shfl_xor(s, m);
  __shared__ float red[8];
  if ((tid & 63) == 0) red[tid >> 6] = s;
  __syncthreads();
  float mu = (red[0] + red[1] + red[2] + red[3]) * (1.0f / D_);
  float v0 = 0.f;
#pragma unroll
  for (int i = 0; i < 4; ++i) { float d = x[i] - mu; v0 += d * d; }
#pragma unroll
  for (int m = 1; m < 64; m <<= 1) v0 += __shfl_xor(v0, m);
  if ((tid & 63) == 0) red[4 + (tid >> 6)] = v0;
  __syncthreads();
  float var = (red[4] + red[5] + red[6] + red[7]) * (1.0f / D_);
  float rs = rsqrtf(var + 1e-12f);
#pragma unroll
  for (int i = 0; i < 4; ++i) {
    int col = tid * 4 + i;
    x[i] = (x[i] - mu) * rs * g[col] + beta[col];
  }
  if (WRITE_BF16) {
    bfx4 o;
    o[0] = (__bf16)x[0]; o[1] = (__bf16)x[1]; o[2] = (__bf16)x[2]; o[3] = (__bf16)x[3];
    *(bfx4*)(outb + base + tid * 4) = o;
  } else {
    *(float4*)(outf + base + tid * 4) = make_float4(x[0], x[1], x[2], x[3]);
  }
}

// ---------------------------------------------------------------- launch
extern "C" void kernel_launch(void* const* d_in, const int* in_sizes, int n_in,
                              void* d_out, int out_size, void* d_ws, size_t ws_size,
                              hipStream_t stream) {
  const float* query    = (const float*)d_in[0];
  const float* key_in   = (const float*)d_in[1];
  const float* value_in = (const float*)d_in[2];
  const float* mask     = (const float*)d_in[3];
  const float* Wq = (const float*)d_in[4];  const float* bq = (const float*)d_in[5];
  const float* Wk = (const float*)d_in[6];  const float* bk = (const float*)d_in[7];
  const float* Wv = (const float*)d_in[8];  const float* bv = (const float*)d_in[9];
  const float* Wo = (const float*)d_in[10]; const float* bo = (const float*)d_in[11];
  const float* ln1g = (const float*)d_in[12]; const float* ln1b = (const float*)d_in[13];
  const float* Wi = (const float*)d_in[14]; const float* bi = (const float*)d_in[15];
  const float* Wd = (const float*)d_in[16]; const float* bd = (const float*)d_in[17];
  const float* ln2g = (const float*)d_in[18]; const float* ln2b = (const float*)d_in[19];

  char* ws = (char*)d_ws;
  const size_t MB = 1ull << 20;
  if (ws_size < 112 * MB) return;

  // liveness-audited layout (bf16 intermediate chain):
  __bf16* xq   = (__bf16*)(ws + 0 * MB);    // alive: cvt -> Wo residual
  __bf16* xk   = (__bf16*)(ws + 8 * MB);    // dead after qkv256
  float*  mask2= (float*)(ws + 8 * MB);     // 16 KB; written after qkv256
  __bf16* xv   = (__bf16*)(ws + 16 * MB);   // dead after qkv256
  __bf16* x1b  = (__bf16*)(ws + 16 * MB);   // LN1 out; Wi input + Wd residual
  __bf16* qb   = (__bf16*)(ws + 24 * MB);   // dead after attn
  __bf16* inter= (__bf16*)(ws + 24 * MB);   // Wi out (24-56); after LN1
  __bf16* kb   = (__bf16*)(ws + 32 * MB);   // dead after attn
  __bf16* vb   = (__bf16*)(ws + 40 * MB);   // dead after transpose_v
  __bf16* alinb= (__bf16*)(ws + 40 * MB);   // Wo out (8MB); dead after LN1
  __bf16* vt   = (__bf16*)(ws + 48 * MB);   // dead after attn
  __bf16* ctxb = (__bf16*)(ws + 56 * MB);   // dead after Wo
  __bf16* ffb  = (__bf16*)(ws + 56 * MB);   // Wd out (8MB); after Wo
  __bf16* wqt  = (__bf16*)(ws + 88 * MB);
  __bf16* wkt  = (__bf16*)(ws + 90 * MB);
  __bf16* wvt  = (__bf16*)(ws + 92 * MB);
  __bf16* wot  = (__bf16*)(ws + 94 * MB);
  __bf16* wit  = (__bf16*)(ws + 96 * MB);
  __bf16* wdt  = (__bf16*)(ws + 104 * MB);

  dim3 b256(256);
  dim3 tblk(32, 8);
  const int n1 = M_ * D_;

  CvtArgs ca;
  ca.in[0] = query; ca.in[1] = key_in; ca.in[2] = value_in;
  ca.out[0] = xq;   ca.out[1] = xk;    ca.out[2] = xv;
  to_bf16_3_kernel<<<dim3(n1 / 1024, 3), b256, 0, stream>>>(ca, n1);

  transpose_conv_kernel<<<dim3(D_ / 32, D_ / 32), tblk, 0, stream>>>(Wq, wqt, D_, D_);
  transpose_conv_kernel<<<dim3(D_ / 32, D_ / 32), tblk, 0, stream>>>(Wk, wkt, D_, D_);
  transpose_conv_kernel<<<dim3(D_ / 32, D_ / 32), tblk, 0, stream>>>(Wv, wvt, D_, D_);
  transpose_conv_kernel<<<dim3(D_ / 32, D_ / 32), tblk, 0, stream>>>(Wo, wot, D_, D_);
  transpose_conv_kernel<<<dim3(DFF_ / 32, D_ / 32), tblk, 0, stream>>>(Wi, wit, D_, DFF_);
  transpose_conv_kernel<<<dim3(D_ / 32, DFF_ / 32), tblk, 0, stream>>>(Wd, wdt, DFF_, D_);

  QKVArgs qa;
  qa.A[0] = xq;  qa.A[1] = xk;  qa.A[2] = xv;
  qa.Bt[0] = wqt; qa.Bt[1] = wkt; qa.Bt[2] = wvt;
  qa.bias[0] = bq; qa.bias[1] = bk; qa.bias[2] = bv;
  qa.out[0] = qb; qa.out[1] = kb; qa.out[2] = vb;
  qkv256_kernel<<<dim3(D_ / 256, M_ / 256, 3), dim3(512), 131072, stream>>>(qa, D_, D_);

  transpose_v_kernel<<<dim3(S_ / 32, 2, B_ * H_), tblk, 0, stream>>>(vb, vt);

  scale_mask_kernel<<<dim3((B_ * S_ + 255) / 256), b256, 0, stream>>>(mask, mask2, B_ * S_);

  attn_kernel<<<dim3(S_ / 128, B_ * H_), dim3(512), 0, stream>>>(qb, kb, vt, mask2, ctxb);

  // Wo with fused +query residual (bf16 xq) -> alinb bf16
  gemm_kernel<4, 64><<<dim3(D_ / 64, M_ / 128), b256, 0, stream>>>(ctxb, wot, bo, xq, (void*)alinb, D_, D_);

  ln_kernel<true><<<dim3(M_), b256, 0, stream>>>(alinb, ln1g, ln1b, nullptr, x1b);

  gemm256_kernel<2><<<dim3(DFF_ / 256, M_ / 256), dim3(512), 131072, stream>>>(x1b, wit, bi, (void*)inter, DFF_, D_);

  // Wd with fused +x1b residual (bf16) -> ffb bf16
  gemm_kernel<4, 64><<<dim3(D_ / 64, M_ / 128), b256, 0, stream>>>(inter, wdt, bd, x1b, (void*)ffb, D_, DFF_);

  ln_kernel<false><<<dim3(M_), b256, 0, stream>>>(ffb, ln2g, ln2b, (float*)d_out, nullptr);
}

// Round 15
// 257.307 us; speedup vs baseline: 1.1924x; 1.0470x over previous
//
#include <hip/hip_runtime.h>
#include <hip/hip_bf16.h>
#include <cmath>

#define B_   2
#define S_   2048
#define D_   1024
#define H_   16
#define DFF_ 4096
#define DH_  64
#define M_   (B_*S_)   // 4096 rows

typedef __bf16 bfx8 __attribute__((ext_vector_type(8)));
typedef __bf16 bfx4 __attribute__((ext_vector_type(4)));
typedef float  fx4  __attribute__((ext_vector_type(4)));

__device__ __forceinline__ float fast_exp2(float x) {
  float r;
  asm volatile("v_exp_f32 %0, %1" : "=v"(r) : "v"(x));
  return r;
}

// Abramowitz-Stegun 7.1.26 erf (max abs err 1.5e-7; exact at bf16 granularity)
__device__ __forceinline__ float fast_erf(float x) {
  float ax = fabsf(x);
  float t  = __builtin_amdgcn_rcpf(fmaf(0.3275911f, ax, 1.0f));
  float p  = fmaf(1.061405429f, t, -1.453152027f);
  p = fmaf(p, t, 1.421413741f);
  p = fmaf(p, t, -0.284496736f);
  p = fmaf(p, t, 0.254829592f);
  p = p * t;
  float e  = fast_exp2(-ax * ax * 1.44269504f);
  float r  = 1.0f - p * e;
  return copysignf(r, x);
}

// ---------------------------------------------------------------- utilities
__device__ __forceinline__ void gload_lds16(const void* g, void* l) {
  __builtin_amdgcn_global_load_lds((__attribute__((address_space(1))) void*)(g),
                                   (__attribute__((address_space(3))) void*)(l),
                                   16, 0, 0);
}

// ---------------------------------------------- fp32 -> bf16 (3 tensors, z)
struct CvtArgs { const float* in[3]; __bf16* out[3]; };

__global__ __launch_bounds__(256)
void to_bf16_3_kernel(CvtArgs args, int n) {
  int z = blockIdx.y;
  int i = (blockIdx.x * 256 + threadIdx.x) * 4;
  if (i < n) {
    float4 v = *(const float4*)(args.in[z] + i);
    bfx4 o;
    o[0] = (__bf16)v.x; o[1] = (__bf16)v.y; o[2] = (__bf16)v.z; o[3] = (__bf16)v.w;
    *(bfx4*)(args.out[z] + i) = o;
  }
}

// ------------------------------------------------ mask * log2(e) (tiny)
__global__ __launch_bounds__(256)
void scale_mask_kernel(const float* __restrict__ in, float* __restrict__ out, int n) {
  int i = blockIdx.x * 256 + threadIdx.x;
  if (i < n) out[i] = in[i] * 1.44269504f;
}

// ------------------- ALL weight transposes in ONE launch (12288 tiles)
// tiles: [0,4096) 4x DxD (Wq,Wk,Wv,Wo); [4096,8192) Wi (D x DFF);
// [8192,12288) Wd (DFF x D). Each block transposes one 32x32 tile.
struct TrArgs { const float* in[6]; __bf16* out[6]; };

__global__ __launch_bounds__(256)
void transpose_all_kernel(TrArgs a) {
  __shared__ float t[32][33];
  int bid = blockIdx.x;
  int wsel, tr, tc, R, C;
  if (bid < 4096) {
    wsel = bid >> 10; int l = bid & 1023;
    tr = l >> 5; tc = l & 31; R = D_; C = D_;
  } else if (bid < 8192) {
    wsel = 4; int l = bid - 4096;
    tr = l >> 7; tc = l & 127; R = D_; C = DFF_;
  } else {
    wsel = 5; int l = bid - 8192;
    tr = l >> 5; tc = l & 31; R = DFF_; C = D_;
  }
  const float* in = a.in[wsel];
  __bf16* out = a.out[wsel];
  int r0 = tr * 32, c0 = tc * 32;
  int tx = threadIdx.x & 31, ty = threadIdx.x >> 5;   // 32 x 8
#pragma unroll
  for (int j = 0; j < 4; ++j) {
    int r = ty + j * 8;
    t[r][tx] = in[(size_t)(r0 + r) * C + c0 + tx];
  }
  __syncthreads();
#pragma unroll
  for (int j = 0; j < 4; ++j) {
    int c = ty + j * 8;
    out[(size_t)(c0 + c) * R + r0 + tx] = (__bf16)t[tx][c];
  }
}

// ----------------------- V [B,S,H,DH] bf16 -> Vt [B,H,DH,S] bf16
__global__ __launch_bounds__(256)
void transpose_v_kernel(const __bf16* __restrict__ vb, __bf16* __restrict__ vt) {
  __shared__ __bf16 t[32][33];
  int bh = blockIdx.z;
  int b = bh >> 4, h = bh & 15;
  int s0 = blockIdx.x * 32, d0 = blockIdx.y * 32;
  int tx = threadIdx.x, ty = threadIdx.y;
#pragma unroll
  for (int j = 0; j < 4; ++j) {
    int s = ty + j * 8;
    t[s][tx] = vb[(size_t)((b * S_ + s0 + s) * H_ + h) * DH_ + d0 + tx];
  }
  __syncthreads();
#pragma unroll
  for (int j = 0; j < 4; ++j) {
    int d = ty + j * 8;
    vt[(size_t)(bh * DH_ + d0 + d) * S_ + s0 + tx] = t[tx][d];
  }
}

// --------------------------------------------------------------- GEMM 128-tile
// Double-buffered, counted-vmcnt pipeline (round-8 attn recipe applied here).
// MODE 0: bf16 out. 1: f32 out. 2: GELU bf16 out.
// MODE 4: bf16 out + bf16 residual add (res is const __bf16*).
// Per-thread loads per K-tile = 4 (A) + TBN/32 (B); only staging VMEM in-loop.
template<int MODE, int TBN>
__global__ __launch_bounds__(256)
void gemm_kernel(const __bf16* __restrict__ A, const __bf16* __restrict__ Bt,
                 const float* __restrict__ bias, const void* __restrict__ res,
                 void* __restrict__ out, int Ndim, int Kdim) {
  __shared__ alignas(16) __bf16 As[2 * 128 * 64];   // 32 KB
  __shared__ alignas(16) __bf16 Bs[2 * TBN * 64];   // TBN=64: 16 KB
  const int tid  = threadIdx.x;
  const int lane = tid & 63;
  const int w    = tid >> 6;
  const int wm   = w >> 1, wn = w & 1;
  constexpr int NF = TBN / 32;
  const int m0 = blockIdx.y * 128, n0 = blockIdx.x * TBN;

  fx4 acc[4][NF];
#pragma unroll
  for (int i = 0; i < 4; ++i)
#pragma unroll
    for (int j = 0; j < NF; ++j) acc[i][j] = {0.f, 0.f, 0.f, 0.f};

  const int KT = Kdim / 64;

  auto stage = [&](int kt, int buf) {
    const int kb0 = kt * 64;
#pragma unroll
    for (int i = 0; i < 4; ++i) {
      int o   = tid * 16 + i * 4096;
      int row = o >> 7, cb = o & 127;
      int cbs = cb ^ ((row & 7) << 4);
      gload_lds16((const char*)A + ((size_t)(m0 + row) * Kdim + kb0) * 2 + cbs,
                  (char*)As + buf * 16384 + o);
    }
#pragma unroll
    for (int i = 0; i < NF; ++i) {
      int o   = tid * 16 + i * 4096;
      int row = o >> 7, cb = o & 127;
      int cbs = cb ^ ((row & 7) << 4);
      gload_lds16((const char*)Bt + ((size_t)(n0 + row) * Kdim + kb0) * 2 + cbs,
                  (char*)Bs + buf * (TBN * 128) + o);
    }
  };

  stage(0, 0);
  asm volatile("s_waitcnt vmcnt(0)" ::: "memory");
  __builtin_amdgcn_s_barrier();
  __builtin_amdgcn_sched_barrier(0);

  for (int kt = 0; kt < KT; ++kt) {
    if (kt + 1 < KT) stage(kt + 1, (kt + 1) & 1);
    __builtin_amdgcn_sched_barrier(0);
    if (kt > 0) {                 // tile kt landed when only stage(kt+1) remains
      if (kt + 1 < KT) {
        if constexpr (TBN == 64) asm volatile("s_waitcnt vmcnt(6)" ::: "memory");
        else                     asm volatile("s_waitcnt vmcnt(8)" ::: "memory");
      } else {
        asm volatile("s_waitcnt vmcnt(0)" ::: "memory");
      }
      __builtin_amdgcn_s_barrier();
      __builtin_amdgcn_sched_barrier(0);
    }
    const char* Ab = (const char*)As + (kt & 1) * 16384;
    const char* Bb = (const char*)Bs + (kt & 1) * (TBN * 128);

#pragma unroll
    for (int kk = 0; kk < 2; ++kk) {
      bfx8 afr[4], bfr[NF];
      const int cb = kk * 64 + ((lane >> 4) << 4);
#pragma unroll
      for (int mf = 0; mf < 4; ++mf) {
        int row = wm * 64 + mf * 16 + (lane & 15);
        afr[mf] = *(const bfx8*)(Ab + row * 128 + (cb ^ ((row & 7) << 4)));
      }
#pragma unroll
      for (int nf = 0; nf < NF; ++nf) {
        int row = wn * (TBN / 2) + nf * 16 + (lane & 15);
        bfr[nf] = *(const bfx8*)(Bb + row * 128 + (cb ^ ((row & 7) << 4)));
      }
#pragma unroll
      for (int mf = 0; mf < 4; ++mf)
#pragma unroll
        for (int nf = 0; nf < NF; ++nf)
          acc[mf][nf] = __builtin_amdgcn_mfma_f32_16x16x32_bf16(afr[mf], bfr[nf],
                                                                acc[mf][nf], 0, 0, 0);
    }
    __builtin_amdgcn_s_barrier();   // raw: buf kt&1 reads retired before reuse
    __builtin_amdgcn_sched_barrier(0);
  }

#pragma unroll
  for (int mf = 0; mf < 4; ++mf) {
#pragma unroll
    for (int nf = 0; nf < NF; ++nf) {
      int col = n0 + wn * (TBN / 2) + nf * 16 + (lane & 15);
      float bvl = bias[col];
#pragma unroll
      for (int r = 0; r < 4; ++r) {
        int rowg = m0 + wm * 64 + mf * 16 + ((lane >> 4) << 2) + r;
        float v = acc[mf][nf][r] + bvl;
        if (MODE == 2) v = 0.5f * v * (1.0f + fast_erf(v * 0.70710678118654752f));
        if (MODE == 4) v += (float)((const __bf16*)res)[(size_t)rowg * Ndim + col];
        if (MODE == 1) ((float*)out)[(size_t)rowg * Ndim + col] = v;
        else           ((__bf16*)out)[(size_t)rowg * Ndim + col] = (__bf16)v;
      }
    }
  }
}

// --------------------------------------------------------------- GEMM 256-tile
// (round-9 validated 8-phase schedule, unchanged)
__device__ __forceinline__ void stage_a256(const __bf16* __restrict__ A, int m0,
                                           int Kdim, int tile, int h, char* Asm) {
  char* dst = Asm + (tile & 1) * 32768;
  const int kb0 = tile * 64;
  const int tid = threadIdx.x;
#pragma unroll
  for (int it = 0; it < 2; ++it) {
    int o = tid * 16 + it * 8192;
    int lrow = o >> 7, cb = o & 127;
    int r = (lrow & 63) + h * 64 + ((lrow >> 6) << 7);
    int csrc = cb ^ ((r & 7) << 4);
    gload_lds16((const char*)A + ((size_t)(m0 + r) * Kdim + kb0) * 2 + csrc,
                dst + r * 128 + cb);
  }
}
__device__ __forceinline__ void stage_b256(const __bf16* __restrict__ Bt, int n0,
                                           int Kdim, int tile, int h, char* Bsm) {
  char* dst = Bsm + (tile & 1) * 32768;
  const int kb0 = tile * 64;
  const int tid = threadIdx.x;
#pragma unroll
  for (int it = 0; it < 2; ++it) {
    int o = tid * 16 + it * 8192;
    int lrow = o >> 7, cb = o & 127;
    int r = h * 128 + lrow;
    int csrc = cb ^ ((r & 7) << 4);
    gload_lds16((const char*)Bt + ((size_t)(n0 + r) * Kdim + kb0) * 2 + csrc,
                dst + r * 128 + cb);
  }
}

template<int MODE>
__device__ __forceinline__ void gemm256_body(const __bf16* __restrict__ A,
                                             const __bf16* __restrict__ Bt,
                                             const float* __restrict__ bias,
                                             void* __restrict__ out,
                                             int Ndim, int Kdim, int m0, int n0) {
  extern __shared__ char smem[];
  char* Asm = smem;
  char* Bsm = smem + 65536;
  const int tid  = threadIdx.x;
  const int lane = tid & 63;
  const int w    = tid >> 6;
  const int wm   = w >> 2;
  const int wn   = w & 3;
  const int g    = lane >> 4;
  const int ql   = lane & 15;
  const int KT   = Kdim / 64;

  fx4 acc[8][4];
#pragma unroll
  for (int i = 0; i < 8; ++i)
#pragma unroll
    for (int j = 0; j < 4; ++j) acc[i][j] = {0.f, 0.f, 0.f, 0.f};

  stage_a256(A, m0, Kdim, 0, 0, Asm);
  stage_a256(A, m0, Kdim, 0, 1, Asm);
  stage_b256(Bt, n0, Kdim, 0, 0, Bsm);
  stage_b256(Bt, n0, Kdim, 0, 1, Bsm);
  stage_a256(A, m0, Kdim, 1, 0, Asm);
  asm volatile("s_waitcnt vmcnt(2)" ::: "memory");
  __builtin_amdgcn_s_barrier();
  __builtin_amdgcn_sched_barrier(0);

  for (int t = 0; t < KT; ++t) {
    const char* Ab = Asm + (t & 1) * 32768;
    const char* Bb = Bsm + (t & 1) * 32768;
#pragma unroll
    for (int p = 0; p < 4; ++p) {
      const int ah = p >> 1, kk = p & 1;
      if (p == 0 && t + 1 < KT) stage_a256(A, m0, Kdim, t + 1, 1, Asm);
      if (p == 1 && t + 1 < KT) stage_b256(Bt, n0, Kdim, t + 1, 0, Bsm);
      if (p == 2 && t + 1 < KT) stage_b256(Bt, n0, Kdim, t + 1, 1, Bsm);
      if (p == 3 && t + 2 < KT) stage_a256(A, m0, Kdim, t + 2, 0, Asm);
      __builtin_amdgcn_sched_barrier(0);

      bfx8 af[4], bf[4];
      const int cbv = kk * 64 + g * 16;
#pragma unroll
      for (int j = 0; j < 4; ++j) {
        int arow = wm * 128 + (ah * 4 + j) * 16 + ql;
        af[j] = *(const bfx8*)(Ab + arow * 128 + (cbv ^ ((arow & 7) << 4)));
      }
#pragma unroll
      for (int nf = 0; nf < 4; ++nf) {
        int brow = wn * 64 + nf * 16 + ql;
        bf[nf] = *(const bfx8*)(Bb + brow * 128 + (cbv ^ ((brow & 7) << 4)));
      }
      __builtin_amdgcn_sched_barrier(0);
      __builtin_amdgcn_s_barrier();
      asm volatile("s_waitcnt lgkmcnt(0)" ::: "memory");
      __builtin_amdgcn_sched_barrier(0);
      __builtin_amdgcn_s_setprio(1);
#pragma unroll
      for (int j = 0; j < 4; ++j)
#pragma unroll
        for (int nf = 0; nf < 4; ++nf)
          acc[ah * 4 + j][nf] = __builtin_amdgcn_mfma_f32_16x16x32_bf16(
              af[j], bf[nf], acc[ah * 4 + j][nf], 0, 0, 0);
      __builtin_amdgcn_s_setprio(0);
      __builtin_amdgcn_s_barrier();
      __builtin_amdgcn_sched_barrier(0);
    }
    if (t + 1 < KT) {
      if (t + 2 < KT) asm volatile("s_waitcnt vmcnt(2)" ::: "memory");
      else            asm volatile("s_waitcnt vmcnt(0)" ::: "memory");
      __builtin_amdgcn_s_barrier();
      __builtin_amdgcn_sched_barrier(0);
    }
  }

#pragma unroll
  for (int mf = 0; mf < 8; ++mf) {
#pragma unroll
    for (int nf = 0; nf < 4; ++nf) {
      int col = n0 + wn * 64 + nf * 16 + ql;
      float bvl = bias[col];
#pragma unroll
      for (int r = 0; r < 4; ++r) {
        int rowg = m0 + wm * 128 + mf * 16 + g * 4 + r;
        float v = acc[mf][nf][r] + bvl;
        if (MODE == 2) v = 0.5f * v * (1.0f + fast_erf(v * 0.70710678118654752f));
        if (MODE == 1) ((float*)out)[(size_t)rowg * Ndim + col] = v;
        else          ((__bf16*)out)[(size_t)rowg * Ndim + col] = (__bf16)v;
      }
    }
  }
}

template<int MODE>
__global__ __launch_bounds__(512)
void gemm256_kernel(const __bf16* __restrict__ A, const __bf16* __restrict__ Bt,
                    const float* __restrict__ bias, void* __restrict__ out,
                    int Ndim, int Kdim) {
  gemm256_body<MODE>(A, Bt, bias, out, Ndim, Kdim,
                     blockIdx.y * 256, blockIdx.x * 256);
}

struct QKVArgs {
  const __bf16* A[3]; const __bf16* Bt[3]; const float* bias[3]; __bf16* out[3];
};

__global__ __launch_bounds__(512)
void qkv256_kernel(QKVArgs args, int Ndim, int Kdim) {
  int z = blockIdx.z;
  gemm256_body<0>(args.A[z], args.Bt[z], args.bias[z], (void*)args.out[z],
                  Ndim, Kdim, blockIdx.y * 256, blockIdx.x * 256);
}

// --------------------------------------------------------- flash attention
// (round-14 validated, unchanged)
__global__ __launch_bounds__(512)
void attn_kernel(const __bf16* __restrict__ Qb, const __bf16* __restrict__ Kb,
                 const __bf16* __restrict__ Vt, const float* __restrict__ mask2,
                 __bf16* __restrict__ ctx) {
  __shared__ alignas(16) __bf16 Ks[3 * 64 * 64];     // 24 KB (3-buf)
  __shared__ alignas(16) __bf16 Vs[3 * 64 * 64];     // 24 KB (3-buf)
  __shared__ alignas(16) __bf16 Ps[8 * 16 * 64];     // 16 KB (aliased by Q stage)
  __shared__ alignas(16) float  Ms[2048];            //  8 KB mask row

  const int tid  = threadIdx.x;
  const int lane = tid & 63;
  const int w    = tid >> 6;
  const int g    = lane >> 4;
  const int ql   = lane & 15;
  const int bh   = blockIdx.y;
  const int b    = bh >> 4;
  const int h    = bh & 15;
  const int q0   = blockIdx.x * 128;

  const size_t kbase  = ((size_t)(b * S_)) * D_ + h * DH_;
  const size_t vtbase = (size_t)bh * DH_ * S_;
  const int NT = S_ / 64;

  char* Qsm = (char*)Ps;                             // overlay
  const size_t qbase = ((size_t)(b * S_) + q0) * D_ + h * DH_;
#pragma unroll
  for (int i = 0; i < 2; ++i) {
    int o   = tid * 16 + i * 8192;
    int row = o >> 7, cb = o & 127;
    int cbs = cb ^ ((row & 7) << 4);
    gload_lds16((const char*)Qb + (qbase + (size_t)row * D_) * 2 + cbs, Qsm + o);
  }
  {
    int o = tid * 16;
    gload_lds16((const char*)mask2 + (size_t)b * S_ * 4 + o, (char*)Ms + o);
  }
  {
    int o   = tid * 16;
    int row = o >> 7, cb = o & 127;
    int cbs = cb ^ ((row & 7) << 4);
    gload_lds16((const char*)Kb + (kbase + (size_t)row * D_) * 2 + cbs, (char*)Ks + o);
    gload_lds16((const char*)Vt + (vtbase + (size_t)row * S_) * 2 + cbs, (char*)Vs + o);
    gload_lds16((const char*)Kb + (kbase + (size_t)(64 + row) * D_) * 2 + cbs,
                (char*)Ks + 8192 + o);
    gload_lds16((const char*)Vt + (vtbase + (size_t)row * S_ + 64) * 2 + cbs,
                (char*)Vs + 8192 + o);
  }
  asm volatile("s_waitcnt vmcnt(4)" ::: "memory");
  __builtin_amdgcn_s_barrier();
  __builtin_amdgcn_sched_barrier(0);

  bfx8 aq[2];
  {
    int row = w * 16 + ql;
#pragma unroll
    for (int kk = 0; kk < 2; ++kk) {
      int cb = kk * 64 + g * 16;
      aq[kk] = *(const bfx8*)(Qsm + row * 128 + (cb ^ ((row & 7) << 4)));
    }
  }
  __syncthreads();
  asm volatile("s_waitcnt vmcnt(2)" ::: "memory");
  __builtin_amdgcn_s_barrier();
  __builtin_amdgcn_sched_barrier(0);

  float mrun = -1e30f, lrun = 0.f;
  fx4 acc[4];
#pragma unroll
  for (int d = 0; d < 4; ++d) acc[d] = {0.f, 0.f, 0.f, 0.f};

  char* pw = (char*)Ps + w * 2048;
  const float SCL = 0.18033688f;

  for (int t = 0; t < NT; ++t) {
    const int kv0 = t * 64;
    if (t + 2 < NT) {
      int o   = tid * 16;
      int row = o >> 7, cb = o & 127;
      int cbs = cb ^ ((row & 7) << 4);
      int nkv = kv0 + 128;
      int bo  = ((t + 2) % 3) * 8192;
      gload_lds16((const char*)Kb + (kbase + (size_t)(nkv + row) * D_) * 2 + cbs,
                  (char*)Ks + bo + o);
      gload_lds16((const char*)Vt + (vtbase + (size_t)row * S_ + nkv) * 2 + cbs,
                  (char*)Vs + bo + o);
    }
    __builtin_amdgcn_sched_barrier(0);
    if (t > 0) {
      if (t + 2 < NT)      asm volatile("s_waitcnt vmcnt(4)" ::: "memory");
      else if (t + 1 < NT) asm volatile("s_waitcnt vmcnt(2)" ::: "memory");
      else                 asm volatile("s_waitcnt vmcnt(0)" ::: "memory");
      __builtin_amdgcn_s_barrier();
      __builtin_amdgcn_sched_barrier(0);
    }
    const char* Kc = (const char*)Ks + (t % 3) * 8192;
    const char* Vc = (const char*)Vs + (t % 3) * 8192;

    fx4 sc[4];
#pragma unroll
    for (int nf = 0; nf < 4; ++nf) sc[nf] = {0.f, 0.f, 0.f, 0.f};
#pragma unroll
    for (int kk = 0; kk < 2; ++kk) {
      const int cb = kk * 64 + g * 16;
      bfx8 bk[4];
#pragma unroll
      for (int nf = 0; nf < 4; ++nf) {
        int row = nf * 16 + ql;
        bk[nf] = *(const bfx8*)(Kc + row * 128 + (cb ^ ((row & 7) << 4)));
      }
#pragma unroll
      for (int nf = 0; nf < 4; ++nf)
        sc[nf] = __builtin_amdgcn_mfma_f32_16x16x32_bf16(bk[nf], aq[kk], sc[nf], 0, 0, 0);
    }

    float sv[4][4];
#pragma unroll
    for (int nf = 0; nf < 4; ++nf) {
      float4 mk = *(const float4*)((const char*)Ms + (kv0 + nf * 16 + g * 4) * 4);
      sv[nf][0] = sc[nf][0] * SCL + mk.x;
      sv[nf][1] = sc[nf][1] * SCL + mk.y;
      sv[nf][2] = sc[nf][2] * SCL + mk.z;
      sv[nf][3] = sc[nf][3] * SCL + mk.w;
    }
    float t0 = fmaxf(fmaxf(sv[0][0], sv[0][1]), fmaxf(sv[0][2], sv[0][3]));
    float t1 = fmaxf(fmaxf(sv[1][0], sv[1][1]), fmaxf(sv[1][2], sv[1][3]));
    float t2 = fmaxf(fmaxf(sv[2][0], sv[2][1]), fmaxf(sv[2][2], sv[2][3]));
    float t3 = fmaxf(fmaxf(sv[3][0], sv[3][1]), fmaxf(sv[3][2], sv[3][3]));
    float mx = fmaxf(fmaxf(t0, t1), fmaxf(t2, t3));
    mx = fmaxf(mx, __shfl_xor(mx, 16));
    mx = fmaxf(mx, __shfl_xor(mx, 32));

    if (!__all(mx <= mrun + 8.0f)) {
      float mnew  = fmaxf(mrun, mx);
      float alpha = fast_exp2(mrun - mnew);
      lrun *= alpha;
      float af[4];
#pragma unroll
      for (int r = 0; r < 4; ++r) af[r] = __shfl(alpha, g * 4 + r);
#pragma unroll
      for (int d = 0; d < 4; ++d)
#pragma unroll
        for (int r = 0; r < 4; ++r) acc[d][r] *= af[r];
      mrun = mnew;
    }

    float ps[4];
#pragma unroll
    for (int nf = 0; nf < 4; ++nf) {
#pragma unroll
      for (int r = 0; r < 4; ++r) sv[nf][r] = fast_exp2(sv[nf][r] - mrun);
      ps[nf] = (sv[nf][0] + sv[nf][1]) + (sv[nf][2] + sv[nf][3]);
    }
    float rs = (ps[0] + ps[1]) + (ps[2] + ps[3]);
    rs += __shfl_xor(rs, 16);
    rs += __shfl_xor(rs, 32);
    lrun += rs;

#pragma unroll
    for (int nf = 0; nf < 4; ++nf) {
      bfx4 pv;
      pv[0] = (__bf16)sv[nf][0]; pv[1] = (__bf16)sv[nf][1];
      pv[2] = (__bf16)sv[nf][2]; pv[3] = (__bf16)sv[nf][3];
      int c = (nf * 32 + g * 8) ^ ((ql & 7) << 4);
      *(bfx4*)(pw + ql * 128 + c) = pv;
    }

    asm volatile("s_waitcnt lgkmcnt(0)" ::: "memory");
    __builtin_amdgcn_sched_barrier(0);

#pragma unroll
    for (int kk = 0; kk < 2; ++kk) {
      int prow = ql;
      int cb   = kk * 64 + g * 16;
      bfx8 ap  = *(const bfx8*)((const char*)pw + prow * 128 + (cb ^ ((prow & 7) << 4)));
#pragma unroll
      for (int d = 0; d < 4; ++d) {
        int vrow = d * 16 + ql;
        bfx8 bv  = *(const bfx8*)(Vc + vrow * 128 + (cb ^ ((vrow & 7) << 4)));
        acc[d] = __builtin_amdgcn_mfma_f32_16x16x32_bf16(ap, bv, acc[d], 0, 0, 0);
      }
    }

    __builtin_amdgcn_s_barrier();
    __builtin_amdgcn_sched_barrier(0);
  }

  float linv = 1.0f / lrun;
#pragma unroll
  for (int r = 0; r < 4; ++r) {
    float inv = __shfl(linv, g * 4 + r);
    int qrow = q0 + w * 16 + g * 4 + r;
    size_t base = ((size_t)(b * S_) + qrow) * D_ + h * DH_;
#pragma unroll
    for (int d = 0; d < 4; ++d)
      ctx[base + d * 16 + ql] = (__bf16)(acc[d][r] * inv);
  }
}

// -------------------- LayerNorm over presummed bf16 input (row=1024)
template<bool WRITE_BF16>
__global__ __launch_bounds__(256)
void ln_kernel(const __bf16* __restrict__ a,
               const float* __restrict__ g, const float* __restrict__ beta,
               float* __restrict__ outf, __bf16* __restrict__ outb) {
  const int row = blockIdx.x;
  const int tid = threadIdx.x;
  const size_t base = (size_t)row * D_;
  bfx4 xa = *(const bfx4*)(a + base + tid * 4);
  float x[4] = {(float)xa[0], (float)xa[1], (float)xa[2], (float)xa[3]};
  float s = x[0] + x[1] + x[2] + x[3];
#pragma unroll
  for (int m = 1; m < 64; m <<= 1) s += __shfl_xor(s, m);
  __shared__ float red[8];
  if ((tid & 63) == 0) red[tid >> 6] = s;
  __syncthreads();
  float mu = (red[0] + red[1] + red[2] + red[3]) * (1.0f / D_);
  float v0 = 0.f;
#pragma unroll
  for (int i = 0; i < 4; ++i) { float d = x[i] - mu; v0 += d * d; }
#pragma unroll
  for (int m = 1; m < 64; m <<= 1) v0 += __shfl_xor(v0, m);
  if ((tid & 63) == 0) red[4 + (tid >> 6)] = v0;
  __syncthreads();
  float var = (red[4] + red[5] + red[6] + red[7]) * (1.0f / D_);
  float rs = rsqrtf(var + 1e-12f);
#pragma unroll
  for (int i = 0; i < 4; ++i) {
    int col = tid * 4 + i;
    x[i] = (x[i] - mu) * rs * g[col] + beta[col];
  }
  if (WRITE_BF16) {
    bfx4 o;
    o[0] = (__bf16)x[0]; o[1] = (__bf16)x[1]; o[2] = (__bf16)x[2]; o[3] = (__bf16)x[3];
    *(bfx4*)(outb + base + tid * 4) = o;
  } else {
    *(float4*)(outf + base + tid * 4) = make_float4(x[0], x[1], x[2], x[3]);
  }
}

// ---------------------------------------------------------------- launch
extern "C" void kernel_launch(void* const* d_in, const int* in_sizes, int n_in,
                              void* d_out, int out_size, void* d_ws, size_t ws_size,
                              hipStream_t stream) {
  const float* query    = (const float*)d_in[0];
  const float* key_in   = (const float*)d_in[1];
  const float* value_in = (const float*)d_in[2];
  const float* mask     = (const float*)d_in[3];
  const float* Wq = (const float*)d_in[4];  const float* bq = (const float*)d_in[5];
  const float* Wk = (const float*)d_in[6];  const float* bk = (const float*)d_in[7];
  const float* Wv = (const float*)d_in[8];  const float* bv = (const float*)d_in[9];
  const float* Wo = (const float*)d_in[10]; const float* bo = (const float*)d_in[11];
  const float* ln1g = (const float*)d_in[12]; const float* ln1b = (const float*)d_in[13];
  const float* Wi = (const float*)d_in[14]; const float* bi = (const float*)d_in[15];
  const float* Wd = (const float*)d_in[16]; const float* bd = (const float*)d_in[17];
  const float* ln2g = (const float*)d_in[18]; const float* ln2b = (const float*)d_in[19];

  char* ws = (char*)d_ws;
  const size_t MB = 1ull << 20;
  if (ws_size < 112 * MB) return;

  // liveness-audited layout (bf16 intermediate chain):
  __bf16* xq   = (__bf16*)(ws + 0 * MB);    // alive: cvt -> Wo residual
  __bf16* xk   = (__bf16*)(ws + 8 * MB);    // dead after qkv256
  float*  mask2= (float*)(ws + 8 * MB);     // 16 KB; written after qkv256
  __bf16* xv   = (__bf16*)(ws + 16 * MB);   // dead after qkv256
  __bf16* x1b  = (__bf16*)(ws + 16 * MB);   // LN1 out; Wi input + Wd residual
  __bf16* qb   = (__bf16*)(ws + 24 * MB);   // dead after attn
  __bf16* inter= (__bf16*)(ws + 24 * MB);   // Wi out (24-56); after LN1
  __bf16* kb   = (__bf16*)(ws + 32 * MB);   // dead after attn
  __bf16* vb   = (__bf16*)(ws + 40 * MB);   // dead after transpose_v
  __bf16* alinb= (__bf16*)(ws + 40 * MB);   // Wo out (8MB); dead after LN1
  __bf16* vt   = (__bf16*)(ws + 48 * MB);   // dead after attn
  __bf16* ctxb = (__bf16*)(ws + 56 * MB);   // dead after Wo
  __bf16* ffb  = (__bf16*)(ws + 56 * MB);   // Wd out (8MB); after Wo
  __bf16* wqt  = (__bf16*)(ws + 88 * MB);
  __bf16* wkt  = (__bf16*)(ws + 90 * MB);
  __bf16* wvt  = (__bf16*)(ws + 92 * MB);
  __bf16* wot  = (__bf16*)(ws + 94 * MB);
  __bf16* wit  = (__bf16*)(ws + 96 * MB);
  __bf16* wdt  = (__bf16*)(ws + 104 * MB);

  dim3 b256(256);
  dim3 tblk(32, 8);
  const int n1 = M_ * D_;

  CvtArgs ca;
  ca.in[0] = query; ca.in[1] = key_in; ca.in[2] = value_in;
  ca.out[0] = xq;   ca.out[1] = xk;    ca.out[2] = xv;
  to_bf16_3_kernel<<<dim3(n1 / 1024, 3), b256, 0, stream>>>(ca, n1);

  TrArgs ta;
  ta.in[0] = Wq; ta.in[1] = Wk; ta.in[2] = Wv; ta.in[3] = Wo; ta.in[4] = Wi; ta.in[5] = Wd;
  ta.out[0] = wqt; ta.out[1] = wkt; ta.out[2] = wvt; ta.out[3] = wot;
  ta.out[4] = wit; ta.out[5] = wdt;
  transpose_all_kernel<<<dim3(12288), b256, 0, stream>>>(ta);

  QKVArgs qa;
  qa.A[0] = xq;  qa.A[1] = xk;  qa.A[2] = xv;
  qa.Bt[0] = wqt; qa.Bt[1] = wkt; qa.Bt[2] = wvt;
  qa.bias[0] = bq; qa.bias[1] = bk; qa.bias[2] = bv;
  qa.out[0] = qb; qa.out[1] = kb; qa.out[2] = vb;
  qkv256_kernel<<<dim3(D_ / 256, M_ / 256, 3), dim3(512), 131072, stream>>>(qa, D_, D_);

  transpose_v_kernel<<<dim3(S_ / 32, 2, B_ * H_), tblk, 0, stream>>>(vb, vt);

  scale_mask_kernel<<<dim3((B_ * S_ + 255) / 256), b256, 0, stream>>>(mask, mask2, B_ * S_);

  attn_kernel<<<dim3(S_ / 128, B_ * H_), dim3(512), 0, stream>>>(qb, kb, vt, mask2, ctxb);

  // Wo with fused +query residual (bf16 xq) -> alinb bf16
  gemm_kernel<4, 64><<<dim3(D_ / 64, M_ / 128), b256, 0, stream>>>(ctxb, wot, bo, xq, (void*)alinb, D_, D_);

  ln_kernel<true><<<dim3(M_), b256, 0, stream>>>(alinb, ln1g, ln1b, nullptr, x1b);

  gemm256_kernel<2><<<dim3(DFF_ / 256, M_ / 256), dim3(512), 131072, stream>>>(x1b, wit, bi, (void*)inter, DFF_, D_);

  // Wd with fused +x1b residual (bf16) -> ffb bf16
  gemm_kernel<4, 64><<<dim3(D_ / 64, M_ / 128), b256, 0, stream>>>(inter, wdt, bd, x1b, (void*)ffb, D_, DFF_);

  ln_kernel<false><<<dim3(M_), b256, 0, stream>>>(ffb, ln2g, ln2b, (float*)d_out, nullptr);
}

// Round 16
// 250.765 us; speedup vs baseline: 1.2235x; 1.0261x over previous
//
#include <hip/hip_runtime.h>
#include <hip/hip_bf16.h>
#include <cmath>

#define B_   2
#define S_   2048
#define D_   1024
#define H_   16
#define DFF_ 4096
#define DH_  64
#define M_   (B_*S_)   // 4096 rows

typedef __bf16 bfx8 __attribute__((ext_vector_type(8)));
typedef __bf16 bfx4 __attribute__((ext_vector_type(4)));
typedef float  fx4  __attribute__((ext_vector_type(4)));

__device__ __forceinline__ float fast_exp2(float x) {
  float r;
  asm volatile("v_exp_f32 %0, %1" : "=v"(r) : "v"(x));
  return r;
}

// Abramowitz-Stegun 7.1.26 erf (max abs err 1.5e-7; exact at bf16 granularity)
__device__ __forceinline__ float fast_erf(float x) {
  float ax = fabsf(x);
  float t  = __builtin_amdgcn_rcpf(fmaf(0.3275911f, ax, 1.0f));
  float p  = fmaf(1.061405429f, t, -1.453152027f);
  p = fmaf(p, t, 1.421413741f);
  p = fmaf(p, t, -0.284496736f);
  p = fmaf(p, t, 0.254829592f);
  p = p * t;
  float e  = fast_exp2(-ax * ax * 1.44269504f);
  float r  = 1.0f - p * e;
  return copysignf(r, x);
}

// ---------------------------------------------------------------- utilities
__device__ __forceinline__ void gload_lds16(const void* g, void* l) {
  __builtin_amdgcn_global_load_lds((__attribute__((address_space(1))) void*)(g),
                                   (__attribute__((address_space(3))) void*)(l),
                                   16, 0, 0);
}

// --------------- combined preprocessing: 6 weight transposes + 3 fp32->bf16
// blocks [0,12288): 32x32 transpose tiles (Wq,Wk,Wv,Wo 4096 | Wi 4096 | Wd 4096)
// blocks [12288, 24576): cvt, 4096 blocks per tensor, 1024 elems per block.
struct PrepArgs {
  const float* win[6]; __bf16* wout[6];
  const float* cin[3]; __bf16* cout[3];
};

__global__ __launch_bounds__(256)
void prep_kernel(PrepArgs a) {
  int bid = blockIdx.x;
  if (bid < 12288) {
    __shared__ float t[32][33];
    int wsel, tr, tc, R, C;
    if (bid < 4096) {
      wsel = bid >> 10; int l = bid & 1023;
      tr = l >> 5; tc = l & 31; R = D_; C = D_;
    } else if (bid < 8192) {
      wsel = 4; int l = bid - 4096;
      tr = l >> 7; tc = l & 127; R = D_; C = DFF_;
    } else {
      wsel = 5; int l = bid - 8192;
      tr = l >> 5; tc = l & 31; R = DFF_; C = D_;
    }
    const float* in = a.win[wsel];
    __bf16* out = a.wout[wsel];
    int r0 = tr * 32, c0 = tc * 32;
    int tx = threadIdx.x & 31, ty = threadIdx.x >> 5;   // 32 x 8
#pragma unroll
    for (int j = 0; j < 4; ++j) {
      int r = ty + j * 8;
      t[r][tx] = in[(size_t)(r0 + r) * C + c0 + tx];
    }
    __syncthreads();
#pragma unroll
    for (int j = 0; j < 4; ++j) {
      int c = ty + j * 8;
      out[(size_t)(c0 + c) * R + r0 + tx] = (__bf16)t[tx][c];
    }
  } else {
    int l = bid - 12288;
    int z = l >> 12;                      // 0..2
    int i = ((l & 4095) * 256 + threadIdx.x) * 4;
    float4 v = *(const float4*)(a.cin[z] + i);
    bfx4 o;
    o[0] = (__bf16)v.x; o[1] = (__bf16)v.y; o[2] = (__bf16)v.z; o[3] = (__bf16)v.w;
    *(bfx4*)(a.cout[z] + i) = o;
  }
}

// ----------------------- V [B,S,H,DH] bf16 -> Vt [B,H,DH,S] bf16
__global__ __launch_bounds__(256)
void transpose_v_kernel(const __bf16* __restrict__ vb, __bf16* __restrict__ vt) {
  __shared__ __bf16 t[32][33];
  int bh = blockIdx.z;
  int b = bh >> 4, h = bh & 15;
  int s0 = blockIdx.x * 32, d0 = blockIdx.y * 32;
  int tx = threadIdx.x, ty = threadIdx.y;
#pragma unroll
  for (int j = 0; j < 4; ++j) {
    int s = ty + j * 8;
    t[s][tx] = vb[(size_t)((b * S_ + s0 + s) * H_ + h) * DH_ + d0 + tx];
  }
  __syncthreads();
#pragma unroll
  for (int j = 0; j < 4; ++j) {
    int d = ty + j * 8;
    vt[(size_t)(bh * DH_ + d0 + d) * S_ + s0 + tx] = t[tx][d];
  }
}

// --------------------------------------------------------------- GEMM 128-tile
// Double-buffered, counted-vmcnt (round-15 validated).
// MODE 0: bf16 out. 1: f32 out. 2: GELU bf16 out. 4: bf16 out + bf16 residual.
template<int MODE, int TBN>
__global__ __launch_bounds__(256)
void gemm_kernel(const __bf16* __restrict__ A, const __bf16* __restrict__ Bt,
                 const float* __restrict__ bias, const void* __restrict__ res,
                 void* __restrict__ out, int Ndim, int Kdim) {
  __shared__ alignas(16) __bf16 As[2 * 128 * 64];   // 32 KB
  __shared__ alignas(16) __bf16 Bs[2 * TBN * 64];   // TBN=64: 16 KB
  const int tid  = threadIdx.x;
  const int lane = tid & 63;
  const int w    = tid >> 6;
  const int wm   = w >> 1, wn = w & 1;
  constexpr int NF = TBN / 32;
  const int m0 = blockIdx.y * 128, n0 = blockIdx.x * TBN;

  fx4 acc[4][NF];
#pragma unroll
  for (int i = 0; i < 4; ++i)
#pragma unroll
    for (int j = 0; j < NF; ++j) acc[i][j] = {0.f, 0.f, 0.f, 0.f};

  const int KT = Kdim / 64;

  auto stage = [&](int kt, int buf) {
    const int kb0 = kt * 64;
#pragma unroll
    for (int i = 0; i < 4; ++i) {
      int o   = tid * 16 + i * 4096;
      int row = o >> 7, cb = o & 127;
      int cbs = cb ^ ((row & 7) << 4);
      gload_lds16((const char*)A + ((size_t)(m0 + row) * Kdim + kb0) * 2 + cbs,
                  (char*)As + buf * 16384 + o);
    }
#pragma unroll
    for (int i = 0; i < NF; ++i) {
      int o   = tid * 16 + i * 4096;
      int row = o >> 7, cb = o & 127;
      int cbs = cb ^ ((row & 7) << 4);
      gload_lds16((const char*)Bt + ((size_t)(n0 + row) * Kdim + kb0) * 2 + cbs,
                  (char*)Bs + buf * (TBN * 128) + o);
    }
  };

  stage(0, 0);
  asm volatile("s_waitcnt vmcnt(0)" ::: "memory");
  __builtin_amdgcn_s_barrier();
  __builtin_amdgcn_sched_barrier(0);

  for (int kt = 0; kt < KT; ++kt) {
    if (kt + 1 < KT) stage(kt + 1, (kt + 1) & 1);
    __builtin_amdgcn_sched_barrier(0);
    if (kt > 0) {
      if (kt + 1 < KT) {
        if constexpr (TBN == 64) asm volatile("s_waitcnt vmcnt(6)" ::: "memory");
        else                     asm volatile("s_waitcnt vmcnt(8)" ::: "memory");
      } else {
        asm volatile("s_waitcnt vmcnt(0)" ::: "memory");
      }
      __builtin_amdgcn_s_barrier();
      __builtin_amdgcn_sched_barrier(0);
    }
    const char* Ab = (const char*)As + (kt & 1) * 16384;
    const char* Bb = (const char*)Bs + (kt & 1) * (TBN * 128);

#pragma unroll
    for (int kk = 0; kk < 2; ++kk) {
      bfx8 afr[4], bfr[NF];
      const int cb = kk * 64 + ((lane >> 4) << 4);
#pragma unroll
      for (int mf = 0; mf < 4; ++mf) {
        int row = wm * 64 + mf * 16 + (lane & 15);
        afr[mf] = *(const bfx8*)(Ab + row * 128 + (cb ^ ((row & 7) << 4)));
      }
#pragma unroll
      for (int nf = 0; nf < NF; ++nf) {
        int row = wn * (TBN / 2) + nf * 16 + (lane & 15);
        bfr[nf] = *(const bfx8*)(Bb + row * 128 + (cb ^ ((row & 7) << 4)));
      }
#pragma unroll
      for (int mf = 0; mf < 4; ++mf)
#pragma unroll
        for (int nf = 0; nf < NF; ++nf)
          acc[mf][nf] = __builtin_amdgcn_mfma_f32_16x16x32_bf16(afr[mf], bfr[nf],
                                                                acc[mf][nf], 0, 0, 0);
    }
    __builtin_amdgcn_s_barrier();
    __builtin_amdgcn_sched_barrier(0);
  }

#pragma unroll
  for (int mf = 0; mf < 4; ++mf) {
#pragma unroll
    for (int nf = 0; nf < NF; ++nf) {
      int col = n0 + wn * (TBN / 2) + nf * 16 + (lane & 15);
      float bvl = bias[col];
#pragma unroll
      for (int r = 0; r < 4; ++r) {
        int rowg = m0 + wm * 64 + mf * 16 + ((lane >> 4) << 2) + r;
        float v = acc[mf][nf][r] + bvl;
        if (MODE == 2) v = 0.5f * v * (1.0f + fast_erf(v * 0.70710678118654752f));
        if (MODE == 4) v += (float)((const __bf16*)res)[(size_t)rowg * Ndim + col];
        if (MODE == 1) ((float*)out)[(size_t)rowg * Ndim + col] = v;
        else           ((__bf16*)out)[(size_t)rowg * Ndim + col] = (__bf16)v;
      }
    }
  }
}

// --------------------------------------------------------------- GEMM 256-tile
// (round-9 validated 8-phase schedule, unchanged)
__device__ __forceinline__ void stage_a256(const __bf16* __restrict__ A, int m0,
                                           int Kdim, int tile, int h, char* Asm) {
  char* dst = Asm + (tile & 1) * 32768;
  const int kb0 = tile * 64;
  const int tid = threadIdx.x;
#pragma unroll
  for (int it = 0; it < 2; ++it) {
    int o = tid * 16 + it * 8192;
    int lrow = o >> 7, cb = o & 127;
    int r = (lrow & 63) + h * 64 + ((lrow >> 6) << 7);
    int csrc = cb ^ ((r & 7) << 4);
    gload_lds16((const char*)A + ((size_t)(m0 + r) * Kdim + kb0) * 2 + csrc,
                dst + r * 128 + cb);
  }
}
__device__ __forceinline__ void stage_b256(const __bf16* __restrict__ Bt, int n0,
                                           int Kdim, int tile, int h, char* Bsm) {
  char* dst = Bsm + (tile & 1) * 32768;
  const int kb0 = tile * 64;
  const int tid = threadIdx.x;
#pragma unroll
  for (int it = 0; it < 2; ++it) {
    int o = tid * 16 + it * 8192;
    int lrow = o >> 7, cb = o & 127;
    int r = h * 128 + lrow;
    int csrc = cb ^ ((r & 7) << 4);
    gload_lds16((const char*)Bt + ((size_t)(n0 + r) * Kdim + kb0) * 2 + csrc,
                dst + r * 128 + cb);
  }
}

template<int MODE>
__device__ __forceinline__ void gemm256_body(const __bf16* __restrict__ A,
                                             const __bf16* __restrict__ Bt,
                                             const float* __restrict__ bias,
                                             void* __restrict__ out,
                                             int Ndim, int Kdim, int m0, int n0) {
  extern __shared__ char smem[];
  char* Asm = smem;
  char* Bsm = smem + 65536;
  const int tid  = threadIdx.x;
  const int lane = tid & 63;
  const int w    = tid >> 6;
  const int wm   = w >> 2;
  const int wn   = w & 3;
  const int g    = lane >> 4;
  const int ql   = lane & 15;
  const int KT   = Kdim / 64;

  fx4 acc[8][4];
#pragma unroll
  for (int i = 0; i < 8; ++i)
#pragma unroll
    for (int j = 0; j < 4; ++j) acc[i][j] = {0.f, 0.f, 0.f, 0.f};

  stage_a256(A, m0, Kdim, 0, 0, Asm);
  stage_a256(A, m0, Kdim, 0, 1, Asm);
  stage_b256(Bt, n0, Kdim, 0, 0, Bsm);
  stage_b256(Bt, n0, Kdim, 0, 1, Bsm);
  stage_a256(A, m0, Kdim, 1, 0, Asm);
  asm volatile("s_waitcnt vmcnt(2)" ::: "memory");
  __builtin_amdgcn_s_barrier();
  __builtin_amdgcn_sched_barrier(0);

  for (int t = 0; t < KT; ++t) {
    const char* Ab = Asm + (t & 1) * 32768;
    const char* Bb = Bsm + (t & 1) * 32768;
#pragma unroll
    for (int p = 0; p < 4; ++p) {
      const int ah = p >> 1, kk = p & 1;
      if (p == 0 && t + 1 < KT) stage_a256(A, m0, Kdim, t + 1, 1, Asm);
      if (p == 1 && t + 1 < KT) stage_b256(Bt, n0, Kdim, t + 1, 0, Bsm);
      if (p == 2 && t + 1 < KT) stage_b256(Bt, n0, Kdim, t + 1, 1, Bsm);
      if (p == 3 && t + 2 < KT) stage_a256(A, m0, Kdim, t + 2, 0, Asm);
      __builtin_amdgcn_sched_barrier(0);

      bfx8 af[4], bf[4];
      const int cbv = kk * 64 + g * 16;
#pragma unroll
      for (int j = 0; j < 4; ++j) {
        int arow = wm * 128 + (ah * 4 + j) * 16 + ql;
        af[j] = *(const bfx8*)(Ab + arow * 128 + (cbv ^ ((arow & 7) << 4)));
      }
#pragma unroll
      for (int nf = 0; nf < 4; ++nf) {
        int brow = wn * 64 + nf * 16 + ql;
        bf[nf] = *(const bfx8*)(Bb + brow * 128 + (cbv ^ ((brow & 7) << 4)));
      }
      __builtin_amdgcn_sched_barrier(0);
      __builtin_amdgcn_s_barrier();
      asm volatile("s_waitcnt lgkmcnt(0)" ::: "memory");
      __builtin_amdgcn_sched_barrier(0);
      __builtin_amdgcn_s_setprio(1);
#pragma unroll
      for (int j = 0; j < 4; ++j)
#pragma unroll
        for (int nf = 0; nf < 4; ++nf)
          acc[ah * 4 + j][nf] = __builtin_amdgcn_mfma_f32_16x16x32_bf16(
              af[j], bf[nf], acc[ah * 4 + j][nf], 0, 0, 0);
      __builtin_amdgcn_s_setprio(0);
      __builtin_amdgcn_s_barrier();
      __builtin_amdgcn_sched_barrier(0);
    }
    if (t + 1 < KT) {
      if (t + 2 < KT) asm volatile("s_waitcnt vmcnt(2)" ::: "memory");
      else            asm volatile("s_waitcnt vmcnt(0)" ::: "memory");
      __builtin_amdgcn_s_barrier();
      __builtin_amdgcn_sched_barrier(0);
    }
  }

#pragma unroll
  for (int mf = 0; mf < 8; ++mf) {
#pragma unroll
    for (int nf = 0; nf < 4; ++nf) {
      int col = n0 + wn * 64 + nf * 16 + ql;
      float bvl = bias[col];
#pragma unroll
      for (int r = 0; r < 4; ++r) {
        int rowg = m0 + wm * 128 + mf * 16 + g * 4 + r;
        float v = acc[mf][nf][r] + bvl;
        if (MODE == 2) v = 0.5f * v * (1.0f + fast_erf(v * 0.70710678118654752f));
        if (MODE == 1) ((float*)out)[(size_t)rowg * Ndim + col] = v;
        else          ((__bf16*)out)[(size_t)rowg * Ndim + col] = (__bf16)v;
      }
    }
  }
}

template<int MODE>
__global__ __launch_bounds__(512)
void gemm256_kernel(const __bf16* __restrict__ A, const __bf16* __restrict__ Bt,
                    const float* __restrict__ bias, void* __restrict__ out,
                    int Ndim, int Kdim) {
  gemm256_body<MODE>(A, Bt, bias, out, Ndim, Kdim,
                     blockIdx.y * 256, blockIdx.x * 256);
}

struct QKVArgs {
  const __bf16* A[3]; const __bf16* Bt[3]; const float* bias[3]; __bf16* out[3];
};

__global__ __launch_bounds__(512)
void qkv256_kernel(QKVArgs args, int Ndim, int Kdim) {
  int z = blockIdx.z;
  gemm256_body<0>(args.A[z], args.Bt[z], args.bias[z], (void*)args.out[z],
                  Ndim, Kdim, blockIdx.y * 256, blockIdx.x * 256);
}

// --------------------------------------------------------- flash attention
// Round-15 skeleton + this round: (1) MFMA row-sum via all-ones B (denominator
// in accumulator; no sum-reduce, no finalize shfl); (2) setprio around MFMA
// clusters; (3) raw mask loaded + log2e-scaled in LDS (scale_mask kernel gone).
__global__ __launch_bounds__(512)
void attn_kernel(const __bf16* __restrict__ Qb, const __bf16* __restrict__ Kb,
                 const __bf16* __restrict__ Vt, const float* __restrict__ mask,
                 __bf16* __restrict__ ctx) {
  __shared__ alignas(16) __bf16 Ks[3 * 64 * 64];     // 24 KB (3-buf)
  __shared__ alignas(16) __bf16 Vs[3 * 64 * 64];     // 24 KB (3-buf)
  __shared__ alignas(16) __bf16 Ps[8 * 16 * 64];     // 16 KB (aliased by Q stage)
  __shared__ alignas(16) float  Ms[2048];            //  8 KB mask row

  const int tid  = threadIdx.x;
  const int lane = tid & 63;
  const int w    = tid >> 6;
  const int g    = lane >> 4;
  const int ql   = lane & 15;
  const int bh   = blockIdx.y;
  const int b    = bh >> 4;
  const int h    = bh & 15;
  const int q0   = blockIdx.x * 128;

  const size_t kbase  = ((size_t)(b * S_)) * D_ + h * DH_;
  const size_t vtbase = (size_t)bh * DH_ * S_;
  const int NT = S_ / 64;

  char* Qsm = (char*)Ps;                             // overlay
  const size_t qbase = ((size_t)(b * S_) + q0) * D_ + h * DH_;
#pragma unroll
  for (int i = 0; i < 2; ++i) {
    int o   = tid * 16 + i * 8192;
    int row = o >> 7, cb = o & 127;
    int cbs = cb ^ ((row & 7) << 4);
    gload_lds16((const char*)Qb + (qbase + (size_t)row * D_) * 2 + cbs, Qsm + o);
  }
  {
    int o = tid * 16;
    gload_lds16((const char*)mask + (size_t)b * S_ * 4 + o, (char*)Ms + o);
  }
  {
    int o   = tid * 16;
    int row = o >> 7, cb = o & 127;
    int cbs = cb ^ ((row & 7) << 4);
    gload_lds16((const char*)Kb + (kbase + (size_t)row * D_) * 2 + cbs, (char*)Ks + o);
    gload_lds16((const char*)Vt + (vtbase + (size_t)row * S_) * 2 + cbs, (char*)Vs + o);
    gload_lds16((const char*)Kb + (kbase + (size_t)(64 + row) * D_) * 2 + cbs,
                (char*)Ks + 8192 + o);
    gload_lds16((const char*)Vt + (vtbase + (size_t)row * S_ + 64) * 2 + cbs,
                (char*)Vs + 8192 + o);
  }
  asm volatile("s_waitcnt vmcnt(4)" ::: "memory");   // Q + Ms landed
  __builtin_amdgcn_s_barrier();
  __builtin_amdgcn_sched_barrier(0);

  // scale mask in-place (log2 domain); visibility via the __syncthreads below
  {
    float4 mv = *(float4*)((char*)Ms + tid * 16);
    mv.x *= 1.44269504f; mv.y *= 1.44269504f;
    mv.z *= 1.44269504f; mv.w *= 1.44269504f;
    *(float4*)((char*)Ms + tid * 16) = mv;
  }

  bfx8 aq[2];
  {
    int row = w * 16 + ql;
#pragma unroll
    for (int kk = 0; kk < 2; ++kk) {
      int cb = kk * 64 + g * 16;
      aq[kk] = *(const bfx8*)(Qsm + row * 128 + (cb ^ ((row & 7) << 4)));
    }
  }
  __syncthreads();                                   // aq reads + Ms scale done
  asm volatile("s_waitcnt vmcnt(2)" ::: "memory");   // tile0 landed
  __builtin_amdgcn_s_barrier();
  __builtin_amdgcn_sched_barrier(0);

  float mrun = -1e30f;
  fx4 acc[4];
  fx4 accl = {0.f, 0.f, 0.f, 0.f};                   // row-sum accumulator
#pragma unroll
  for (int d = 0; d < 4; ++d) acc[d] = {0.f, 0.f, 0.f, 0.f};

  bfx8 ones;
#pragma unroll
  for (int j = 0; j < 8; ++j) ones[j] = (__bf16)1.0f;

  char* pw = (char*)Ps + w * 2048;
  const float SCL = 0.18033688f;                     // 0.125 * log2(e)

  for (int t = 0; t < NT; ++t) {
    const int kv0 = t * 64;
    if (t + 2 < NT) {
      int o   = tid * 16;
      int row = o >> 7, cb = o & 127;
      int cbs = cb ^ ((row & 7) << 4);
      int nkv = kv0 + 128;
      int bo  = ((t + 2) % 3) * 8192;
      gload_lds16((const char*)Kb + (kbase + (size_t)(nkv + row) * D_) * 2 + cbs,
                  (char*)Ks + bo + o);
      gload_lds16((const char*)Vt + (vtbase + (size_t)row * S_ + nkv) * 2 + cbs,
                  (char*)Vs + bo + o);
    }
    __builtin_amdgcn_sched_barrier(0);
    if (t > 0) {
      if (t + 2 < NT)      asm volatile("s_waitcnt vmcnt(4)" ::: "memory");
      else if (t + 1 < NT) asm volatile("s_waitcnt vmcnt(2)" ::: "memory");
      else                 asm volatile("s_waitcnt vmcnt(0)" ::: "memory");
      __builtin_amdgcn_s_barrier();
      __builtin_amdgcn_sched_barrier(0);
    }
    const char* Kc = (const char*)Ks + (t % 3) * 8192;
    const char* Vc = (const char*)Vs + (t % 3) * 8192;

    // swapped QK^T
    fx4 sc[4];
#pragma unroll
    for (int nf = 0; nf < 4; ++nf) sc[nf] = {0.f, 0.f, 0.f, 0.f};
#pragma unroll
    for (int kk = 0; kk < 2; ++kk) {
      const int cb = kk * 64 + g * 16;
      bfx8 bk[4];
#pragma unroll
      for (int nf = 0; nf < 4; ++nf) {
        int row = nf * 16 + ql;
        bk[nf] = *(const bfx8*)(Kc + row * 128 + (cb ^ ((row & 7) << 4)));
      }
      __builtin_amdgcn_s_setprio(1);
#pragma unroll
      for (int nf = 0; nf < 4; ++nf)
        sc[nf] = __builtin_amdgcn_mfma_f32_16x16x32_bf16(bk[nf], aq[kk], sc[nf], 0, 0, 0);
      __builtin_amdgcn_s_setprio(0);
    }

    float sv[4][4];
#pragma unroll
    for (int nf = 0; nf < 4; ++nf) {
      float4 mk = *(const float4*)((const char*)Ms + (kv0 + nf * 16 + g * 4) * 4);
      sv[nf][0] = sc[nf][0] * SCL + mk.x;
      sv[nf][1] = sc[nf][1] * SCL + mk.y;
      sv[nf][2] = sc[nf][2] * SCL + mk.z;
      sv[nf][3] = sc[nf][3] * SCL + mk.w;
    }
    float t0 = fmaxf(fmaxf(sv[0][0], sv[0][1]), fmaxf(sv[0][2], sv[0][3]));
    float t1 = fmaxf(fmaxf(sv[1][0], sv[1][1]), fmaxf(sv[1][2], sv[1][3]));
    float t2 = fmaxf(fmaxf(sv[2][0], sv[2][1]), fmaxf(sv[2][2], sv[2][3]));
    float t3 = fmaxf(fmaxf(sv[3][0], sv[3][1]), fmaxf(sv[3][2], sv[3][3]));
    float mx = fmaxf(fmaxf(t0, t1), fmaxf(t2, t3));
    mx = fmaxf(mx, __shfl_xor(mx, 16));
    mx = fmaxf(mx, __shfl_xor(mx, 32));

    // defer-max: rescale only when tile max exceeds running max + 8 (log2)
    if (!__all(mx <= mrun + 8.0f)) {
      float mnew  = fmaxf(mrun, mx);
      float alpha = fast_exp2(mrun - mnew);
      float af[4];
#pragma unroll
      for (int r = 0; r < 4; ++r) af[r] = __shfl(alpha, g * 4 + r);
#pragma unroll
      for (int d = 0; d < 4; ++d)
#pragma unroll
        for (int r = 0; r < 4; ++r) acc[d][r] *= af[r];
#pragma unroll
      for (int r = 0; r < 4; ++r) accl[r] *= af[r];
      mrun = mnew;
    }

#pragma unroll
    for (int nf = 0; nf < 4; ++nf)
#pragma unroll
      for (int r = 0; r < 4; ++r) sv[nf][r] = fast_exp2(sv[nf][r] - mrun);

    // write P strip row ql (vector bfx4)
#pragma unroll
    for (int nf = 0; nf < 4; ++nf) {
      bfx4 pv;
      pv[0] = (__bf16)sv[nf][0]; pv[1] = (__bf16)sv[nf][1];
      pv[2] = (__bf16)sv[nf][2]; pv[3] = (__bf16)sv[nf][3];
      int c = (nf * 32 + g * 8) ^ ((ql & 7) << 4);
      *(bfx4*)(pw + ql * 128 + c) = pv;
    }

    // fence: P-strip writes complete + no compiler motion of PV reads above
    asm volatile("s_waitcnt lgkmcnt(0)" ::: "memory");
    __builtin_amdgcn_sched_barrier(0);

    // PV + row-sum (ones-operand): accl accumulates sum_k P[q][k]
#pragma unroll
    for (int kk = 0; kk < 2; ++kk) {
      int prow = ql;
      int cb   = kk * 64 + g * 16;
      bfx8 ap  = *(const bfx8*)((const char*)pw + prow * 128 + (cb ^ ((prow & 7) << 4)));
      __builtin_amdgcn_s_setprio(1);
#pragma unroll
      for (int d = 0; d < 4; ++d) {
        int vrow = d * 16 + ql;
        bfx8 bv  = *(const bfx8*)(Vc + vrow * 128 + (cb ^ ((vrow & 7) << 4)));
        acc[d] = __builtin_amdgcn_mfma_f32_16x16x32_bf16(ap, bv, acc[d], 0, 0, 0);
      }
      accl = __builtin_amdgcn_mfma_f32_16x16x32_bf16(ap, ones, accl, 0, 0, 0);
      __builtin_amdgcn_s_setprio(0);
    }

    __builtin_amdgcn_s_barrier();
    __builtin_amdgcn_sched_barrier(0);
  }

  // finalize: denominator lane-local in accl[r] (every column = row-sum)
#pragma unroll
  for (int r = 0; r < 4; ++r) {
    float inv = 1.0f / accl[r];
    int qrow = q0 + w * 16 + g * 4 + r;
    size_t base = ((size_t)(b * S_) + qrow) * D_ + h * DH_;
#pragma unroll
    for (int d = 0; d < 4; ++d)
      ctx[base + d * 16 + ql] = (__bf16)(acc[d][r] * inv);
  }
}

// -------------------- LayerNorm over presummed bf16 input (row=1024)
template<bool WRITE_BF16>
__global__ __launch_bounds__(256)
void ln_kernel(const __bf16* __restrict__ a,
               const float* __restrict__ g, const float* __restrict__ beta,
               float* __restrict__ outf, __bf16* __restrict__ outb) {
  const int row = blockIdx.x;
  const int tid = threadIdx.x;
  const size_t base = (size_t)row * D_;
  bfx4 xa = *(const bfx4*)(a + base + tid * 4);
  float x[4] = {(float)xa[0], (float)xa[1], (float)xa[2], (float)xa[3]};
  float s = x[0] + x[1] + x[2] + x[3];
#pragma unroll
  for (int m = 1; m < 64; m <<= 1) s += __shfl_xor(s, m);
  __shared__ float red[8];
  if ((tid & 63) == 0) red[tid >> 6] = s;
  __syncthreads();
  float mu = (red[0] + red[1] + red[2] + red[3]) * (1.0f / D_);
  float v0 = 0.f;
#pragma unroll
  for (int i = 0; i < 4; ++i) { float d = x[i] - mu; v0 += d * d; }
#pragma unroll
  for (int m = 1; m < 64; m <<= 1) v0 += __shfl_xor(v0, m);
  if ((tid & 63) == 0) red[4 + (tid >> 6)] = v0;
  __syncthreads();
  float var = (red[4] + red[5] + red[6] + red[7]) * (1.0f / D_);
  float rs = rsqrtf(var + 1e-12f);
#pragma unroll
  for (int i = 0; i < 4; ++i) {
    int col = tid * 4 + i;
    x[i] = (x[i] - mu) * rs * g[col] + beta[col];
  }
  if (WRITE_BF16) {
    bfx4 o;
    o[0] = (__bf16)x[0]; o[1] = (__bf16)x[1]; o[2] = (__bf16)x[2]; o[3] = (__bf16)x[3];
    *(bfx4*)(outb + base + tid * 4) = o;
  } else {
    *(float4*)(outf + base + tid * 4) = make_float4(x[0], x[1], x[2], x[3]);
  }
}

// ---------------------------------------------------------------- launch
extern "C" void kernel_launch(void* const* d_in, const int* in_sizes, int n_in,
                              void* d_out, int out_size, void* d_ws, size_t ws_size,
                              hipStream_t stream) {
  const float* query    = (const float*)d_in[0];
  const float* key_in   = (const float*)d_in[1];
  const float* value_in = (const float*)d_in[2];
  const float* mask     = (const float*)d_in[3];
  const float* Wq = (const float*)d_in[4];  const float* bq = (const float*)d_in[5];
  const float* Wk = (const float*)d_in[6];  const float* bk = (const float*)d_in[7];
  const float* Wv = (const float*)d_in[8];  const float* bv = (const float*)d_in[9];
  const float* Wo = (const float*)d_in[10]; const float* bo = (const float*)d_in[11];
  const float* ln1g = (const float*)d_in[12]; const float* ln1b = (const float*)d_in[13];
  const float* Wi = (const float*)d_in[14]; const float* bi = (const float*)d_in[15];
  const float* Wd = (const float*)d_in[16]; const float* bd = (const float*)d_in[17];
  const float* ln2g = (const float*)d_in[18]; const float* ln2b = (const float*)d_in[19];

  char* ws = (char*)d_ws;
  const size_t MB = 1ull << 20;
  if (ws_size < 112 * MB) return;

  // liveness-audited layout (bf16 intermediate chain):
  __bf16* xq   = (__bf16*)(ws + 0 * MB);    // alive: cvt -> Wo residual
  __bf16* xk   = (__bf16*)(ws + 8 * MB);    // dead after qkv256
  __bf16* xv   = (__bf16*)(ws + 16 * MB);   // dead after qkv256
  __bf16* x1b  = (__bf16*)(ws + 16 * MB);   // LN1 out; Wi input + Wd residual
  __bf16* qb   = (__bf16*)(ws + 24 * MB);   // dead after attn
  __bf16* inter= (__bf16*)(ws + 24 * MB);   // Wi out (24-56); after LN1
  __bf16* kb   = (__bf16*)(ws + 32 * MB);   // dead after attn
  __bf16* vb   = (__bf16*)(ws + 40 * MB);   // dead after transpose_v
  __bf16* alinb= (__bf16*)(ws + 40 * MB);   // Wo out (8MB); dead after LN1
  __bf16* vt   = (__bf16*)(ws + 48 * MB);   // dead after attn
  __bf16* ctxb = (__bf16*)(ws + 56 * MB);   // dead after Wo
  __bf16* ffb  = (__bf16*)(ws + 56 * MB);   // Wd out (8MB); after Wo
  __bf16* wqt  = (__bf16*)(ws + 88 * MB);
  __bf16* wkt  = (__bf16*)(ws + 90 * MB);
  __bf16* wvt  = (__bf16*)(ws + 92 * MB);
  __bf16* wot  = (__bf16*)(ws + 94 * MB);
  __bf16* wit  = (__bf16*)(ws + 96 * MB);
  __bf16* wdt  = (__bf16*)(ws + 104 * MB);

  dim3 b256(256);
  dim3 tblk(32, 8);

  PrepArgs pa;
  pa.win[0] = Wq; pa.win[1] = Wk; pa.win[2] = Wv; pa.win[3] = Wo;
  pa.win[4] = Wi; pa.win[5] = Wd;
  pa.wout[0] = wqt; pa.wout[1] = wkt; pa.wout[2] = wvt; pa.wout[3] = wot;
  pa.wout[4] = wit; pa.wout[5] = wdt;
  pa.cin[0] = query; pa.cin[1] = key_in; pa.cin[2] = value_in;
  pa.cout[0] = xq;   pa.cout[1] = xk;    pa.cout[2] = xv;
  prep_kernel<<<dim3(24576), b256, 0, stream>>>(pa);

  QKVArgs qa;
  qa.A[0] = xq;  qa.A[1] = xk;  qa.A[2] = xv;
  qa.Bt[0] = wqt; qa.Bt[1] = wkt; qa.Bt[2] = wvt;
  qa.bias[0] = bq; qa.bias[1] = bk; qa.bias[2] = bv;
  qa.out[0] = qb; qa.out[1] = kb; qa.out[2] = vb;
  qkv256_kernel<<<dim3(D_ / 256, M_ / 256, 3), dim3(512), 131072, stream>>>(qa, D_, D_);

  transpose_v_kernel<<<dim3(S_ / 32, 2, B_ * H_), tblk, 0, stream>>>(vb, vt);

  attn_kernel<<<dim3(S_ / 128, B_ * H_), dim3(512), 0, stream>>>(qb, kb, vt, mask, ctxb);

  // Wo with fused +query residual (bf16 xq) -> alinb bf16
  gemm_kernel<4, 64><<<dim3(D_ / 64, M_ / 128), b256, 0, stream>>>(ctxb, wot, bo, xq, (void*)alinb, D_, D_);

  ln_kernel<true><<<dim3(M_), b256, 0, stream>>>(alinb, ln1g, ln1b, nullptr, x1b);

  gemm256_kernel<2><<<dim3(DFF_ / 256, M_ / 256), dim3(512), 131072, stream>>>(x1b, wit, bi, (void*)inter, DFF_, D_);

  // Wd with fused +x1b residual (bf16) -> ffb bf16
  gemm_kernel<4, 64><<<dim3(D_ / 64, M_ / 128), b256, 0, stream>>>(inter, wdt, bd, x1b, (void*)ffb, D_, DFF_);

  ln_kernel<false><<<dim3(M_), b256, 0, stream>>>(ffb, ln2g, ln2b, (float*)d_out, nullptr);
}